// Round 2
// baseline (2488.178 us; speedup 1.0000x reference)
//
#include <hip/hip_runtime.h>
#include <hip/hip_fp16.h>
#include <math.h>

#ifndef M_PI
#define M_PI 3.14159265358979323846
#endif

static constexpr int N_NODES = 20000;
static constexpr int N_EDGES = 320000;
static constexpr int NLAYER  = 3;

// ---------------- CSR build ----------------
__global__ void k_hist(const int* __restrict__ idx_i, int* __restrict__ cnt) {
  int e = blockIdx.x * 256 + threadIdx.x;
  if (e < N_EDGES) atomicAdd(&cnt[idx_i[e]], 1);
}

__global__ void k_scan(const int* __restrict__ cnt, int* __restrict__ rs) {
  __shared__ int buf[256];
  __shared__ int carry;
  int tid = threadIdx.x;
  if (tid == 0) carry = 0;
  __syncthreads();
  for (int base = 0; base < N_NODES; base += 256) {
    int i = base + tid;
    int v = (i < N_NODES) ? cnt[i] : 0;
    buf[tid] = v;
    __syncthreads();
    for (int off = 1; off < 256; off <<= 1) {
      int t = (tid >= off) ? buf[tid - off] : 0;
      __syncthreads();
      buf[tid] += t;
      __syncthreads();
    }
    int incl = buf[tid];
    if (i < N_NODES) rs[i] = carry + incl - v;
    __syncthreads();
    if (tid == 255) carry += incl;
    __syncthreads();
  }
  if (tid == 0) rs[N_NODES] = carry;
}

__global__ void k_fill(const int* __restrict__ idx_i, int* __restrict__ cur, int* __restrict__ eidx) {
  int e = blockIdx.x * 256 + threadIdx.x;
  if (e < N_EDGES) {
    int p = atomicAdd(&cur[idx_i[e]], 1);
    eidx[p] = e;
  }
}

// ---------------- edge geometry, CSR-permuted outputs ----------------
__global__ void k_edge_geom(const float* __restrict__ pos, const int* __restrict__ idx_all,
                            const int* __restrict__ eidx, float* __restrict__ dirp,
                            float* __restrict__ dij, float* __restrict__ fcut,
                            int* __restrict__ jperm) {
  int p = blockIdx.x * 256 + threadIdx.x;
  if (p >= N_EDGES) return;
  int e = eidx[p];
  int i = idx_all[e];
  int j = idx_all[N_EDGES + e];
  float rx = pos[j*3+0] - pos[i*3+0];
  float ry = pos[j*3+1] - pos[i*3+1];
  float rz = pos[j*3+2] - pos[i*3+2];
  float d = sqrtf(rx*rx + ry*ry + rz*rz);
  d = fmaxf(d, 1e-8f);
  float inv = 1.0f / d;
  dirp[p*3+0] = rx*inv; dirp[p*3+1] = ry*inv; dirp[p*3+2] = rz*inv;
  dij[p] = d;
  float xc = fminf(d * 0.2f, 1.0f);
  float fc = 0.5f * (cosf((float)M_PI * xc) + 1.0f);
  if (!(xc < 1.0f)) fc = 0.0f;
  fcut[p] = fc;
  jperm[p] = j;
}

// ---------------- generic fp32 SGEMM: C = epi(A@B + bias) ----------------
// EPI: 0 = bias only, 1 = silu(bias)
template<int EPI>
__global__ __launch_bounds__(256) void k_gemm(
    const float* __restrict__ A, const float* __restrict__ B,
    const float* __restrict__ bias, float* __restrict__ C,
    int M, int K, int ldb, int ldc) {
  __shared__ float As[16][132];
  __shared__ float Bs[16][132];
  const int bm = blockIdx.x * 128;
  const int bn = blockIdx.y * 128;
  const int tid = threadIdx.x;
  const int tr = (tid >> 4) << 3;
  const int tc = (tid & 15) << 3;
  float acc[8][8] = {};
  for (int k0 = 0; k0 < K; k0 += 16) {
    {
      int row = tid >> 1;
      int c8  = (tid & 1) << 3;
      int gm  = bm + row;
      float4 v0 = make_float4(0.f,0.f,0.f,0.f), v1 = v0;
      if (gm < M) {
        const float* ap = A + (size_t)gm * K + k0 + c8;
        v0 = *(const float4*)(ap);
        v1 = *(const float4*)(ap + 4);
      }
      As[c8+0][row]=v0.x; As[c8+1][row]=v0.y; As[c8+2][row]=v0.z; As[c8+3][row]=v0.w;
      As[c8+4][row]=v1.x; As[c8+5][row]=v1.y; As[c8+6][row]=v1.z; As[c8+7][row]=v1.w;
    }
    {
      int row = tid >> 4;
      int c8  = (tid & 15) << 3;
      const float* bp = B + (size_t)(k0 + row) * ldb + bn + c8;
      *(float4*)&Bs[row][c8]   = *(const float4*)bp;
      *(float4*)&Bs[row][c8+4] = *(const float4*)(bp + 4);
    }
    __syncthreads();
    #pragma unroll
    for (int kk = 0; kk < 16; ++kk) {
      float a[8], b[8];
      *(float4*)&a[0] = *(const float4*)&As[kk][tr];
      *(float4*)&a[4] = *(const float4*)&As[kk][tr+4];
      *(float4*)&b[0] = *(const float4*)&Bs[kk][tc];
      *(float4*)&b[4] = *(const float4*)&Bs[kk][tc+4];
      #pragma unroll
      for (int i2 = 0; i2 < 8; ++i2)
        #pragma unroll
        for (int j2 = 0; j2 < 8; ++j2)
          acc[i2][j2] = fmaf(a[i2], b[j2], acc[i2][j2]);
    }
    __syncthreads();
  }
  #pragma unroll
  for (int i2 = 0; i2 < 8; ++i2) {
    int gm = bm + tr + i2;
    if (gm >= M) continue;
    #pragma unroll
    for (int j2 = 0; j2 < 8; ++j2) {
      int gn = bn + tc + j2;
      float v = acc[i2][j2] + (bias ? bias[gn] : 0.0f);
      if (EPI == 1) v = v / (1.0f + expf(-v));
      C[(size_t)gm * ldc + gn] = v;
    }
  }
}

// ------- filter GEMM: phi computed on the fly from d; C fp16, chunked -------
// Processes CSR positions [rs[n0], rs[n1]); writes chunk-local rows of C.
__global__ __launch_bounds__(256) void k_filt_gemm(
    const float* __restrict__ dij, const float* __restrict__ fcut,
    const float* __restrict__ B, const float* __restrict__ bias,
    __half* __restrict__ C, const int* __restrict__ rs, int n0, int n1) {
  const int base = rs[n0];
  const int Mloc = rs[n1] - base;
  const int bm = blockIdx.x * 128;
  if (bm >= Mloc) return;
  const int bn = blockIdx.y * 128;
  __shared__ float As[16][132];
  __shared__ float Bs[16][132];
  const int tid = threadIdx.x;
  const int tr = (tid >> 4) << 3;
  const int tc = (tid & 15) << 3;
  const float delta = 5.0f / 63.0f;
  const float coeff = -0.5f / (delta * delta);
  // per-thread row assignment for A staging
  const int arow = tid >> 1;
  const int ac8  = (tid & 1) << 3;
  const int agm  = bm + arow;
  const float dv = (agm < Mloc) ? dij[base + agm] : 1.0f;
  float acc[8][8] = {};
  for (int k0 = 0; k0 < 64; k0 += 16) {
    #pragma unroll
    for (int t = 0; t < 8; ++t) {
      float u = dv - delta * (float)(k0 + ac8 + t);
      As[ac8 + t][arow] = expf(coeff * u * u);
    }
    {
      int row = tid >> 4;
      int c8  = (tid & 15) << 3;
      const float* bp = B + (size_t)(k0 + row) * 384 + bn + c8;
      *(float4*)&Bs[row][c8]   = *(const float4*)bp;
      *(float4*)&Bs[row][c8+4] = *(const float4*)(bp + 4);
    }
    __syncthreads();
    #pragma unroll
    for (int kk = 0; kk < 16; ++kk) {
      float a[8], b[8];
      *(float4*)&a[0] = *(const float4*)&As[kk][tr];
      *(float4*)&a[4] = *(const float4*)&As[kk][tr+4];
      *(float4*)&b[0] = *(const float4*)&Bs[kk][tc];
      *(float4*)&b[4] = *(const float4*)&Bs[kk][tc+4];
      #pragma unroll
      for (int i2 = 0; i2 < 8; ++i2)
        #pragma unroll
        for (int j2 = 0; j2 < 8; ++j2)
          acc[i2][j2] = fmaf(a[i2], b[j2], acc[i2][j2]);
    }
    __syncthreads();
  }
  #pragma unroll
  for (int i2 = 0; i2 < 8; ++i2) {
    int gm = bm + tr + i2;
    if (gm >= Mloc) continue;
    float fc = fcut[base + gm];
    #pragma unroll
    for (int j2 = 0; j2 < 8; ++j2) {
      int gn = bn + tc + j2;
      float v = (acc[i2][j2] + bias[gn]) * fc;
      v = fminf(fmaxf(v, -5.0f), 5.0f);
      C[(size_t)gm * 384 + gn] = __float2half(v);
    }
  }
}

// ---------------- per-node edge reduction (message passing) ----------------
__global__ __launch_bounds__(128) void k_edge_msg(
    const int* __restrict__ rs, const int* __restrict__ jperm,
    const float* __restrict__ x, const __half* __restrict__ filt,
    const float* __restrict__ dirp, const float* __restrict__ mu_in,
    float* __restrict__ q, float* __restrict__ mu_out, int n0) {
  int i = n0 + blockIdx.x;
  int d = threadIdx.x;
  int base = rs[n0];
  float accq = 0.f, am0 = 0.f, am1 = 0.f, am2 = 0.f;
  int s = rs[i], e_end = rs[i+1];
  for (int p = s; p < e_end; ++p) {
    int j = jperm[p];
    const __half* fe = filt + (size_t)(p - base) * 384;
    float W0 = __half2float(fe[d]);
    float W1 = __half2float(fe[128 + d]);
    float W2 = __half2float(fe[256 + d]);
    const float* xj = x + (size_t)j * 384;
    float x0 = xj[d], x1 = xj[128 + d], x2 = xj[256 + d];
    float dx = dirp[p*3+0], dy = dirp[p*3+1], dz = dirp[p*3+2];
    const float* mj = mu_in + (size_t)j * 384;
    float m1 = x1 * W1, m2 = x2 * W2;
    accq = fmaf(x0, W0, accq);
    am0 += m1 * dx + m2 * mj[d];
    am1 += m1 * dy + m2 * mj[128 + d];
    am2 += m1 * dz + m2 * mj[256 + d];
  }
  size_t qi = (size_t)i * 128 + d;
  q[qi] = q[qi] + accq;
  size_t mi = (size_t)i * 384;
  mu_out[mi + d]       = mu_in[mi + d]       + am0;
  mu_out[mi + 128 + d] = mu_in[mi + 128 + d] + am1;
  mu_out[mi + 256 + d] = mu_in[mi + 256 + d] + am2;
}

// ---------------- mix-phase elementwise kernels ----------------
__global__ void k_ctx(const float* __restrict__ xV, const float* __restrict__ muW,
                      const float* __restrict__ q, float* __restrict__ ctx,
                      float* __restrict__ svw) {
  int t = blockIdx.x * 256 + threadIdx.x;
  if (t >= N_NODES * 128) return;
  int n = t >> 7, d = t & 127;
  const float* vp = xV  + (size_t)n * 384;
  const float* wp = muW + (size_t)n * 384;
  float v0 = vp[d], v1 = vp[128 + d], v2 = vp[256 + d];
  float w0 = wp[d], w1 = wp[128 + d], w2 = wp[256 + d];
  float vn = sqrtf(v0*v0 + v1*v1 + v2*v2 + 1e-8f);
  float s  = v0*w0 + v1*w1 + v2*w2;
  ctx[(size_t)n * 256 + d]       = q[t];
  ctx[(size_t)n * 256 + 128 + d] = vn;
  svw[t] = s;
}

__global__ void k_mixupd(const float* __restrict__ xm, const float* __restrict__ muW,
                         const float* __restrict__ svw, float* __restrict__ q,
                         float* __restrict__ mu) {
  int t = blockIdx.x * 256 + threadIdx.x;
  if (t >= N_NODES * 128) return;
  int n = t >> 7, d = t & 127;
  const float* xr = xm + (size_t)n * 384;
  float dq = xr[d], dmu = xr[128 + d], dqmu = xr[256 + d];
  q[t] += dq + dqmu * svw[t];
  const float* wp = muW + (size_t)n * 384;
  float* mr = mu + (size_t)n * 384;
  mr[d]       += dmu * wp[d];
  mr[128 + d] += dmu * wp[128 + d];
  mr[256 + d] += dmu * wp[256 + d];
}

// ---------------- final outputs ----------------
__global__ __launch_bounds__(128) void k_posattr(
    const int* __restrict__ rs, const int* __restrict__ jperm,
    const float* __restrict__ mu, const float* __restrict__ w, float* __restrict__ pos_out) {
  __shared__ float red[3][128];
  int i = blockIdx.x, d = threadIdx.x;
  float a0 = 0.f, a1 = 0.f, a2 = 0.f;
  int s = rs[i], e_end = rs[i+1];
  for (int p = s; p < e_end; ++p) {
    int j = jperm[p];
    const float* mj = mu + (size_t)j * 384;
    a0 += mj[d]; a1 += mj[128 + d]; a2 += mj[256 + d];
  }
  a0 = fminf(fmaxf(a0, -5.f), 5.f);
  a1 = fminf(fmaxf(a1, -5.f), 5.f);
  a2 = fminf(fmaxf(a2, -5.f), 5.f);
  float wd = w[d];
  red[0][d] = a0 * wd; red[1][d] = a1 * wd; red[2][d] = a2 * wd;
  __syncthreads();
  for (int off = 64; off > 0; off >>= 1) {
    if (d < off) {
      red[0][d] += red[0][d+off];
      red[1][d] += red[1][d+off];
      red[2][d] += red[2][d+off];
    }
    __syncthreads();
  }
  if (d < 3) {
    float v = red[d][0];
    pos_out[(size_t)i * 3 + d] = fminf(fmaxf(v, -5.f), 5.f);
  }
}

__global__ __launch_bounds__(128) void k_ln(const float* __restrict__ q, const float* __restrict__ g,
                                            const float* __restrict__ b, float* __restrict__ out) {
  __shared__ float s1[128], s2[128];
  int n = blockIdx.x, d = threadIdx.x;
  float v = q[(size_t)n * 128 + d];
  v = fminf(fmaxf(v, -5.f), 5.f);
  s1[d] = v; s2[d] = v * v;
  __syncthreads();
  for (int off = 64; off > 0; off >>= 1) {
    if (d < off) { s1[d] += s1[d+off]; s2[d] += s2[d+off]; }
    __syncthreads();
  }
  float mean = s1[0] * (1.0f / 128.0f);
  float var  = s2[0] * (1.0f / 128.0f) - mean * mean;
  float y = (v - mean) * rsqrtf(var + 1e-5f) * g[d] + b[d];
  out[(size_t)n * 128 + d] = tanhf(y);
}

extern "C" void kernel_launch(void* const* d_in, const int* in_sizes, int n_in,
                              void* d_out, int out_size, void* d_ws, size_t ws_size,
                              hipStream_t stream) {
  const float* z         = (const float*)d_in[0];
  const float* pos       = (const float*)d_in[1];
  const int*   edge_idx  = (const int*)d_in[2];
  const float* in_w      = (const float*)d_in[3];
  const float* in_b      = (const float*)d_in[4];
  const float* filt_w    = (const float*)d_in[5];
  const float* filt_b    = (const float*)d_in[6];
  const float* inter_w1  = (const float*)d_in[7];
  const float* inter_b1  = (const float*)d_in[8];
  const float* inter_w2  = (const float*)d_in[9];
  const float* inter_b2  = (const float*)d_in[10];
  const float* mix_mu_w  = (const float*)d_in[11];
  const float* mix_w1    = (const float*)d_in[12];
  const float* mix_b1    = (const float*)d_in[13];
  const float* mix_w2    = (const float*)d_in[14];
  const float* mix_b2    = (const float*)d_in[15];
  const float* mu_proj_w = (const float*)d_in[16];
  const float* ln_g      = (const float*)d_in[17];
  const float* ln_b      = (const float*)d_in[18];

  char* base = (char*)d_ws;
  size_t off = 0;
  auto alloc = [&](size_t bytes) -> char* {
    char* p = base + off;
    off += (bytes + 255) & ~(size_t)255;
    return p;
  };
  float* q    = (float*)alloc((size_t)N_NODES * 128 * 4);
  float* h    = (float*)alloc((size_t)N_NODES * 128 * 4);
  float* xbuf = (float*)alloc((size_t)N_NODES * 384 * 4);  // x / mu_V / xm
  float* muW  = (float*)alloc((size_t)N_NODES * 384 * 4);
  float* mu_a = (float*)alloc((size_t)N_NODES * 384 * 4);
  float* mu_b = (float*)alloc((size_t)N_NODES * 384 * 4);
  float* ctx  = (float*)alloc((size_t)N_NODES * 256 * 4);
  float* svw  = (float*)alloc((size_t)N_NODES * 128 * 4);
  float* dirp = (float*)alloc((size_t)N_EDGES * 3 * 4);
  float* dij  = (float*)alloc((size_t)N_EDGES * 4);
  float* fcut = (float*)alloc((size_t)N_EDGES * 4);
  int*   cnt  = (int*)alloc((size_t)N_NODES * 4);
  int*   rs   = (int*)alloc((size_t)(N_NODES + 1) * 4);
  int*   cur  = (int*)alloc((size_t)N_NODES * 4);
  int*   eidx = (int*)alloc((size_t)N_EDGES * 4);
  int*   jperm= (int*)alloc((size_t)N_EDGES * 4);

  if (off > ws_size) return;  // fixed pool must fit
  size_t avail = ws_size - off;
  const size_t filt_full = (size_t)N_EDGES * 384 * 2;

  bool pre = (avail >= filt_full);
  int nchunk = 1, npc = N_NODES;
  size_t cap = N_EDGES;
  if (!pre) {
    bool found = false;
    for (int k = 2; k <= 100; ++k) {
      npc = (N_NODES + k - 1) / k;
      double mean_e = (double)N_EDGES * npc / N_NODES;
      cap = (size_t)(mean_e * 1.35) + 4096;
      if (cap * 768 <= avail) { nchunk = k; found = true; break; }
    }
    if (!found) return;
  }
  __half* filt = (__half*)alloc(cap * 384 * 2);
  if (off > ws_size) return;

  float* out_node = (float*)d_out;
  float* out_pos  = (float*)d_out + (size_t)N_NODES * 128;

  // ---- CSR build ----
  hipMemsetAsync(cnt, 0, (size_t)N_NODES * 4, stream);
  k_hist<<<N_EDGES / 256, 256, 0, stream>>>(edge_idx, cnt);
  k_scan<<<1, 256, 0, stream>>>(cnt, rs);
  hipMemcpyAsync(cur, rs, (size_t)N_NODES * 4, hipMemcpyDeviceToDevice, stream);
  k_fill<<<N_EDGES / 256, 256, 0, stream>>>(edge_idx, cur, eidx);

  // ---- edge geometry (CSR-permuted) ----
  k_edge_geom<<<N_EDGES / 256, 256, 0, stream>>>(pos, edge_idx, eidx, dirp, dij, fcut, jperm);

  // ---- filters (tier A: once for all edges) ----
  if (pre) {
    dim3 g((N_EDGES + 127) / 128, 3);
    k_filt_gemm<<<g, 256, 0, stream>>>(dij, fcut, filt_w, filt_b, filt, rs, 0, N_NODES);
  }

  // ---- input embedding ----
  dim3 ge((N_NODES + 127) / 128, 1);
  dim3 gx((N_NODES + 127) / 128, 3);
  dim3 gv((N_NODES * 3 + 127) / 128, 1);
  k_gemm<1><<<ge, 256, 0, stream>>>(z, in_w, in_b, q, N_NODES, 64, 128, 128);
  hipMemsetAsync(mu_a, 0, (size_t)N_NODES * 384 * 4, stream);

  float* mu_cur = mu_a;
  float* mu_nxt = mu_b;
  for (int l = 0; l < NLAYER; ++l) {
    k_gemm<1><<<ge, 256, 0, stream>>>(q, inter_w1 + (size_t)l*128*128, inter_b1 + (size_t)l*128,
                                      h, N_NODES, 128, 128, 128);
    k_gemm<0><<<gx, 256, 0, stream>>>(h, inter_w2 + (size_t)l*128*384, inter_b2 + (size_t)l*384,
                                      xbuf, N_NODES, 128, 384, 384);
    if (pre) {
      k_edge_msg<<<N_NODES, 128, 0, stream>>>(rs, jperm, xbuf, filt, dirp, mu_cur, q, mu_nxt, 0);
    } else {
      for (int c = 0; c < nchunk; ++c) {
        int n0 = c * npc;
        int n1 = n0 + npc; if (n1 > N_NODES) n1 = N_NODES;
        if (n0 >= n1) break;
        dim3 g(((int)cap + 127) / 128, 3);
        k_filt_gemm<<<g, 256, 0, stream>>>(dij, fcut, filt_w, filt_b, filt, rs, n0, n1);
        k_edge_msg<<<n1 - n0, 128, 0, stream>>>(rs, jperm, xbuf, filt, dirp, mu_cur, q, mu_nxt, n0);
      }
    }
    { float* t = mu_cur; mu_cur = mu_nxt; mu_nxt = t; }
    // mu_mix split: V -> xbuf, W -> muW   (mix_mu_w is (128,256) row-major)
    k_gemm<0><<<gv, 256, 0, stream>>>(mu_cur, mix_mu_w + (size_t)l*128*256,       nullptr,
                                      xbuf, N_NODES * 3, 128, 256, 128);
    k_gemm<0><<<gv, 256, 0, stream>>>(mu_cur, mix_mu_w + (size_t)l*128*256 + 128, nullptr,
                                      muW,  N_NODES * 3, 128, 256, 128);
    k_ctx<<<(N_NODES * 128) / 256, 256, 0, stream>>>(xbuf, muW, q, ctx, svw);
    k_gemm<1><<<ge, 256, 0, stream>>>(ctx, mix_w1 + (size_t)l*256*128, mix_b1 + (size_t)l*128,
                                      h, N_NODES, 256, 128, 128);
    k_gemm<0><<<gx, 256, 0, stream>>>(h, mix_w2 + (size_t)l*128*384, mix_b2 + (size_t)l*384,
                                      xbuf, N_NODES, 128, 384, 384);
    k_mixupd<<<(N_NODES * 128) / 256, 256, 0, stream>>>(xbuf, muW, svw, q, mu_cur);
  }

  // ---- outputs ----
  k_posattr<<<N_NODES, 128, 0, stream>>>(rs, jperm, mu_cur, mu_proj_w, out_pos);
  k_ln<<<N_NODES, 128, 0, stream>>>(q, ln_g, ln_b, out_node);
}

// Round 3
// 1742.257 us; speedup vs baseline: 1.4281x; 1.4281x over previous
//
#include <hip/hip_runtime.h>
#include <math.h>

#ifndef M_PI
#define M_PI 3.14159265358979323846
#endif

static constexpr int N_NODES = 20000;
static constexpr int N_EDGES = 320000;
static constexpr int NLAYER  = 3;
static constexpr int NB_SCAN = (N_NODES + 255) / 256;  // 79

typedef _Float16 f16;
typedef __attribute__((ext_vector_type(8))) _Float16 f16x8;
typedef __attribute__((ext_vector_type(4))) float f32x4;

// ---------------- CSR build ----------------
__global__ void k_hist(const int* __restrict__ idx_i, int* __restrict__ cnt) {
  int e = blockIdx.x * 256 + threadIdx.x;
  if (e < N_EDGES) atomicAdd(&cnt[idx_i[e]], 1);
}

__global__ void k_scan_blk(const int* __restrict__ cnt, int* __restrict__ incl,
                           int* __restrict__ bsum) {
  __shared__ int buf[256];
  int t = threadIdx.x;
  int i = blockIdx.x * 256 + t;
  int v = (i < N_NODES) ? cnt[i] : 0;
  buf[t] = v;
  __syncthreads();
  #pragma unroll
  for (int off = 1; off < 256; off <<= 1) {
    int x = (t >= off) ? buf[t - off] : 0;
    __syncthreads();
    buf[t] += x;
    __syncthreads();
  }
  if (i < N_NODES) incl[i] = buf[t];
  if (t == 255) bsum[blockIdx.x] = buf[255];
}

__global__ void k_scan_top(int* __restrict__ bsum) {
  __shared__ int buf[128];
  int t = threadIdx.x;
  int v = (t < NB_SCAN) ? bsum[t] : 0;
  buf[t] = v;
  __syncthreads();
  #pragma unroll
  for (int off = 1; off < 128; off <<= 1) {
    int x = (t >= off) ? buf[t - off] : 0;
    __syncthreads();
    buf[t] += x;
    __syncthreads();
  }
  if (t <= NB_SCAN) bsum[t] = buf[t] - v;  // exclusive; t==NB_SCAN -> total
}

__global__ void k_scan_add(const int* __restrict__ cnt, const int* __restrict__ incl,
                           const int* __restrict__ bsum, int* __restrict__ rs) {
  int i = blockIdx.x * 256 + threadIdx.x;
  if (i < N_NODES) rs[i] = bsum[blockIdx.x] + incl[i] - cnt[i];
  if (i == 0) rs[N_NODES] = bsum[NB_SCAN];
}

__global__ void k_fill(const int* __restrict__ idx_i, int* __restrict__ cur, int* __restrict__ eidx) {
  int e = blockIdx.x * 256 + threadIdx.x;
  if (e < N_EDGES) {
    int p = atomicAdd(&cur[idx_i[e]], 1);
    eidx[p] = e;
  }
}

// ---------------- edge geometry, CSR-permuted outputs ----------------
__global__ void k_edge_geom(const float* __restrict__ pos, const int* __restrict__ idx_all,
                            const int* __restrict__ eidx, float* __restrict__ dirp,
                            float* __restrict__ dij, float* __restrict__ fcut,
                            int* __restrict__ jperm) {
  int p = blockIdx.x * 256 + threadIdx.x;
  if (p >= N_EDGES) return;
  int e = eidx[p];
  int i = idx_all[e];
  int j = idx_all[N_EDGES + e];
  float rx = pos[j*3+0] - pos[i*3+0];
  float ry = pos[j*3+1] - pos[i*3+1];
  float rz = pos[j*3+2] - pos[i*3+2];
  float d = sqrtf(rx*rx + ry*ry + rz*rz);
  d = fmaxf(d, 1e-8f);
  float inv = 1.0f / d;
  dirp[p*3+0] = rx*inv; dirp[p*3+1] = ry*inv; dirp[p*3+2] = rz*inv;
  dij[p] = d;
  float xc = fminf(d * 0.2f, 1.0f);
  float fc = 0.5f * (cosf((float)M_PI * xc) + 1.0f);
  if (!(xc < 1.0f)) fc = 0.0f;
  fcut[p] = fc;
  jperm[p] = j;
}

// ---------------- weight transpose+convert: Wt[n][k] = (f16)src[k][col0+n] ----------------
struct WJob { const float* src; f16* dst; int kshift; int ld; int col0; int nk; };
struct WJobs { WJob j[20]; };

__global__ void k_wt_all(WJobs jb) {
  WJob w = jb.j[blockIdx.y];
  int t = blockIdx.x * 256 + threadIdx.x;
  if (t >= w.nk) return;
  int K = 1 << w.kshift;
  int n = t >> w.kshift;
  int k = t & (K - 1);
  w.dst[t] = (f16)w.src[(size_t)k * w.ld + w.col0 + n];
}

// ---------------- MFMA f16 GEMM: C[M x *] = epi(A[M x K] @ Wt[N][K]^T + bias) ----------------
// A fp32 row-major (row stride K), Wt f16 [N][K], C fp32 (row stride ldc, col offset bn).
// Block: 256 thr = 4 waves (2x2), tile 128x128, BK=32. EPI: 0=bias, 1=silu(bias).
template<int EPI>
__global__ __launch_bounds__(256) void k_mgemm(
    const float* __restrict__ A, const f16* __restrict__ Wt,
    const float* __restrict__ bias, float* __restrict__ C,
    int M, int K, int ldc) {
  __shared__ f16 As[128 * 32];
  __shared__ f16 Bs[128 * 32];
  const int bm = blockIdx.x * 128;
  const int bn = blockIdx.y * 128;
  const int tid = threadIdx.x;
  const int wave = tid >> 6, lane = tid & 63;
  const int wm = (wave & 1) * 64, wn = (wave >> 1) * 64;
  const int lr = lane & 15;
  const int lk = lane >> 4;
  const int srow = tid >> 1;
  const int sc0 = (tid & 1) * 2;
  const int sw = (srow >> 1) & 3;
  f32x4 acc[4][4] = {};
  for (int k0 = 0; k0 < K; k0 += 32) {
    // stage A (fp32 -> f16)
    {
      int gm = bm + srow;
      f16x8 c0, c1;
      if (gm < M) {
        const float* ap = A + (size_t)gm * K + k0 + sc0 * 8;
        float4 v0 = ((const float4*)ap)[0];
        float4 v1 = ((const float4*)ap)[1];
        float4 v2 = ((const float4*)ap)[2];
        float4 v3 = ((const float4*)ap)[3];
        c0[0]=(f16)v0.x; c0[1]=(f16)v0.y; c0[2]=(f16)v0.z; c0[3]=(f16)v0.w;
        c0[4]=(f16)v1.x; c0[5]=(f16)v1.y; c0[6]=(f16)v1.z; c0[7]=(f16)v1.w;
        c1[0]=(f16)v2.x; c1[1]=(f16)v2.y; c1[2]=(f16)v2.z; c1[3]=(f16)v2.w;
        c1[4]=(f16)v3.x; c1[5]=(f16)v3.y; c1[6]=(f16)v3.z; c1[7]=(f16)v3.w;
      } else {
        #pragma unroll
        for (int u = 0; u < 8; ++u) { c0[u] = (f16)0.f; c1[u] = (f16)0.f; }
      }
      *(f16x8*)&As[srow * 32 + ((sc0 ^ sw) << 3)]       = c0;
      *(f16x8*)&As[srow * 32 + (((sc0 + 1) ^ sw) << 3)] = c1;
    }
    // stage B (f16 direct)
    {
      const f16* bp = Wt + (size_t)(bn + srow) * K + k0 + sc0 * 8;
      f16x8 b0 = *(const f16x8*)bp;
      f16x8 b1 = *(const f16x8*)(bp + 8);
      *(f16x8*)&Bs[srow * 32 + ((sc0 ^ sw) << 3)]       = b0;
      *(f16x8*)&Bs[srow * 32 + (((sc0 + 1) ^ sw) << 3)] = b1;
    }
    __syncthreads();
    f16x8 af[4], bf[4];
    #pragma unroll
    for (int mt = 0; mt < 4; ++mt) {
      int r = wm + mt * 16 + lr;
      af[mt] = *(const f16x8*)&As[r * 32 + ((lk ^ ((r >> 1) & 3)) << 3)];
    }
    #pragma unroll
    for (int nt = 0; nt < 4; ++nt) {
      int r = wn + nt * 16 + lr;
      bf[nt] = *(const f16x8*)&Bs[r * 32 + ((lk ^ ((r >> 1) & 3)) << 3)];
    }
    #pragma unroll
    for (int mt = 0; mt < 4; ++mt)
      #pragma unroll
      for (int nt = 0; nt < 4; ++nt)
        acc[mt][nt] = __builtin_amdgcn_mfma_f32_16x16x32_f16(af[mt], bf[nt], acc[mt][nt], 0, 0, 0);
    __syncthreads();
  }
  #pragma unroll
  for (int mt = 0; mt < 4; ++mt) {
    int gm0 = bm + wm + mt * 16 + lk * 4;
    #pragma unroll
    for (int nt = 0; nt < 4; ++nt) {
      int gn = bn + wn + nt * 16 + lr;
      float bv = bias ? bias[gn] : 0.0f;
      #pragma unroll
      for (int rr = 0; rr < 4; ++rr) {
        int gm = gm0 + rr;
        if (gm >= M) continue;
        float v = acc[mt][nt][rr] + bv;
        if (EPI == 1) v = v / (1.0f + expf(-v));
        C[(size_t)gm * ldc + gn] = v;
      }
    }
  }
}

// ------- filter GEMM (MFMA): phi on-the-fly from d; C f16, CSR chunk [rs[n0], rs[n1]) -------
__global__ __launch_bounds__(256) void k_mfilt(
    const float* __restrict__ dij, const float* __restrict__ fcut,
    const f16* __restrict__ Wt, const float* __restrict__ bias,
    f16* __restrict__ C, const int* __restrict__ rs, int n0, int n1) {
  const int base = rs[n0];
  const int Mloc = rs[n1] - base;
  const int bm = blockIdx.x * 128;
  if (bm >= Mloc) return;
  const int bn = blockIdx.y * 128;
  __shared__ f16 As[128 * 32];
  __shared__ f16 Bs[128 * 32];
  const int tid = threadIdx.x;
  const int wave = tid >> 6, lane = tid & 63;
  const int wm = (wave & 1) * 64, wn = (wave >> 1) * 64;
  const int lr = lane & 15;
  const int lk = lane >> 4;
  const int srow = tid >> 1;
  const int sc0 = (tid & 1) * 2;
  const int sw = (srow >> 1) & 3;
  const float delta = 5.0f / 63.0f;
  const float coeff = -0.5f / (delta * delta);
  const float dv = (bm + srow < Mloc) ? dij[base + bm + srow] : 1e9f;
  f32x4 acc[4][4] = {};
  for (int k0 = 0; k0 < 64; k0 += 32) {
    {
      f16x8 c0, c1;
      #pragma unroll
      for (int u = 0; u < 8; ++u) {
        float u0 = dv - delta * (float)(k0 + sc0 * 8 + u);
        float u1 = dv - delta * (float)(k0 + sc0 * 8 + 8 + u);
        c0[u] = (f16)expf(coeff * u0 * u0);
        c1[u] = (f16)expf(coeff * u1 * u1);
      }
      *(f16x8*)&As[srow * 32 + ((sc0 ^ sw) << 3)]       = c0;
      *(f16x8*)&As[srow * 32 + (((sc0 + 1) ^ sw) << 3)] = c1;
    }
    {
      const f16* bp = Wt + (size_t)(bn + srow) * 64 + k0 + sc0 * 8;
      f16x8 b0 = *(const f16x8*)bp;
      f16x8 b1 = *(const f16x8*)(bp + 8);
      *(f16x8*)&Bs[srow * 32 + ((sc0 ^ sw) << 3)]       = b0;
      *(f16x8*)&Bs[srow * 32 + (((sc0 + 1) ^ sw) << 3)] = b1;
    }
    __syncthreads();
    f16x8 af[4], bf[4];
    #pragma unroll
    for (int mt = 0; mt < 4; ++mt) {
      int r = wm + mt * 16 + lr;
      af[mt] = *(const f16x8*)&As[r * 32 + ((lk ^ ((r >> 1) & 3)) << 3)];
    }
    #pragma unroll
    for (int nt = 0; nt < 4; ++nt) {
      int r = wn + nt * 16 + lr;
      bf[nt] = *(const f16x8*)&Bs[r * 32 + ((lk ^ ((r >> 1) & 3)) << 3)];
    }
    #pragma unroll
    for (int mt = 0; mt < 4; ++mt)
      #pragma unroll
      for (int nt = 0; nt < 4; ++nt)
        acc[mt][nt] = __builtin_amdgcn_mfma_f32_16x16x32_f16(af[mt], bf[nt], acc[mt][nt], 0, 0, 0);
    __syncthreads();
  }
  #pragma unroll
  for (int mt = 0; mt < 4; ++mt) {
    int gm0 = bm + wm + mt * 16 + lk * 4;
    #pragma unroll
    for (int nt = 0; nt < 4; ++nt) {
      int gn = bn + wn + nt * 16 + lr;
      float bv = bias[gn];
      #pragma unroll
      for (int rr = 0; rr < 4; ++rr) {
        int gm = gm0 + rr;
        if (gm >= Mloc) continue;
        float v = (acc[mt][nt][rr] + bv) * fcut[base + gm];
        v = fminf(fmaxf(v, -5.0f), 5.0f);
        C[(size_t)gm * 384 + gn] = (f16)v;
      }
    }
  }
}

// ---------------- per-node edge reduction (message passing) ----------------
__global__ __launch_bounds__(128) void k_edge_msg(
    const int* __restrict__ rs, const int* __restrict__ jperm,
    const float* __restrict__ x, const f16* __restrict__ filt,
    const float* __restrict__ dirp, const float* __restrict__ mu_in,
    float* __restrict__ q, float* __restrict__ mu_out, int n0) {
  int i = n0 + blockIdx.x;
  int d = threadIdx.x;
  int base = rs[n0];
  float accq = 0.f, am0 = 0.f, am1 = 0.f, am2 = 0.f;
  int s = rs[i], e_end = rs[i+1];
  for (int p = s; p < e_end; ++p) {
    int j = jperm[p];
    const f16* fe = filt + (size_t)(p - base) * 384;
    float W0 = (float)fe[d];
    float W1 = (float)fe[128 + d];
    float W2 = (float)fe[256 + d];
    const float* xj = x + (size_t)j * 384;
    float x0 = xj[d], x1 = xj[128 + d], x2 = xj[256 + d];
    float dx = dirp[p*3+0], dy = dirp[p*3+1], dz = dirp[p*3+2];
    const float* mj = mu_in + (size_t)j * 384;
    float m1 = x1 * W1, m2 = x2 * W2;
    accq = fmaf(x0, W0, accq);
    am0 += m1 * dx + m2 * mj[d];
    am1 += m1 * dy + m2 * mj[128 + d];
    am2 += m1 * dz + m2 * mj[256 + d];
  }
  size_t qi = (size_t)i * 128 + d;
  q[qi] = q[qi] + accq;
  size_t mi = (size_t)i * 384;
  mu_out[mi + d]       = mu_in[mi + d]       + am0;
  mu_out[mi + 128 + d] = mu_in[mi + 128 + d] + am1;
  mu_out[mi + 256 + d] = mu_in[mi + 256 + d] + am2;
}

// ---------------- mix-phase elementwise kernels ----------------
__global__ void k_ctx(const float* __restrict__ xV, const float* __restrict__ muW,
                      const float* __restrict__ q, float* __restrict__ ctx,
                      float* __restrict__ svw) {
  int t = blockIdx.x * 256 + threadIdx.x;
  if (t >= N_NODES * 128) return;
  int n = t >> 7, d = t & 127;
  const float* vp = xV  + (size_t)n * 384;
  const float* wp = muW + (size_t)n * 384;
  float v0 = vp[d], v1 = vp[128 + d], v2 = vp[256 + d];
  float w0 = wp[d], w1 = wp[128 + d], w2 = wp[256 + d];
  float vn = sqrtf(v0*v0 + v1*v1 + v2*v2 + 1e-8f);
  float s  = v0*w0 + v1*w1 + v2*w2;
  ctx[(size_t)n * 256 + d]       = q[t];
  ctx[(size_t)n * 256 + 128 + d] = vn;
  svw[t] = s;
}

__global__ void k_mixupd(const float* __restrict__ xm, const float* __restrict__ muW,
                         const float* __restrict__ svw, float* __restrict__ q,
                         float* __restrict__ mu) {
  int t = blockIdx.x * 256 + threadIdx.x;
  if (t >= N_NODES * 128) return;
  int n = t >> 7, d = t & 127;
  const float* xr = xm + (size_t)n * 384;
  float dq = xr[d], dmu = xr[128 + d], dqmu = xr[256 + d];
  q[t] += dq + dqmu * svw[t];
  const float* wp = muW + (size_t)n * 384;
  float* mr = mu + (size_t)n * 384;
  mr[d]       += dmu * wp[d];
  mr[128 + d] += dmu * wp[128 + d];
  mr[256 + d] += dmu * wp[256 + d];
}

// ---------------- final outputs ----------------
__global__ __launch_bounds__(128) void k_posattr(
    const int* __restrict__ rs, const int* __restrict__ jperm,
    const float* __restrict__ mu, const float* __restrict__ w, float* __restrict__ pos_out) {
  __shared__ float red[3][128];
  int i = blockIdx.x, d = threadIdx.x;
  float a0 = 0.f, a1 = 0.f, a2 = 0.f;
  int s = rs[i], e_end = rs[i+1];
  for (int p = s; p < e_end; ++p) {
    int j = jperm[p];
    const float* mj = mu + (size_t)j * 384;
    a0 += mj[d]; a1 += mj[128 + d]; a2 += mj[256 + d];
  }
  a0 = fminf(fmaxf(a0, -5.f), 5.f);
  a1 = fminf(fmaxf(a1, -5.f), 5.f);
  a2 = fminf(fmaxf(a2, -5.f), 5.f);
  float wd = w[d];
  red[0][d] = a0 * wd; red[1][d] = a1 * wd; red[2][d] = a2 * wd;
  __syncthreads();
  for (int off = 64; off > 0; off >>= 1) {
    if (d < off) {
      red[0][d] += red[0][d+off];
      red[1][d] += red[1][d+off];
      red[2][d] += red[2][d+off];
    }
    __syncthreads();
  }
  if (d < 3) {
    float v = red[d][0];
    pos_out[(size_t)i * 3 + d] = fminf(fmaxf(v, -5.f), 5.f);
  }
}

__global__ __launch_bounds__(128) void k_ln(const float* __restrict__ q, const float* __restrict__ g,
                                            const float* __restrict__ b, float* __restrict__ out) {
  __shared__ float s1[128], s2[128];
  int n = blockIdx.x, d = threadIdx.x;
  float v = q[(size_t)n * 128 + d];
  v = fminf(fmaxf(v, -5.f), 5.f);
  s1[d] = v; s2[d] = v * v;
  __syncthreads();
  for (int off = 64; off > 0; off >>= 1) {
    if (d < off) { s1[d] += s1[d+off]; s2[d] += s2[d+off]; }
    __syncthreads();
  }
  float mean = s1[0] * (1.0f / 128.0f);
  float var  = s2[0] * (1.0f / 128.0f) - mean * mean;
  float y = (v - mean) * rsqrtf(var + 1e-5f) * g[d] + b[d];
  out[(size_t)n * 128 + d] = tanhf(y);
}

extern "C" void kernel_launch(void* const* d_in, const int* in_sizes, int n_in,
                              void* d_out, int out_size, void* d_ws, size_t ws_size,
                              hipStream_t stream) {
  const float* z         = (const float*)d_in[0];
  const float* pos       = (const float*)d_in[1];
  const int*   edge_idx  = (const int*)d_in[2];
  const float* in_w      = (const float*)d_in[3];
  const float* in_b      = (const float*)d_in[4];
  const float* filt_w    = (const float*)d_in[5];
  const float* filt_b    = (const float*)d_in[6];
  const float* inter_w1  = (const float*)d_in[7];
  const float* inter_b1  = (const float*)d_in[8];
  const float* inter_w2  = (const float*)d_in[9];
  const float* inter_b2  = (const float*)d_in[10];
  const float* mix_mu_w  = (const float*)d_in[11];
  const float* mix_w1    = (const float*)d_in[12];
  const float* mix_b1    = (const float*)d_in[13];
  const float* mix_w2    = (const float*)d_in[14];
  const float* mix_b2    = (const float*)d_in[15];
  const float* mu_proj_w = (const float*)d_in[16];
  const float* ln_g      = (const float*)d_in[17];
  const float* ln_b      = (const float*)d_in[18];

  char* base = (char*)d_ws;
  size_t off = 0;
  auto alloc = [&](size_t bytes) -> char* {
    char* p = base + off;
    off += (bytes + 255) & ~(size_t)255;
    return p;
  };
  float* q    = (float*)alloc((size_t)N_NODES * 128 * 4);
  float* h    = (float*)alloc((size_t)N_NODES * 128 * 4);
  float* xbuf = (float*)alloc((size_t)N_NODES * 384 * 4);  // x / mu_V / xm
  float* muW  = (float*)alloc((size_t)N_NODES * 384 * 4);
  float* mu_a = (float*)alloc((size_t)N_NODES * 384 * 4);
  float* mu_b = (float*)alloc((size_t)N_NODES * 384 * 4);
  float* ctx  = (float*)alloc((size_t)N_NODES * 256 * 4);
  float* svw  = (float*)alloc((size_t)N_NODES * 128 * 4);
  float* dirp = (float*)alloc((size_t)N_EDGES * 3 * 4);
  float* dij  = (float*)alloc((size_t)N_EDGES * 4);
  float* fcut = (float*)alloc((size_t)N_EDGES * 4);
  int*   cnt  = (int*)alloc((size_t)N_NODES * 4);
  int*   incl = (int*)alloc((size_t)N_NODES * 4);
  int*   bsum = (int*)alloc(128 * 4);
  int*   rs   = (int*)alloc((size_t)(N_NODES + 1) * 4);
  int*   cur  = (int*)alloc((size_t)N_NODES * 4);
  int*   eidx = (int*)alloc((size_t)N_EDGES * 4);
  int*   jperm= (int*)alloc((size_t)N_EDGES * 4);
  // f16 transposed weights
  f16* wt_in = (f16*)alloc((size_t)128 * 64 * 2);
  f16* wt_f  = (f16*)alloc((size_t)384 * 64 * 2);
  f16* wt_i1 = (f16*)alloc((size_t)3 * 128 * 128 * 2);
  f16* wt_i2 = (f16*)alloc((size_t)3 * 384 * 128 * 2);
  f16* wt_mV = (f16*)alloc((size_t)3 * 128 * 128 * 2);
  f16* wt_mW = (f16*)alloc((size_t)3 * 128 * 128 * 2);
  f16* wt_x1 = (f16*)alloc((size_t)3 * 128 * 256 * 2);
  f16* wt_x2 = (f16*)alloc((size_t)3 * 384 * 128 * 2);

  if (off > ws_size) return;
  size_t avail = ws_size - off;
  const size_t filt_full = (size_t)N_EDGES * 384 * 2;

  bool pre = (avail >= filt_full);
  int nchunk = 1, npc = N_NODES;
  size_t cap = N_EDGES;
  if (!pre) {
    bool found = false;
    for (int k = 2; k <= 100; ++k) {
      npc = (N_NODES + k - 1) / k;
      double mean_e = (double)N_EDGES * npc / N_NODES;
      cap = (size_t)(mean_e * 1.35) + 4096;
      if (cap * 768 <= avail) { nchunk = k; found = true; break; }
    }
    if (!found) return;
  }
  f16* filt = (f16*)alloc(cap * 384 * 2);
  if (off > ws_size) return;

  float* out_node = (float*)d_out;
  float* out_pos  = (float*)d_out + (size_t)N_NODES * 128;

  // ---- weight prep (f16, [N][K]) ----
  {
    WJobs jb;
    int ji = 0;
    jb.j[ji++] = {in_w,   wt_in, 6, 128, 0, 128 * 64};
    jb.j[ji++] = {filt_w, wt_f,  6, 384, 0, 384 * 64};
    for (int l = 0; l < 3; ++l)
      jb.j[ji++] = {inter_w1 + (size_t)l*128*128, wt_i1 + (size_t)l*128*128, 7, 128, 0, 128*128};
    for (int l = 0; l < 3; ++l)
      jb.j[ji++] = {inter_w2 + (size_t)l*128*384, wt_i2 + (size_t)l*384*128, 7, 384, 0, 384*128};
    for (int l = 0; l < 3; ++l)
      jb.j[ji++] = {mix_mu_w + (size_t)l*128*256, wt_mV + (size_t)l*128*128, 7, 256, 0,   128*128};
    for (int l = 0; l < 3; ++l)
      jb.j[ji++] = {mix_mu_w + (size_t)l*128*256, wt_mW + (size_t)l*128*128, 7, 256, 128, 128*128};
    for (int l = 0; l < 3; ++l)
      jb.j[ji++] = {mix_w1 + (size_t)l*256*128, wt_x1 + (size_t)l*128*256, 8, 128, 0, 128*256};
    for (int l = 0; l < 3; ++l)
      jb.j[ji++] = {mix_w2 + (size_t)l*128*384, wt_x2 + (size_t)l*384*128, 7, 384, 0, 384*128};
    dim3 g(192, 20);
    k_wt_all<<<g, 256, 0, stream>>>(jb);
  }

  // ---- CSR build ----
  hipMemsetAsync(cnt, 0, (size_t)N_NODES * 4, stream);
  k_hist<<<N_EDGES / 256, 256, 0, stream>>>(edge_idx, cnt);
  k_scan_blk<<<NB_SCAN, 256, 0, stream>>>(cnt, incl, bsum);
  k_scan_top<<<1, 128, 0, stream>>>(bsum);
  k_scan_add<<<NB_SCAN, 256, 0, stream>>>(cnt, incl, bsum, rs);
  hipMemcpyAsync(cur, rs, (size_t)N_NODES * 4, hipMemcpyDeviceToDevice, stream);
  k_fill<<<N_EDGES / 256, 256, 0, stream>>>(edge_idx, cur, eidx);

  // ---- edge geometry (CSR-permuted) ----
  k_edge_geom<<<N_EDGES / 256, 256, 0, stream>>>(pos, edge_idx, eidx, dirp, dij, fcut, jperm);

  // ---- filters (tier A: once for all edges) ----
  if (pre) {
    dim3 g((N_EDGES + 127) / 128, 3);
    k_mfilt<<<g, 256, 0, stream>>>(dij, fcut, wt_f, filt_b, filt, rs, 0, N_NODES);
  }

  // ---- input embedding ----
  dim3 ge((N_NODES + 127) / 128, 1);
  dim3 gx((N_NODES + 127) / 128, 3);
  dim3 gv((N_NODES * 3 + 127) / 128, 1);
  k_mgemm<1><<<ge, 256, 0, stream>>>(z, wt_in, in_b, q, N_NODES, 64, 128);
  hipMemsetAsync(mu_a, 0, (size_t)N_NODES * 384 * 4, stream);

  float* mu_cur = mu_a;
  float* mu_nxt = mu_b;
  for (int l = 0; l < NLAYER; ++l) {
    k_mgemm<1><<<ge, 256, 0, stream>>>(q, wt_i1 + (size_t)l*128*128, inter_b1 + (size_t)l*128,
                                       h, N_NODES, 128, 128);
    k_mgemm<0><<<gx, 256, 0, stream>>>(h, wt_i2 + (size_t)l*384*128, inter_b2 + (size_t)l*384,
                                       xbuf, N_NODES, 128, 384);
    if (pre) {
      k_edge_msg<<<N_NODES, 128, 0, stream>>>(rs, jperm, xbuf, filt, dirp, mu_cur, q, mu_nxt, 0);
    } else {
      for (int c = 0; c < nchunk; ++c) {
        int n0 = c * npc;
        int n1 = n0 + npc; if (n1 > N_NODES) n1 = N_NODES;
        if (n0 >= n1) break;
        dim3 g(((int)cap + 127) / 128, 3);
        k_mfilt<<<g, 256, 0, stream>>>(dij, fcut, wt_f, filt_b, filt, rs, n0, n1);
        k_edge_msg<<<n1 - n0, 128, 0, stream>>>(rs, jperm, xbuf, filt, dirp, mu_cur, q, mu_nxt, n0);
      }
    }
    { float* t = mu_cur; mu_cur = mu_nxt; mu_nxt = t; }
    k_mgemm<0><<<gv, 256, 0, stream>>>(mu_cur, wt_mV + (size_t)l*128*128, nullptr,
                                       xbuf, N_NODES * 3, 128, 128);
    k_mgemm<0><<<gv, 256, 0, stream>>>(mu_cur, wt_mW + (size_t)l*128*128, nullptr,
                                       muW, N_NODES * 3, 128, 128);
    k_ctx<<<(N_NODES * 128) / 256, 256, 0, stream>>>(xbuf, muW, q, ctx, svw);
    k_mgemm<1><<<ge, 256, 0, stream>>>(ctx, wt_x1 + (size_t)l*128*256, mix_b1 + (size_t)l*128,
                                       h, N_NODES, 256, 128);
    k_mgemm<0><<<gx, 256, 0, stream>>>(h, wt_x2 + (size_t)l*384*128, mix_b2 + (size_t)l*384,
                                       xbuf, N_NODES, 128, 384);
    k_mixupd<<<(N_NODES * 128) / 256, 256, 0, stream>>>(xbuf, muW, svw, q, mu_cur);
  }

  // ---- outputs ----
  k_posattr<<<N_NODES, 128, 0, stream>>>(rs, jperm, mu_cur, mu_proj_w, out_pos);
  k_ln<<<N_NODES, 128, 0, stream>>>(q, ln_g, ln_b, out_node);
}

// Round 4
// 1415.060 us; speedup vs baseline: 1.7584x; 1.2312x over previous
//
#include <hip/hip_runtime.h>
#include <math.h>

#ifndef M_PI
#define M_PI 3.14159265358979323846
#endif

static constexpr int N_NODES = 20000;
static constexpr int N_EDGES = 320000;
static constexpr int NLAYER  = 3;
static constexpr int NB_SCAN = (N_NODES + 255) / 256;  // 79

typedef _Float16 f16;
typedef __attribute__((ext_vector_type(8))) _Float16 f16x8;
typedef __attribute__((ext_vector_type(4))) float f32x4;

__device__ __forceinline__ void storev(float* p, float v) { *p = v; }
__device__ __forceinline__ void storev(f16* p, float v)   { *p = (f16)v; }

// ---------------- CSR build ----------------
__global__ void k_hist(const int* __restrict__ idx_i, int* __restrict__ cnt) {
  int e = blockIdx.x * 256 + threadIdx.x;
  if (e < N_EDGES) atomicAdd(&cnt[idx_i[e]], 1);
}

__global__ void k_scan_blk(const int* __restrict__ cnt, int* __restrict__ incl,
                           int* __restrict__ bsum) {
  __shared__ int buf[256];
  int t = threadIdx.x;
  int i = blockIdx.x * 256 + t;
  int v = (i < N_NODES) ? cnt[i] : 0;
  buf[t] = v;
  __syncthreads();
  #pragma unroll
  for (int off = 1; off < 256; off <<= 1) {
    int x = (t >= off) ? buf[t - off] : 0;
    __syncthreads();
    buf[t] += x;
    __syncthreads();
  }
  if (i < N_NODES) incl[i] = buf[t];
  if (t == 255) bsum[blockIdx.x] = buf[255];
}

__global__ void k_scan_top(int* __restrict__ bsum) {
  __shared__ int buf[128];
  int t = threadIdx.x;
  int v = (t < NB_SCAN) ? bsum[t] : 0;
  buf[t] = v;
  __syncthreads();
  #pragma unroll
  for (int off = 1; off < 128; off <<= 1) {
    int x = (t >= off) ? buf[t - off] : 0;
    __syncthreads();
    buf[t] += x;
    __syncthreads();
  }
  if (t <= NB_SCAN) bsum[t] = buf[t] - v;  // exclusive; t==NB_SCAN -> total
}

__global__ void k_scan_add(const int* __restrict__ cnt, const int* __restrict__ incl,
                           const int* __restrict__ bsum, int* __restrict__ rs) {
  int i = blockIdx.x * 256 + threadIdx.x;
  if (i < N_NODES) rs[i] = bsum[blockIdx.x] + incl[i] - cnt[i];
  if (i == 0) rs[N_NODES] = bsum[NB_SCAN];
}

__global__ void k_fill(const int* __restrict__ idx_i, int* __restrict__ cur, int* __restrict__ eidx) {
  int e = blockIdx.x * 256 + threadIdx.x;
  if (e < N_EDGES) {
    int p = atomicAdd(&cur[idx_i[e]], 1);
    eidx[p] = e;
  }
}

// ---------------- edge geometry, CSR-permuted outputs ----------------
__global__ void k_edge_geom(const float* __restrict__ pos, const int* __restrict__ idx_all,
                            const int* __restrict__ eidx, float* __restrict__ dirp,
                            float* __restrict__ dij, float* __restrict__ fcut,
                            int* __restrict__ jperm) {
  int p = blockIdx.x * 256 + threadIdx.x;
  if (p >= N_EDGES) return;
  int e = eidx[p];
  int i = idx_all[e];
  int j = idx_all[N_EDGES + e];
  float rx = pos[j*3+0] - pos[i*3+0];
  float ry = pos[j*3+1] - pos[i*3+1];
  float rz = pos[j*3+2] - pos[i*3+2];
  float d = sqrtf(rx*rx + ry*ry + rz*rz);
  d = fmaxf(d, 1e-8f);
  float inv = 1.0f / d;
  dirp[p*3+0] = rx*inv; dirp[p*3+1] = ry*inv; dirp[p*3+2] = rz*inv;
  dij[p] = d;
  float xc = fminf(d * 0.2f, 1.0f);
  float fc = 0.5f * (cosf((float)M_PI * xc) + 1.0f);
  if (!(xc < 1.0f)) fc = 0.0f;
  fcut[p] = fc;
  jperm[p] = j;
}

// ---------------- weight transpose+convert: Wt[n][k] = (f16)src[k][col0+n] ----------------
struct WJob { const float* src; f16* dst; int kshift; int ld; int col0; int nk; };
struct WJobs { WJob j[17]; };

__global__ void k_wt_all(WJobs jb) {
  WJob w = jb.j[blockIdx.y];
  int t = blockIdx.x * 256 + threadIdx.x;
  if (t >= w.nk) return;
  int K = 1 << w.kshift;
  int n = t >> w.kshift;
  int k = t & (K - 1);
  w.dst[t] = (f16)w.src[(size_t)k * w.ld + w.col0 + n];
}

// ---------------- MFMA f16 GEMM: C[M x *] = epi(A[M x K] @ Wt[N][K]^T + bias) ----------------
// A row-major (row stride K, f32 or f16), Wt f16 [N][K], C (row stride ldc, f32 or f16).
// Block: 256 thr = 4 waves (2x2), tile 128x128, BK=32. EPI: 0=bias, 1=silu(bias).
template<int EPI, typename AT, typename CT>
__global__ __launch_bounds__(256) void k_mgemm(
    const AT* __restrict__ A, const f16* __restrict__ Wt,
    const float* __restrict__ bias, CT* __restrict__ C,
    int M, int K, int ldc) {
  __shared__ f16 As[128 * 32];
  __shared__ f16 Bs[128 * 32];
  const int bm = blockIdx.x * 128;
  const int bn = blockIdx.y * 128;
  const int tid = threadIdx.x;
  const int wave = tid >> 6, lane = tid & 63;
  const int wm = (wave & 1) * 64, wn = (wave >> 1) * 64;
  const int lr = lane & 15;
  const int lk = lane >> 4;
  const int srow = tid >> 1;
  const int sc0 = (tid & 1) * 2;
  const int sw = (srow >> 1) & 3;
  f32x4 acc[4][4] = {};
  for (int k0 = 0; k0 < K; k0 += 32) {
    // stage A
    {
      int gm = bm + srow;
      f16x8 c0, c1;
      if (gm < M) {
        if constexpr (sizeof(AT) == 2) {
          const f16* ap = (const f16*)A + (size_t)gm * K + k0 + sc0 * 8;
          c0 = *(const f16x8*)ap;
          c1 = *(const f16x8*)(ap + 8);
        } else {
          const float* ap = (const float*)A + (size_t)gm * K + k0 + sc0 * 8;
          float4 v0 = ((const float4*)ap)[0];
          float4 v1 = ((const float4*)ap)[1];
          float4 v2 = ((const float4*)ap)[2];
          float4 v3 = ((const float4*)ap)[3];
          c0[0]=(f16)v0.x; c0[1]=(f16)v0.y; c0[2]=(f16)v0.z; c0[3]=(f16)v0.w;
          c0[4]=(f16)v1.x; c0[5]=(f16)v1.y; c0[6]=(f16)v1.z; c0[7]=(f16)v1.w;
          c1[0]=(f16)v2.x; c1[1]=(f16)v2.y; c1[2]=(f16)v2.z; c1[3]=(f16)v2.w;
          c1[4]=(f16)v3.x; c1[5]=(f16)v3.y; c1[6]=(f16)v3.z; c1[7]=(f16)v3.w;
        }
      } else {
        #pragma unroll
        for (int u = 0; u < 8; ++u) { c0[u] = (f16)0.f; c1[u] = (f16)0.f; }
      }
      *(f16x8*)&As[srow * 32 + ((sc0 ^ sw) << 3)]       = c0;
      *(f16x8*)&As[srow * 32 + (((sc0 + 1) ^ sw) << 3)] = c1;
    }
    // stage B (f16 direct)
    {
      const f16* bp = Wt + (size_t)(bn + srow) * K + k0 + sc0 * 8;
      f16x8 b0 = *(const f16x8*)bp;
      f16x8 b1 = *(const f16x8*)(bp + 8);
      *(f16x8*)&Bs[srow * 32 + ((sc0 ^ sw) << 3)]       = b0;
      *(f16x8*)&Bs[srow * 32 + (((sc0 + 1) ^ sw) << 3)] = b1;
    }
    __syncthreads();
    f16x8 af[4], bf[4];
    #pragma unroll
    for (int mt = 0; mt < 4; ++mt) {
      int r = wm + mt * 16 + lr;
      af[mt] = *(const f16x8*)&As[r * 32 + ((lk ^ ((r >> 1) & 3)) << 3)];
    }
    #pragma unroll
    for (int nt = 0; nt < 4; ++nt) {
      int r = wn + nt * 16 + lr;
      bf[nt] = *(const f16x8*)&Bs[r * 32 + ((lk ^ ((r >> 1) & 3)) << 3)];
    }
    #pragma unroll
    for (int mt = 0; mt < 4; ++mt)
      #pragma unroll
      for (int nt = 0; nt < 4; ++nt)
        acc[mt][nt] = __builtin_amdgcn_mfma_f32_16x16x32_f16(af[mt], bf[nt], acc[mt][nt], 0, 0, 0);
    __syncthreads();
  }
  #pragma unroll
  for (int mt = 0; mt < 4; ++mt) {
    int gm0 = bm + wm + mt * 16 + lk * 4;
    #pragma unroll
    for (int nt = 0; nt < 4; ++nt) {
      int gn = bn + wn + nt * 16 + lr;
      float bv = bias ? bias[gn] : 0.0f;
      #pragma unroll
      for (int rr = 0; rr < 4; ++rr) {
        int gm = gm0 + rr;
        if (gm >= M) continue;
        float v = acc[mt][nt][rr] + bv;
        if (EPI == 1) v = v / (1.0f + expf(-v));
        storev(&C[(size_t)gm * ldc + gn], v);
      }
    }
  }
}

// ------- filter GEMM (MFMA): phi on-the-fly from d; C f16, CSR chunk [rs[n0], rs[n1]) -------
__global__ __launch_bounds__(256) void k_mfilt(
    const float* __restrict__ dij, const float* __restrict__ fcut,
    const f16* __restrict__ Wt, const float* __restrict__ bias,
    f16* __restrict__ C, const int* __restrict__ rs, int n0, int n1) {
  const int base = rs[n0];
  const int Mloc = rs[n1] - base;
  const int bm = blockIdx.x * 128;
  if (bm >= Mloc) return;
  const int bn = blockIdx.y * 128;
  __shared__ f16 As[128 * 32];
  __shared__ f16 Bs[128 * 32];
  const int tid = threadIdx.x;
  const int wave = tid >> 6, lane = tid & 63;
  const int wm = (wave & 1) * 64, wn = (wave >> 1) * 64;
  const int lr = lane & 15;
  const int lk = lane >> 4;
  const int srow = tid >> 1;
  const int sc0 = (tid & 1) * 2;
  const int sw = (srow >> 1) & 3;
  const float delta = 5.0f / 63.0f;
  const float coeff = -0.5f / (delta * delta);
  const float dv = (bm + srow < Mloc) ? dij[base + bm + srow] : 1e9f;
  f32x4 acc[4][4] = {};
  for (int k0 = 0; k0 < 64; k0 += 32) {
    {
      f16x8 c0, c1;
      #pragma unroll
      for (int u = 0; u < 8; ++u) {
        float u0 = dv - delta * (float)(k0 + sc0 * 8 + u);
        float u1 = dv - delta * (float)(k0 + sc0 * 8 + 8 + u);
        c0[u] = (f16)expf(coeff * u0 * u0);
        c1[u] = (f16)expf(coeff * u1 * u1);
      }
      *(f16x8*)&As[srow * 32 + ((sc0 ^ sw) << 3)]       = c0;
      *(f16x8*)&As[srow * 32 + (((sc0 + 1) ^ sw) << 3)] = c1;
    }
    {
      const f16* bp = Wt + (size_t)(bn + srow) * 64 + k0 + sc0 * 8;
      f16x8 b0 = *(const f16x8*)bp;
      f16x8 b1 = *(const f16x8*)(bp + 8);
      *(f16x8*)&Bs[srow * 32 + ((sc0 ^ sw) << 3)]       = b0;
      *(f16x8*)&Bs[srow * 32 + (((sc0 + 1) ^ sw) << 3)] = b1;
    }
    __syncthreads();
    f16x8 af[4], bf[4];
    #pragma unroll
    for (int mt = 0; mt < 4; ++mt) {
      int r = wm + mt * 16 + lr;
      af[mt] = *(const f16x8*)&As[r * 32 + ((lk ^ ((r >> 1) & 3)) << 3)];
    }
    #pragma unroll
    for (int nt = 0; nt < 4; ++nt) {
      int r = wn + nt * 16 + lr;
      bf[nt] = *(const f16x8*)&Bs[r * 32 + ((lk ^ ((r >> 1) & 3)) << 3)];
    }
    #pragma unroll
    for (int mt = 0; mt < 4; ++mt)
      #pragma unroll
      for (int nt = 0; nt < 4; ++nt)
        acc[mt][nt] = __builtin_amdgcn_mfma_f32_16x16x32_f16(af[mt], bf[nt], acc[mt][nt], 0, 0, 0);
    __syncthreads();
  }
  #pragma unroll
  for (int mt = 0; mt < 4; ++mt) {
    int gm0 = bm + wm + mt * 16 + lk * 4;
    #pragma unroll
    for (int nt = 0; nt < 4; ++nt) {
      int gn = bn + wn + nt * 16 + lr;
      float bv = bias[gn];
      #pragma unroll
      for (int rr = 0; rr < 4; ++rr) {
        int gm = gm0 + rr;
        if (gm >= Mloc) continue;
        float v = (acc[mt][nt][rr] + bv) * fcut[base + gm];
        v = fminf(fmaxf(v, -5.0f), 5.0f);
        C[(size_t)gm * 384 + gn] = (f16)v;
      }
    }
  }
}

// ---------------- per-node edge reduction (message passing, f16 operands) ----------------
__global__ __launch_bounds__(128) void k_edge_msg(
    const int* __restrict__ rs, const int* __restrict__ jperm,
    const f16* __restrict__ x, const f16* __restrict__ filt,
    const float* __restrict__ dirp, const f16* __restrict__ mu_in,
    float* __restrict__ q, f16* __restrict__ mu_out, int n0) {
  int i = n0 + blockIdx.x;
  int d = threadIdx.x;
  int base = rs[n0];
  float accq = 0.f, am0 = 0.f, am1 = 0.f, am2 = 0.f;
  int s = rs[i], e_end = rs[i+1];
  for (int p = s; p < e_end; ++p) {
    int j = jperm[p];
    const f16* fe = filt + (size_t)(p - base) * 384;
    float W0 = (float)fe[d];
    float W1 = (float)fe[128 + d];
    float W2 = (float)fe[256 + d];
    const f16* xj = x + (size_t)j * 384;
    float x0 = (float)xj[d], x1 = (float)xj[128 + d], x2 = (float)xj[256 + d];
    float dx = dirp[p*3+0], dy = dirp[p*3+1], dz = dirp[p*3+2];
    const f16* mj = mu_in + (size_t)j * 384;
    float m1 = x1 * W1, m2 = x2 * W2;
    accq = fmaf(x0, W0, accq);
    am0 += m1 * dx + m2 * (float)mj[d];
    am1 += m1 * dy + m2 * (float)mj[128 + d];
    am2 += m1 * dz + m2 * (float)mj[256 + d];
  }
  size_t qi = (size_t)i * 128 + d;
  q[qi] = q[qi] + accq;
  size_t mi = (size_t)i * 384;
  mu_out[mi + d]       = (f16)((float)mu_in[mi + d]       + am0);
  mu_out[mi + 128 + d] = (f16)((float)mu_in[mi + 128 + d] + am1);
  mu_out[mi + 256 + d] = (f16)((float)mu_in[mi + 256 + d] + am2);
}

// ---------------- mix-phase elementwise kernels ----------------
// mumix layout: [N][3][256], per (n,dir): cols 0-127 = V, 128-255 = W
__global__ void k_ctx(const f16* __restrict__ mumix, const float* __restrict__ q,
                      f16* __restrict__ ctx, float* __restrict__ svw) {
  int t = blockIdx.x * 256 + threadIdx.x;
  if (t >= N_NODES * 128) return;
  int n = t >> 7, d = t & 127;
  const f16* mm = mumix + (size_t)n * 768;
  float v0 = (float)mm[d],       w0 = (float)mm[128 + d];
  float v1 = (float)mm[256 + d], w1 = (float)mm[384 + d];
  float v2 = (float)mm[512 + d], w2 = (float)mm[640 + d];
  float vn = sqrtf(v0*v0 + v1*v1 + v2*v2 + 1e-8f);
  float s  = v0*w0 + v1*w1 + v2*w2;
  ctx[(size_t)n * 256 + d]       = (f16)q[t];
  ctx[(size_t)n * 256 + 128 + d] = (f16)vn;
  svw[t] = s;
}

__global__ void k_mixupd(const f16* __restrict__ xm, const f16* __restrict__ mumix,
                         const float* __restrict__ svw, float* __restrict__ q,
                         f16* __restrict__ mu) {
  int t = blockIdx.x * 256 + threadIdx.x;
  if (t >= N_NODES * 128) return;
  int n = t >> 7, d = t & 127;
  const f16* xr = xm + (size_t)n * 384;
  float dq = (float)xr[d], dmu = (float)xr[128 + d], dqmu = (float)xr[256 + d];
  q[t] += dq + dqmu * svw[t];
  const f16* mm = mumix + (size_t)n * 768;
  f16* mr = mu + (size_t)n * 384;
  mr[d]       = (f16)((float)mr[d]       + dmu * (float)mm[128 + d]);
  mr[128 + d] = (f16)((float)mr[128 + d] + dmu * (float)mm[384 + d]);
  mr[256 + d] = (f16)((float)mr[256 + d] + dmu * (float)mm[640 + d]);
}

// ---------------- final outputs ----------------
__global__ __launch_bounds__(128) void k_posattr(
    const int* __restrict__ rs, const int* __restrict__ jperm,
    const f16* __restrict__ mu, const float* __restrict__ w, float* __restrict__ pos_out) {
  __shared__ float red[3][128];
  int i = blockIdx.x, d = threadIdx.x;
  float a0 = 0.f, a1 = 0.f, a2 = 0.f;
  int s = rs[i], e_end = rs[i+1];
  for (int p = s; p < e_end; ++p) {
    int j = jperm[p];
    const f16* mj = mu + (size_t)j * 384;
    a0 += (float)mj[d]; a1 += (float)mj[128 + d]; a2 += (float)mj[256 + d];
  }
  a0 = fminf(fmaxf(a0, -5.f), 5.f);
  a1 = fminf(fmaxf(a1, -5.f), 5.f);
  a2 = fminf(fmaxf(a2, -5.f), 5.f);
  float wd = w[d];
  red[0][d] = a0 * wd; red[1][d] = a1 * wd; red[2][d] = a2 * wd;
  __syncthreads();
  for (int off = 64; off > 0; off >>= 1) {
    if (d < off) {
      red[0][d] += red[0][d+off];
      red[1][d] += red[1][d+off];
      red[2][d] += red[2][d+off];
    }
    __syncthreads();
  }
  if (d < 3) {
    float v = red[d][0];
    pos_out[(size_t)i * 3 + d] = fminf(fmaxf(v, -5.f), 5.f);
  }
}

__global__ __launch_bounds__(128) void k_ln(const float* __restrict__ q, const float* __restrict__ g,
                                            const float* __restrict__ b, float* __restrict__ out) {
  __shared__ float s1[128], s2[128];
  int n = blockIdx.x, d = threadIdx.x;
  float v = q[(size_t)n * 128 + d];
  v = fminf(fmaxf(v, -5.f), 5.f);
  s1[d] = v; s2[d] = v * v;
  __syncthreads();
  for (int off = 64; off > 0; off >>= 1) {
    if (d < off) { s1[d] += s1[d+off]; s2[d] += s2[d+off]; }
    __syncthreads();
  }
  float mean = s1[0] * (1.0f / 128.0f);
  float var  = s2[0] * (1.0f / 128.0f) - mean * mean;
  float y = (v - mean) * rsqrtf(var + 1e-5f) * g[d] + b[d];
  out[(size_t)n * 128 + d] = tanhf(y);
}

extern "C" void kernel_launch(void* const* d_in, const int* in_sizes, int n_in,
                              void* d_out, int out_size, void* d_ws, size_t ws_size,
                              hipStream_t stream) {
  const float* z         = (const float*)d_in[0];
  const float* pos       = (const float*)d_in[1];
  const int*   edge_idx  = (const int*)d_in[2];
  const float* in_w      = (const float*)d_in[3];
  const float* in_b      = (const float*)d_in[4];
  const float* filt_w    = (const float*)d_in[5];
  const float* filt_b    = (const float*)d_in[6];
  const float* inter_w1  = (const float*)d_in[7];
  const float* inter_b1  = (const float*)d_in[8];
  const float* inter_w2  = (const float*)d_in[9];
  const float* inter_b2  = (const float*)d_in[10];
  const float* mix_mu_w  = (const float*)d_in[11];
  const float* mix_w1    = (const float*)d_in[12];
  const float* mix_b1    = (const float*)d_in[13];
  const float* mix_w2    = (const float*)d_in[14];
  const float* mix_b2    = (const float*)d_in[15];
  const float* mu_proj_w = (const float*)d_in[16];
  const float* ln_g      = (const float*)d_in[17];
  const float* ln_b      = (const float*)d_in[18];

  char* base = (char*)d_ws;
  size_t off = 0;
  auto alloc = [&](size_t bytes) -> char* {
    char* p = base + off;
    off += (bytes + 255) & ~(size_t)255;
    return p;
  };
  float* q     = (float*)alloc((size_t)N_NODES * 128 * 4);
  float* svw   = (float*)alloc((size_t)N_NODES * 128 * 4);
  f16*   h     = (f16*)alloc((size_t)N_NODES * 128 * 2);
  f16*   x16   = (f16*)alloc((size_t)N_NODES * 384 * 2);   // x / xm
  f16*   mu_a  = (f16*)alloc((size_t)N_NODES * 384 * 2);
  f16*   mu_b  = (f16*)alloc((size_t)N_NODES * 384 * 2);
  f16*   mumix = (f16*)alloc((size_t)N_NODES * 768 * 2);
  f16*   ctx   = (f16*)alloc((size_t)N_NODES * 256 * 2);
  float* dirp  = (float*)alloc((size_t)N_EDGES * 3 * 4);
  float* dij   = (float*)alloc((size_t)N_EDGES * 4);
  float* fcut  = (float*)alloc((size_t)N_EDGES * 4);
  int*   cnt   = (int*)alloc((size_t)N_NODES * 4);
  int*   incl  = (int*)alloc((size_t)N_NODES * 4);
  int*   bsum  = (int*)alloc(128 * 4);
  int*   rs    = (int*)alloc((size_t)(N_NODES + 1) * 4);
  int*   cur   = (int*)alloc((size_t)N_NODES * 4);
  int*   eidx  = (int*)alloc((size_t)N_EDGES * 4);
  int*   jperm = (int*)alloc((size_t)N_EDGES * 4);
  // f16 transposed weights
  f16* wt_in = (f16*)alloc((size_t)128 * 64 * 2);
  f16* wt_f  = (f16*)alloc((size_t)384 * 64 * 2);
  f16* wt_i1 = (f16*)alloc((size_t)3 * 128 * 128 * 2);
  f16* wt_i2 = (f16*)alloc((size_t)3 * 384 * 128 * 2);
  f16* wt_mu = (f16*)alloc((size_t)3 * 256 * 128 * 2);
  f16* wt_x1 = (f16*)alloc((size_t)3 * 128 * 256 * 2);
  f16* wt_x2 = (f16*)alloc((size_t)3 * 384 * 128 * 2);

  if (off > ws_size) return;
  size_t avail = ws_size - off;
  const size_t filt_full = (size_t)N_EDGES * 384 * 2;

  bool pre = (avail >= filt_full);
  int nchunk = 1, npc = N_NODES;
  size_t cap = N_EDGES;
  if (!pre) {
    bool found = false;
    for (int k = 2; k <= 100; ++k) {
      npc = (N_NODES + k - 1) / k;
      double mean_e = (double)N_EDGES * npc / N_NODES;
      cap = (size_t)(mean_e * 1.35) + 4096;
      if (cap * 768 <= avail) { nchunk = k; found = true; break; }
    }
    if (!found) return;
  }
  f16* filt = (f16*)alloc(cap * 384 * 2);
  if (off > ws_size) return;

  float* out_node = (float*)d_out;
  float* out_pos  = (float*)d_out + (size_t)N_NODES * 128;

  // ---- weight prep (f16, [N][K]) ----
  {
    WJobs jb;
    int ji = 0;
    jb.j[ji++] = {in_w,   wt_in, 6, 128, 0, 128 * 64};
    jb.j[ji++] = {filt_w, wt_f,  6, 384, 0, 384 * 64};
    for (int l = 0; l < 3; ++l)
      jb.j[ji++] = {inter_w1 + (size_t)l*128*128, wt_i1 + (size_t)l*128*128, 7, 128, 0, 128*128};
    for (int l = 0; l < 3; ++l)
      jb.j[ji++] = {inter_w2 + (size_t)l*128*384, wt_i2 + (size_t)l*384*128, 7, 384, 0, 384*128};
    for (int l = 0; l < 3; ++l)
      jb.j[ji++] = {mix_mu_w + (size_t)l*128*256, wt_mu + (size_t)l*256*128, 7, 256, 0, 256*128};
    for (int l = 0; l < 3; ++l)
      jb.j[ji++] = {mix_w1 + (size_t)l*256*128, wt_x1 + (size_t)l*128*256, 8, 128, 0, 128*256};
    for (int l = 0; l < 3; ++l)
      jb.j[ji++] = {mix_w2 + (size_t)l*128*384, wt_x2 + (size_t)l*384*128, 7, 384, 0, 384*128};
    dim3 g(192, 17);
    k_wt_all<<<g, 256, 0, stream>>>(jb);
  }

  // ---- CSR build ----
  hipMemsetAsync(cnt, 0, (size_t)N_NODES * 4, stream);
  k_hist<<<N_EDGES / 256, 256, 0, stream>>>(edge_idx, cnt);
  k_scan_blk<<<NB_SCAN, 256, 0, stream>>>(cnt, incl, bsum);
  k_scan_top<<<1, 128, 0, stream>>>(bsum);
  k_scan_add<<<NB_SCAN, 256, 0, stream>>>(cnt, incl, bsum, rs);
  hipMemcpyAsync(cur, rs, (size_t)N_NODES * 4, hipMemcpyDeviceToDevice, stream);
  k_fill<<<N_EDGES / 256, 256, 0, stream>>>(edge_idx, cur, eidx);

  // ---- edge geometry (CSR-permuted) ----
  k_edge_geom<<<N_EDGES / 256, 256, 0, stream>>>(pos, edge_idx, eidx, dirp, dij, fcut, jperm);

  // ---- filters (tier A: once for all edges) ----
  if (pre) {
    dim3 g((N_EDGES + 127) / 128, 3);
    k_mfilt<<<g, 256, 0, stream>>>(dij, fcut, wt_f, filt_b, filt, rs, 0, N_NODES);
  }

  // ---- input embedding ----
  dim3 ge((N_NODES + 127) / 128, 1);
  dim3 gx((N_NODES + 127) / 128, 3);
  dim3 gv((N_NODES * 3 + 127) / 128, 2);
  k_mgemm<1, float, float><<<ge, 256, 0, stream>>>(z, wt_in, in_b, q, N_NODES, 64, 128);
  hipMemsetAsync(mu_a, 0, (size_t)N_NODES * 384 * 2, stream);

  f16* mu_cur = mu_a;
  f16* mu_nxt = mu_b;
  for (int l = 0; l < NLAYER; ++l) {
    k_mgemm<1, float, f16><<<ge, 256, 0, stream>>>(q, wt_i1 + (size_t)l*128*128,
                                                   inter_b1 + (size_t)l*128, h, N_NODES, 128, 128);
    k_mgemm<0, f16, f16><<<gx, 256, 0, stream>>>(h, wt_i2 + (size_t)l*384*128,
                                                 inter_b2 + (size_t)l*384, x16, N_NODES, 128, 384);
    if (pre) {
      k_edge_msg<<<N_NODES, 128, 0, stream>>>(rs, jperm, x16, filt, dirp, mu_cur, q, mu_nxt, 0);
    } else {
      for (int c = 0; c < nchunk; ++c) {
        int n0 = c * npc;
        int n1 = n0 + npc; if (n1 > N_NODES) n1 = N_NODES;
        if (n0 >= n1) break;
        dim3 g(((int)cap + 127) / 128, 3);
        k_mfilt<<<g, 256, 0, stream>>>(dij, fcut, wt_f, filt_b, filt, rs, n0, n1);
        k_edge_msg<<<n1 - n0, 128, 0, stream>>>(rs, jperm, x16, filt, dirp, mu_cur, q, mu_nxt, n0);
      }
    }
    { f16* t = mu_cur; mu_cur = mu_nxt; mu_nxt = t; }
    // mumix: [3N][128] @ [256][128]^T -> [3N][256] (V cols 0-127, W cols 128-255)
    k_mgemm<0, f16, f16><<<gv, 256, 0, stream>>>(mu_cur, wt_mu + (size_t)l*256*128, nullptr,
                                                 mumix, N_NODES * 3, 128, 256);
    k_ctx<<<(N_NODES * 128) / 256, 256, 0, stream>>>(mumix, q, ctx, svw);
    k_mgemm<1, f16, f16><<<ge, 256, 0, stream>>>(ctx, wt_x1 + (size_t)l*128*256,
                                                 mix_b1 + (size_t)l*128, h, N_NODES, 256, 128);
    k_mgemm<0, f16, f16><<<gx, 256, 0, stream>>>(h, wt_x2 + (size_t)l*384*128,
                                                 mix_b2 + (size_t)l*384, x16, N_NODES, 128, 384);
    k_mixupd<<<(N_NODES * 128) / 256, 256, 0, stream>>>(x16, mumix, svw, q, mu_cur);
  }

  // ---- outputs ----
  k_posattr<<<N_NODES, 128, 0, stream>>>(rs, jperm, mu_cur, mu_proj_w, out_pos);
  k_ln<<<N_NODES, 128, 0, stream>>>(q, ln_g, ln_b, out_node);
}

// Round 5
// 832.321 us; speedup vs baseline: 2.9894x; 1.7001x over previous
//
#include <hip/hip_runtime.h>
#include <math.h>

#ifndef M_PI
#define M_PI 3.14159265358979323846
#endif

static constexpr int N_NODES = 20000;
static constexpr int N_EDGES = 320000;
static constexpr int NLAYER  = 3;
static constexpr int NB_SCAN = (N_NODES + 255) / 256;  // 79
static constexpr int TAB_T   = 4096;                   // filter lookup rows

typedef _Float16 f16;
typedef __attribute__((ext_vector_type(8))) _Float16 f16x8;
typedef __attribute__((ext_vector_type(4))) float f32x4;

__device__ __forceinline__ void storev(float* p, float v) { *p = v; }
__device__ __forceinline__ void storev(f16* p, float v)   { *p = (f16)v; }

// ---------------- CSR build ----------------
__global__ void k_hist(const int* __restrict__ idx_i, int* __restrict__ cnt) {
  int e = blockIdx.x * 256 + threadIdx.x;
  if (e < N_EDGES) atomicAdd(&cnt[idx_i[e]], 1);
}

__global__ void k_scan_blk(const int* __restrict__ cnt, int* __restrict__ incl,
                           int* __restrict__ bsum) {
  __shared__ int buf[256];
  int t = threadIdx.x;
  int i = blockIdx.x * 256 + t;
  int v = (i < N_NODES) ? cnt[i] : 0;
  buf[t] = v;
  __syncthreads();
  #pragma unroll
  for (int off = 1; off < 256; off <<= 1) {
    int x = (t >= off) ? buf[t - off] : 0;
    __syncthreads();
    buf[t] += x;
    __syncthreads();
  }
  if (i < N_NODES) incl[i] = buf[t];
  if (t == 255) bsum[blockIdx.x] = buf[255];
}

__global__ void k_scan_top(int* __restrict__ bsum) {
  __shared__ int buf[128];
  int t = threadIdx.x;
  int v = (t < NB_SCAN) ? bsum[t] : 0;
  buf[t] = v;
  __syncthreads();
  #pragma unroll
  for (int off = 1; off < 128; off <<= 1) {
    int x = (t >= off) ? buf[t - off] : 0;
    __syncthreads();
    buf[t] += x;
    __syncthreads();
  }
  if (t <= NB_SCAN) bsum[t] = buf[t] - v;  // exclusive; t==NB_SCAN -> total
}

__global__ void k_scan_add(const int* __restrict__ cnt, const int* __restrict__ incl,
                           const int* __restrict__ bsum, int* __restrict__ rs) {
  int i = blockIdx.x * 256 + threadIdx.x;
  if (i < N_NODES) rs[i] = bsum[blockIdx.x] + incl[i] - cnt[i];
  if (i == 0) rs[N_NODES] = bsum[NB_SCAN];
}

__global__ void k_fill(const int* __restrict__ idx_i, int* __restrict__ cur, int* __restrict__ eidx) {
  int e = blockIdx.x * 256 + threadIdx.x;
  if (e < N_EDGES) {
    int p = atomicAdd(&cur[idx_i[e]], 1);
    eidx[p] = e;
  }
}

// ---------------- edge geometry, CSR-permuted outputs ----------------
__global__ void k_edge_geom(const float* __restrict__ pos, const int* __restrict__ idx_all,
                            const int* __restrict__ eidx, float* __restrict__ dirp,
                            float* __restrict__ dij, int* __restrict__ jperm) {
  int p = blockIdx.x * 256 + threadIdx.x;
  if (p >= N_EDGES) return;
  int e = eidx[p];
  int i = idx_all[e];
  int j = idx_all[N_EDGES + e];
  float rx = pos[j*3+0] - pos[i*3+0];
  float ry = pos[j*3+1] - pos[i*3+1];
  float rz = pos[j*3+2] - pos[i*3+2];
  float d = sqrtf(rx*rx + ry*ry + rz*rz);
  d = fmaxf(d, 1e-8f);
  float inv = 1.0f / d;
  dirp[p*3+0] = rx*inv; dirp[p*3+1] = ry*inv; dirp[p*3+2] = rz*inv;
  dij[p] = d;
  jperm[p] = j;
}

// ---------------- weight transpose+convert: Wt[n][k] = (f16)src[k][col0+n] ----------------
struct WJob { const float* src; f16* dst; int kshift; int ld; int col0; int nk; };
struct WJobs { WJob j[17]; };

__global__ void k_wt_all(WJobs jb) {
  WJob w = jb.j[blockIdx.y];
  int t = blockIdx.x * 256 + threadIdx.x;
  if (t >= w.nk) return;
  int K = 1 << w.kshift;
  int n = t >> w.kshift;
  int k = t & (K - 1);
  w.dst[t] = (f16)w.src[(size_t)k * w.ld + w.col0 + n];
}

// ---------------- filter lookup table: tab[t][n], t over d in [0,5] ----------------
// tab[t][n] = clip((sum_k phi_k(d_t) * fw[k][n] + b[n]) * fcut(d_t), -5, 5)
__global__ __launch_bounds__(128) void k_tab(const f16* __restrict__ wt_f /*[384][64]*/,
                                             const float* __restrict__ bias,
                                             f16* __restrict__ tab) {
  __shared__ float ph[64];
  const int t = blockIdx.x;
  const float dist = 5.0f * (float)t / (float)(TAB_T - 1);
  const int tid = threadIdx.x;
  const float delta = 5.0f / 63.0f;
  const float coeff = -0.5f / (delta * delta);
  if (tid < 64) {
    float u = dist - delta * (float)tid;
    ph[tid] = expf(coeff * u * u);
  }
  __syncthreads();
  float xc = dist * 0.2f;
  float fc = (xc < 1.0f) ? 0.5f * (cosf((float)M_PI * xc) + 1.0f) : 0.0f;
  #pragma unroll
  for (int s = 0; s < 3; ++s) {
    int n = tid + s * 128;
    const f16* wr = wt_f + (size_t)n * 64;
    float acc = 0.f;
    #pragma unroll
    for (int k = 0; k < 64; ++k) acc += ph[k] * (float)wr[k];
    float v = (acc + bias[n]) * fc;
    v = fminf(fmaxf(v, -5.0f), 5.0f);
    tab[(size_t)t * 384 + n] = (f16)v;
  }
}

// ---------------- MFMA f16 GEMM: C[M x *] = epi(A[M x K] @ Wt[N][K]^T + bias) ----------------
template<int EPI, typename AT, typename CT>
__global__ __launch_bounds__(256) void k_mgemm(
    const AT* __restrict__ A, const f16* __restrict__ Wt,
    const float* __restrict__ bias, CT* __restrict__ C,
    int M, int K, int ldc) {
  __shared__ f16 As[128 * 32];
  __shared__ f16 Bs[128 * 32];
  const int bm = blockIdx.x * 128;
  const int bn = blockIdx.y * 128;
  const int tid = threadIdx.x;
  const int wave = tid >> 6, lane = tid & 63;
  const int wm = (wave & 1) * 64, wn = (wave >> 1) * 64;
  const int lr = lane & 15;
  const int lk = lane >> 4;
  const int srow = tid >> 1;
  const int sc0 = (tid & 1) * 2;
  const int sw = (srow >> 1) & 3;
  f32x4 acc[4][4] = {};
  for (int k0 = 0; k0 < K; k0 += 32) {
    // stage A
    {
      int gm = bm + srow;
      f16x8 c0, c1;
      if (gm < M) {
        if constexpr (sizeof(AT) == 2) {
          const f16* ap = (const f16*)A + (size_t)gm * K + k0 + sc0 * 8;
          c0 = *(const f16x8*)ap;
          c1 = *(const f16x8*)(ap + 8);
        } else {
          const float* ap = (const float*)A + (size_t)gm * K + k0 + sc0 * 8;
          float4 v0 = ((const float4*)ap)[0];
          float4 v1 = ((const float4*)ap)[1];
          float4 v2 = ((const float4*)ap)[2];
          float4 v3 = ((const float4*)ap)[3];
          c0[0]=(f16)v0.x; c0[1]=(f16)v0.y; c0[2]=(f16)v0.z; c0[3]=(f16)v0.w;
          c0[4]=(f16)v1.x; c0[5]=(f16)v1.y; c0[6]=(f16)v1.z; c0[7]=(f16)v1.w;
          c1[0]=(f16)v2.x; c1[1]=(f16)v2.y; c1[2]=(f16)v2.z; c1[3]=(f16)v2.w;
          c1[4]=(f16)v3.x; c1[5]=(f16)v3.y; c1[6]=(f16)v3.z; c1[7]=(f16)v3.w;
        }
      } else {
        #pragma unroll
        for (int u = 0; u < 8; ++u) { c0[u] = (f16)0.f; c1[u] = (f16)0.f; }
      }
      *(f16x8*)&As[srow * 32 + ((sc0 ^ sw) << 3)]       = c0;
      *(f16x8*)&As[srow * 32 + (((sc0 + 1) ^ sw) << 3)] = c1;
    }
    // stage B
    {
      const f16* bp = Wt + (size_t)(bn + srow) * K + k0 + sc0 * 8;
      f16x8 b0 = *(const f16x8*)bp;
      f16x8 b1 = *(const f16x8*)(bp + 8);
      *(f16x8*)&Bs[srow * 32 + ((sc0 ^ sw) << 3)]       = b0;
      *(f16x8*)&Bs[srow * 32 + (((sc0 + 1) ^ sw) << 3)] = b1;
    }
    __syncthreads();
    f16x8 af[4], bf[4];
    #pragma unroll
    for (int mt = 0; mt < 4; ++mt) {
      int r = wm + mt * 16 + lr;
      af[mt] = *(const f16x8*)&As[r * 32 + ((lk ^ ((r >> 1) & 3)) << 3)];
    }
    #pragma unroll
    for (int nt = 0; nt < 4; ++nt) {
      int r = wn + nt * 16 + lr;
      bf[nt] = *(const f16x8*)&Bs[r * 32 + ((lk ^ ((r >> 1) & 3)) << 3)];
    }
    #pragma unroll
    for (int mt = 0; mt < 4; ++mt)
      #pragma unroll
      for (int nt = 0; nt < 4; ++nt)
        acc[mt][nt] = __builtin_amdgcn_mfma_f32_16x16x32_f16(af[mt], bf[nt], acc[mt][nt], 0, 0, 0);
    __syncthreads();
  }
  #pragma unroll
  for (int mt = 0; mt < 4; ++mt) {
    int gm0 = bm + wm + mt * 16 + lk * 4;
    #pragma unroll
    for (int nt = 0; nt < 4; ++nt) {
      int gn = bn + wn + nt * 16 + lr;
      float bv = bias ? bias[gn] : 0.0f;
      #pragma unroll
      for (int rr = 0; rr < 4; ++rr) {
        int gm = gm0 + rr;
        if (gm >= M) continue;
        float v = acc[mt][nt][rr] + bv;
        if (EPI == 1) v = v / (1.0f + expf(-v));
        storev(&C[(size_t)gm * ldc + gn], v);
      }
    }
  }
}

// ---------------- per-node edge reduction (message passing, table-lookup filters) ----------------
__global__ __launch_bounds__(128) void k_edge_msg(
    const int* __restrict__ rs, const int* __restrict__ jperm,
    const f16* __restrict__ x, const f16* __restrict__ tab,
    const float* __restrict__ dij, const float* __restrict__ dirp,
    const f16* __restrict__ mu_in, float* __restrict__ q,
    f16* __restrict__ mu_out) {
  const int i = blockIdx.x;
  const int dd = threadIdx.x;
  const float scale = (float)(TAB_T - 1) / 5.0f;
  float accq = 0.f, am0 = 0.f, am1 = 0.f, am2 = 0.f;
  int s = rs[i], e_end = rs[i+1];
  for (int p = s; p < e_end; ++p) {
    int j = jperm[p];
    float u = fminf(dij[p], 5.0f) * scale;
    int t0 = (int)u;
    t0 = min(t0, TAB_T - 2);
    float fr = u - (float)t0;
    float fo = 1.0f - fr;
    const f16* ta = tab + (size_t)t0 * 384;
    const f16* tb = ta + 384;
    float W0 = fo * (float)ta[dd]       + fr * (float)tb[dd];
    float W1 = fo * (float)ta[128 + dd] + fr * (float)tb[128 + dd];
    float W2 = fo * (float)ta[256 + dd] + fr * (float)tb[256 + dd];
    const f16* xj = x + (size_t)j * 384;
    float x0 = (float)xj[dd], x1 = (float)xj[128 + dd], x2 = (float)xj[256 + dd];
    float dx = dirp[p*3+0], dy = dirp[p*3+1], dz = dirp[p*3+2];
    const f16* mj = mu_in + (size_t)j * 384;
    float m1 = x1 * W1, m2 = x2 * W2;
    accq = fmaf(x0, W0, accq);
    am0 += m1 * dx + m2 * (float)mj[dd];
    am1 += m1 * dy + m2 * (float)mj[128 + dd];
    am2 += m1 * dz + m2 * (float)mj[256 + dd];
  }
  size_t qi = (size_t)i * 128 + dd;
  q[qi] = q[qi] + accq;
  size_t mi = (size_t)i * 384;
  mu_out[mi + dd]       = (f16)((float)mu_in[mi + dd]       + am0);
  mu_out[mi + 128 + dd] = (f16)((float)mu_in[mi + 128 + dd] + am1);
  mu_out[mi + 256 + dd] = (f16)((float)mu_in[mi + 256 + dd] + am2);
}

// ---------------- mix-phase elementwise kernels ----------------
// mumix layout: [N][3][256], per (n,dir): cols 0-127 = V, 128-255 = W
__global__ void k_ctx(const f16* __restrict__ mumix, const float* __restrict__ q,
                      f16* __restrict__ ctx, float* __restrict__ svw) {
  int t = blockIdx.x * 256 + threadIdx.x;
  if (t >= N_NODES * 128) return;
  int n = t >> 7, d = t & 127;
  const f16* mm = mumix + (size_t)n * 768;
  float v0 = (float)mm[d],       w0 = (float)mm[128 + d];
  float v1 = (float)mm[256 + d], w1 = (float)mm[384 + d];
  float v2 = (float)mm[512 + d], w2 = (float)mm[640 + d];
  float vn = sqrtf(v0*v0 + v1*v1 + v2*v2 + 1e-8f);
  float s  = v0*w0 + v1*w1 + v2*w2;
  ctx[(size_t)n * 256 + d]       = (f16)q[t];
  ctx[(size_t)n * 256 + 128 + d] = (f16)vn;
  svw[t] = s;
}

__global__ void k_mixupd(const f16* __restrict__ xm, const f16* __restrict__ mumix,
                         const float* __restrict__ svw, float* __restrict__ q,
                         f16* __restrict__ mu) {
  int t = blockIdx.x * 256 + threadIdx.x;
  if (t >= N_NODES * 128) return;
  int n = t >> 7, d = t & 127;
  const f16* xr = xm + (size_t)n * 384;
  float dq = (float)xr[d], dmu = (float)xr[128 + d], dqmu = (float)xr[256 + d];
  q[t] += dq + dqmu * svw[t];
  const f16* mm = mumix + (size_t)n * 768;
  f16* mr = mu + (size_t)n * 384;
  mr[d]       = (f16)((float)mr[d]       + dmu * (float)mm[128 + d]);
  mr[128 + d] = (f16)((float)mr[128 + d] + dmu * (float)mm[384 + d]);
  mr[256 + d] = (f16)((float)mr[256 + d] + dmu * (float)mm[640 + d]);
}

// ---------------- final outputs ----------------
__global__ __launch_bounds__(128) void k_posattr(
    const int* __restrict__ rs, const int* __restrict__ jperm,
    const f16* __restrict__ mu, const float* __restrict__ w, float* __restrict__ pos_out) {
  __shared__ float red[3][128];
  int i = blockIdx.x, d = threadIdx.x;
  float a0 = 0.f, a1 = 0.f, a2 = 0.f;
  int s = rs[i], e_end = rs[i+1];
  for (int p = s; p < e_end; ++p) {
    int j = jperm[p];
    const f16* mj = mu + (size_t)j * 384;
    a0 += (float)mj[d]; a1 += (float)mj[128 + d]; a2 += (float)mj[256 + d];
  }
  a0 = fminf(fmaxf(a0, -5.f), 5.f);
  a1 = fminf(fmaxf(a1, -5.f), 5.f);
  a2 = fminf(fmaxf(a2, -5.f), 5.f);
  float wd = w[d];
  red[0][d] = a0 * wd; red[1][d] = a1 * wd; red[2][d] = a2 * wd;
  __syncthreads();
  for (int off = 64; off > 0; off >>= 1) {
    if (d < off) {
      red[0][d] += red[0][d+off];
      red[1][d] += red[1][d+off];
      red[2][d] += red[2][d+off];
    }
    __syncthreads();
  }
  if (d < 3) {
    float v = red[d][0];
    pos_out[(size_t)i * 3 + d] = fminf(fmaxf(v, -5.f), 5.f);
  }
}

__global__ __launch_bounds__(128) void k_ln(const float* __restrict__ q, const float* __restrict__ g,
                                            const float* __restrict__ b, float* __restrict__ out) {
  __shared__ float s1[128], s2[128];
  int n = blockIdx.x, d = threadIdx.x;
  float v = q[(size_t)n * 128 + d];
  v = fminf(fmaxf(v, -5.f), 5.f);
  s1[d] = v; s2[d] = v * v;
  __syncthreads();
  for (int off = 64; off > 0; off >>= 1) {
    if (d < off) { s1[d] += s1[d+off]; s2[d] += s2[d+off]; }
    __syncthreads();
  }
  float mean = s1[0] * (1.0f / 128.0f);
  float var  = s2[0] * (1.0f / 128.0f) - mean * mean;
  float y = (v - mean) * rsqrtf(var + 1e-5f) * g[d] + b[d];
  out[(size_t)n * 128 + d] = tanhf(y);
}

extern "C" void kernel_launch(void* const* d_in, const int* in_sizes, int n_in,
                              void* d_out, int out_size, void* d_ws, size_t ws_size,
                              hipStream_t stream) {
  const float* z         = (const float*)d_in[0];
  const float* pos       = (const float*)d_in[1];
  const int*   edge_idx  = (const int*)d_in[2];
  const float* in_w      = (const float*)d_in[3];
  const float* in_b      = (const float*)d_in[4];
  const float* filt_w    = (const float*)d_in[5];
  const float* filt_b    = (const float*)d_in[6];
  const float* inter_w1  = (const float*)d_in[7];
  const float* inter_b1  = (const float*)d_in[8];
  const float* inter_w2  = (const float*)d_in[9];
  const float* inter_b2  = (const float*)d_in[10];
  const float* mix_mu_w  = (const float*)d_in[11];
  const float* mix_w1    = (const float*)d_in[12];
  const float* mix_b1    = (const float*)d_in[13];
  const float* mix_w2    = (const float*)d_in[14];
  const float* mix_b2    = (const float*)d_in[15];
  const float* mu_proj_w = (const float*)d_in[16];
  const float* ln_g      = (const float*)d_in[17];
  const float* ln_b      = (const float*)d_in[18];

  char* base = (char*)d_ws;
  size_t off = 0;
  auto alloc = [&](size_t bytes) -> char* {
    char* p = base + off;
    off += (bytes + 255) & ~(size_t)255;
    return p;
  };
  float* q     = (float*)alloc((size_t)N_NODES * 128 * 4);
  float* svw   = (float*)alloc((size_t)N_NODES * 128 * 4);
  f16*   h     = (f16*)alloc((size_t)N_NODES * 128 * 2);
  f16*   x16   = (f16*)alloc((size_t)N_NODES * 384 * 2);   // x / xm
  f16*   mu_a  = (f16*)alloc((size_t)N_NODES * 384 * 2);
  f16*   mu_b  = (f16*)alloc((size_t)N_NODES * 384 * 2);
  f16*   mumix = (f16*)alloc((size_t)N_NODES * 768 * 2);
  f16*   ctx   = (f16*)alloc((size_t)N_NODES * 256 * 2);
  float* dirp  = (float*)alloc((size_t)N_EDGES * 3 * 4);
  float* dij   = (float*)alloc((size_t)N_EDGES * 4);
  int*   cnt   = (int*)alloc((size_t)N_NODES * 4);
  int*   incl  = (int*)alloc((size_t)N_NODES * 4);
  int*   bsum  = (int*)alloc(128 * 4);
  int*   rs    = (int*)alloc((size_t)(N_NODES + 1) * 4);
  int*   cur   = (int*)alloc((size_t)N_NODES * 4);
  int*   eidx  = (int*)alloc((size_t)N_EDGES * 4);
  int*   jperm = (int*)alloc((size_t)N_EDGES * 4);
  f16*   tab   = (f16*)alloc((size_t)TAB_T * 384 * 2);
  // f16 transposed weights
  f16* wt_in = (f16*)alloc((size_t)128 * 64 * 2);
  f16* wt_f  = (f16*)alloc((size_t)384 * 64 * 2);
  f16* wt_i1 = (f16*)alloc((size_t)3 * 128 * 128 * 2);
  f16* wt_i2 = (f16*)alloc((size_t)3 * 384 * 128 * 2);
  f16* wt_mu = (f16*)alloc((size_t)3 * 256 * 128 * 2);
  f16* wt_x1 = (f16*)alloc((size_t)3 * 128 * 256 * 2);
  f16* wt_x2 = (f16*)alloc((size_t)3 * 384 * 128 * 2);
  if (off > ws_size) return;

  float* out_node = (float*)d_out;
  float* out_pos  = (float*)d_out + (size_t)N_NODES * 128;

  // ---- weight prep (f16, [N][K]) ----
  {
    WJobs jb;
    int ji = 0;
    jb.j[ji++] = {in_w,   wt_in, 6, 128, 0, 128 * 64};
    jb.j[ji++] = {filt_w, wt_f,  6, 384, 0, 384 * 64};
    for (int l = 0; l < 3; ++l)
      jb.j[ji++] = {inter_w1 + (size_t)l*128*128, wt_i1 + (size_t)l*128*128, 7, 128, 0, 128*128};
    for (int l = 0; l < 3; ++l)
      jb.j[ji++] = {inter_w2 + (size_t)l*128*384, wt_i2 + (size_t)l*384*128, 7, 384, 0, 384*128};
    for (int l = 0; l < 3; ++l)
      jb.j[ji++] = {mix_mu_w + (size_t)l*128*256, wt_mu + (size_t)l*256*128, 7, 256, 0, 256*128};
    for (int l = 0; l < 3; ++l)
      jb.j[ji++] = {mix_w1 + (size_t)l*256*128, wt_x1 + (size_t)l*128*256, 8, 128, 0, 128*256};
    for (int l = 0; l < 3; ++l)
      jb.j[ji++] = {mix_w2 + (size_t)l*128*384, wt_x2 + (size_t)l*384*128, 7, 384, 0, 384*128};
    dim3 g(192, 17);
    k_wt_all<<<g, 256, 0, stream>>>(jb);
  }

  // ---- filter lookup table ----
  k_tab<<<TAB_T, 128, 0, stream>>>(wt_f, filt_b, tab);

  // ---- CSR build ----
  hipMemsetAsync(cnt, 0, (size_t)N_NODES * 4, stream);
  k_hist<<<N_EDGES / 256, 256, 0, stream>>>(edge_idx, cnt);
  k_scan_blk<<<NB_SCAN, 256, 0, stream>>>(cnt, incl, bsum);
  k_scan_top<<<1, 128, 0, stream>>>(bsum);
  k_scan_add<<<NB_SCAN, 256, 0, stream>>>(cnt, incl, bsum, rs);
  hipMemcpyAsync(cur, rs, (size_t)N_NODES * 4, hipMemcpyDeviceToDevice, stream);
  k_fill<<<N_EDGES / 256, 256, 0, stream>>>(edge_idx, cur, eidx);

  // ---- edge geometry (CSR-permuted) ----
  k_edge_geom<<<N_EDGES / 256, 256, 0, stream>>>(pos, edge_idx, eidx, dirp, dij, jperm);

  // ---- input embedding ----
  dim3 ge((N_NODES + 127) / 128, 1);
  dim3 gx((N_NODES + 127) / 128, 3);
  dim3 gv((N_NODES * 3 + 127) / 128, 2);
  k_mgemm<1, float, float><<<ge, 256, 0, stream>>>(z, wt_in, in_b, q, N_NODES, 64, 128);
  hipMemsetAsync(mu_a, 0, (size_t)N_NODES * 384 * 2, stream);

  f16* mu_cur = mu_a;
  f16* mu_nxt = mu_b;
  for (int l = 0; l < NLAYER; ++l) {
    k_mgemm<1, float, f16><<<ge, 256, 0, stream>>>(q, wt_i1 + (size_t)l*128*128,
                                                   inter_b1 + (size_t)l*128, h, N_NODES, 128, 128);
    k_mgemm<0, f16, f16><<<gx, 256, 0, stream>>>(h, wt_i2 + (size_t)l*384*128,
                                                 inter_b2 + (size_t)l*384, x16, N_NODES, 128, 384);
    k_edge_msg<<<N_NODES, 128, 0, stream>>>(rs, jperm, x16, tab, dij, dirp, mu_cur, q, mu_nxt);
    { f16* t = mu_cur; mu_cur = mu_nxt; mu_nxt = t; }
    // mumix: [3N][128] @ [256][128]^T -> [3N][256] (V cols 0-127, W cols 128-255)
    k_mgemm<0, f16, f16><<<gv, 256, 0, stream>>>(mu_cur, wt_mu + (size_t)l*256*128, nullptr,
                                                 mumix, N_NODES * 3, 128, 256);
    k_ctx<<<(N_NODES * 128) / 256, 256, 0, stream>>>(mumix, q, ctx, svw);
    k_mgemm<1, f16, f16><<<ge, 256, 0, stream>>>(ctx, wt_x1 + (size_t)l*128*256,
                                                 mix_b1 + (size_t)l*128, h, N_NODES, 256, 128);
    k_mgemm<0, f16, f16><<<gx, 256, 0, stream>>>(h, wt_x2 + (size_t)l*384*128,
                                                 mix_b2 + (size_t)l*384, x16, N_NODES, 128, 384);
    k_mixupd<<<(N_NODES * 128) / 256, 256, 0, stream>>>(x16, mumix, svw, q, mu_cur);
  }

  // ---- outputs ----
  k_posattr<<<N_NODES, 128, 0, stream>>>(rs, jperm, mu_cur, mu_proj_w, out_pos);
  k_ln<<<N_NODES, 128, 0, stream>>>(q, ln_g, ln_b, out_node);
}

// Round 6
// 828.670 us; speedup vs baseline: 3.0026x; 1.0044x over previous
//
#include <hip/hip_runtime.h>
#include <math.h>

#ifndef M_PI
#define M_PI 3.14159265358979323846
#endif

static constexpr int N_NODES = 20000;
static constexpr int N_EDGES = 320000;
static constexpr int NLAYER  = 3;
static constexpr int NB_SCAN = (N_NODES + 255) / 256;  // 79
static constexpr int TAB_T   = 4096;                   // filter lookup rows

typedef _Float16 f16;
typedef __attribute__((ext_vector_type(2))) _Float16 f16x2;
typedef __attribute__((ext_vector_type(8))) _Float16 f16x8;
typedef __attribute__((ext_vector_type(4))) float f32x4;

__device__ __forceinline__ void storev(float* p, float v) { *p = v; }
__device__ __forceinline__ void storev(f16* p, float v)   { *p = (f16)v; }

// ---------------- CSR build ----------------
__global__ void k_hist(const int* __restrict__ idx_i, int* __restrict__ cnt) {
  int e = blockIdx.x * 256 + threadIdx.x;
  if (e < N_EDGES) atomicAdd(&cnt[idx_i[e]], 1);
}

__global__ void k_scan_blk(const int* __restrict__ cnt, int* __restrict__ incl,
                           int* __restrict__ bsum) {
  __shared__ int buf[256];
  int t = threadIdx.x;
  int i = blockIdx.x * 256 + t;
  int v = (i < N_NODES) ? cnt[i] : 0;
  buf[t] = v;
  __syncthreads();
  #pragma unroll
  for (int off = 1; off < 256; off <<= 1) {
    int x = (t >= off) ? buf[t - off] : 0;
    __syncthreads();
    buf[t] += x;
    __syncthreads();
  }
  if (i < N_NODES) incl[i] = buf[t];
  if (t == 255) bsum[blockIdx.x] = buf[255];
}

__global__ void k_scan_top(int* __restrict__ bsum) {
  __shared__ int buf[128];
  int t = threadIdx.x;
  int v = (t < NB_SCAN) ? bsum[t] : 0;
  buf[t] = v;
  __syncthreads();
  #pragma unroll
  for (int off = 1; off < 128; off <<= 1) {
    int x = (t >= off) ? buf[t - off] : 0;
    __syncthreads();
    buf[t] += x;
    __syncthreads();
  }
  if (t <= NB_SCAN) bsum[t] = buf[t] - v;  // exclusive; t==NB_SCAN -> total
}

__global__ void k_scan_add(const int* __restrict__ cnt, const int* __restrict__ incl,
                           const int* __restrict__ bsum, int* __restrict__ rs) {
  int i = blockIdx.x * 256 + threadIdx.x;
  if (i < N_NODES) rs[i] = bsum[blockIdx.x] + incl[i] - cnt[i];
  if (i == 0) rs[N_NODES] = bsum[NB_SCAN];
}

__global__ void k_fill(const int* __restrict__ idx_i, int* __restrict__ cur, int* __restrict__ eidx) {
  int e = blockIdx.x * 256 + threadIdx.x;
  if (e < N_EDGES) {
    int p = atomicAdd(&cur[idx_i[e]], 1);
    eidx[p] = e;
  }
}

// ---------------- edge geometry, CSR-permuted; geo = {d, dx, dy, dz} ----------------
__global__ void k_edge_geom(const float* __restrict__ pos, const int* __restrict__ idx_all,
                            const int* __restrict__ eidx, float4* __restrict__ geo,
                            int* __restrict__ jperm) {
  int p = blockIdx.x * 256 + threadIdx.x;
  if (p >= N_EDGES) return;
  int e = eidx[p];
  int i = idx_all[e];
  int j = idx_all[N_EDGES + e];
  float rx = pos[j*3+0] - pos[i*3+0];
  float ry = pos[j*3+1] - pos[i*3+1];
  float rz = pos[j*3+2] - pos[i*3+2];
  float d = sqrtf(rx*rx + ry*ry + rz*rz);
  d = fmaxf(d, 1e-8f);
  float inv = 1.0f / d;
  geo[p] = make_float4(d, rx*inv, ry*inv, rz*inv);
  jperm[p] = j;
}

// ---------------- weight transpose+convert: Wt[n][k] = (f16)src[k][col0+n] ----------------
struct WJob { const float* src; f16* dst; int kshift; int ld; int col0; int nk; };
struct WJobs { WJob j[17]; };

__global__ void k_wt_all(WJobs jb) {
  WJob w = jb.j[blockIdx.y];
  int t = blockIdx.x * 256 + threadIdx.x;
  if (t >= w.nk) return;
  int K = 1 << w.kshift;
  int n = t >> w.kshift;
  int k = t & (K - 1);
  w.dst[t] = (f16)w.src[(size_t)k * w.ld + w.col0 + n];
}

// ---------------- filter lookup table: tab[t][n], t over d in [0,5] ----------------
__global__ __launch_bounds__(128) void k_tab(const f16* __restrict__ wt_f /*[384][64]*/,
                                             const float* __restrict__ bias,
                                             f16* __restrict__ tab) {
  __shared__ float ph[64];
  const int t = blockIdx.x;
  const float dist = 5.0f * (float)t / (float)(TAB_T - 1);
  const int tid = threadIdx.x;
  const float delta = 5.0f / 63.0f;
  const float coeff = -0.5f / (delta * delta);
  if (tid < 64) {
    float u = dist - delta * (float)tid;
    ph[tid] = expf(coeff * u * u);
  }
  __syncthreads();
  float xc = dist * 0.2f;
  float fc = (xc < 1.0f) ? 0.5f * (cosf((float)M_PI * xc) + 1.0f) : 0.0f;
  #pragma unroll
  for (int s = 0; s < 3; ++s) {
    int n = tid + s * 128;
    const f16* wr = wt_f + (size_t)n * 64;
    float acc = 0.f;
    #pragma unroll
    for (int k = 0; k < 64; ++k) acc += ph[k] * (float)wr[k];
    float v = (acc + bias[n]) * fc;
    v = fminf(fmaxf(v, -5.0f), 5.0f);
    tab[(size_t)t * 384 + n] = (f16)v;
  }
}

// ---------------- MFMA f16 GEMM: C[M x *] = epi(A[M x K] @ Wt[N][K]^T + bias) ----------------
template<int EPI, typename AT, typename CT>
__global__ __launch_bounds__(256) void k_mgemm(
    const AT* __restrict__ A, const f16* __restrict__ Wt,
    const float* __restrict__ bias, CT* __restrict__ C,
    int M, int K, int ldc) {
  __shared__ f16 As[128 * 32];
  __shared__ f16 Bs[128 * 32];
  const int bm = blockIdx.x * 128;
  const int bn = blockIdx.y * 128;
  const int tid = threadIdx.x;
  const int wave = tid >> 6, lane = tid & 63;
  const int wm = (wave & 1) * 64, wn = (wave >> 1) * 64;
  const int lr = lane & 15;
  const int lk = lane >> 4;
  const int srow = tid >> 1;
  const int sc0 = (tid & 1) * 2;
  const int sw = (srow >> 1) & 3;
  f32x4 acc[4][4] = {};
  for (int k0 = 0; k0 < K; k0 += 32) {
    // stage A
    {
      int gm = bm + srow;
      f16x8 c0, c1;
      if (gm < M) {
        if constexpr (sizeof(AT) == 2) {
          const f16* ap = (const f16*)A + (size_t)gm * K + k0 + sc0 * 8;
          c0 = *(const f16x8*)ap;
          c1 = *(const f16x8*)(ap + 8);
        } else {
          const float* ap = (const float*)A + (size_t)gm * K + k0 + sc0 * 8;
          float4 v0 = ((const float4*)ap)[0];
          float4 v1 = ((const float4*)ap)[1];
          float4 v2 = ((const float4*)ap)[2];
          float4 v3 = ((const float4*)ap)[3];
          c0[0]=(f16)v0.x; c0[1]=(f16)v0.y; c0[2]=(f16)v0.z; c0[3]=(f16)v0.w;
          c0[4]=(f16)v1.x; c0[5]=(f16)v1.y; c0[6]=(f16)v1.z; c0[7]=(f16)v1.w;
          c1[0]=(f16)v2.x; c1[1]=(f16)v2.y; c1[2]=(f16)v2.z; c1[3]=(f16)v2.w;
          c1[4]=(f16)v3.x; c1[5]=(f16)v3.y; c1[6]=(f16)v3.z; c1[7]=(f16)v3.w;
        }
      } else {
        #pragma unroll
        for (int u = 0; u < 8; ++u) { c0[u] = (f16)0.f; c1[u] = (f16)0.f; }
      }
      *(f16x8*)&As[srow * 32 + ((sc0 ^ sw) << 3)]       = c0;
      *(f16x8*)&As[srow * 32 + (((sc0 + 1) ^ sw) << 3)] = c1;
    }
    // stage B
    {
      const f16* bp = Wt + (size_t)(bn + srow) * K + k0 + sc0 * 8;
      f16x8 b0 = *(const f16x8*)bp;
      f16x8 b1 = *(const f16x8*)(bp + 8);
      *(f16x8*)&Bs[srow * 32 + ((sc0 ^ sw) << 3)]       = b0;
      *(f16x8*)&Bs[srow * 32 + (((sc0 + 1) ^ sw) << 3)] = b1;
    }
    __syncthreads();
    f16x8 af[4], bf[4];
    #pragma unroll
    for (int mt = 0; mt < 4; ++mt) {
      int r = wm + mt * 16 + lr;
      af[mt] = *(const f16x8*)&As[r * 32 + ((lk ^ ((r >> 1) & 3)) << 3)];
    }
    #pragma unroll
    for (int nt = 0; nt < 4; ++nt) {
      int r = wn + nt * 16 + lr;
      bf[nt] = *(const f16x8*)&Bs[r * 32 + ((lk ^ ((r >> 1) & 3)) << 3)];
    }
    #pragma unroll
    for (int mt = 0; mt < 4; ++mt)
      #pragma unroll
      for (int nt = 0; nt < 4; ++nt)
        acc[mt][nt] = __builtin_amdgcn_mfma_f32_16x16x32_f16(af[mt], bf[nt], acc[mt][nt], 0, 0, 0);
    __syncthreads();
  }
  #pragma unroll
  for (int mt = 0; mt < 4; ++mt) {
    int gm0 = bm + wm + mt * 16 + lk * 4;
    #pragma unroll
    for (int nt = 0; nt < 4; ++nt) {
      int gn = bn + wn + nt * 16 + lr;
      float bv = bias ? bias[gn] : 0.0f;
      #pragma unroll
      for (int rr = 0; rr < 4; ++rr) {
        int gm = gm0 + rr;
        if (gm >= M) continue;
        float v = acc[mt][nt][rr] + bv;
        if (EPI == 1) v = v / (1.0f + expf(-v));
        storev(&C[(size_t)gm * ldc + gn], v);
      }
    }
  }
}

// ---------------- per-node edge reduction: wave per node, f16x2, 2x unroll ----------------
__global__ __launch_bounds__(256) void k_edge_msg(
    const int* __restrict__ rs, const int* __restrict__ jperm,
    const f16* __restrict__ x, const f16* __restrict__ tab,
    const float4* __restrict__ geo, const f16* __restrict__ mu_in,
    float* __restrict__ q, f16* __restrict__ mu_out) {
  const int wid  = threadIdx.x >> 6;
  const int lane = threadIdx.x & 63;
  const int i = blockIdx.x * 4 + wid;
  if (i >= N_NODES) return;
  const int d0 = lane * 2;
  const float scale = (float)(TAB_T - 1) / 5.0f;
  float aqx = 0.f, aqy = 0.f;
  float a0x = 0.f, a0y = 0.f, a1x = 0.f, a1y = 0.f, a2x = 0.f, a2y = 0.f;
  const int s = rs[i], e = rs[i + 1];

  auto body = [&](int j, float u, float dx, float dy, float dz,
                  f16x2 ta0, f16x2 ta1, f16x2 ta2, f16x2 tb0, f16x2 tb1, f16x2 tb2,
                  f16x2 xv0, f16x2 xv1, f16x2 xv2, f16x2 mv0, f16x2 mv1, f16x2 mv2,
                  float fr) {
    float fo = 1.0f - fr;
    float W0x = fo * (float)ta0[0] + fr * (float)tb0[0];
    float W0y = fo * (float)ta0[1] + fr * (float)tb0[1];
    float W1x = fo * (float)ta1[0] + fr * (float)tb1[0];
    float W1y = fo * (float)ta1[1] + fr * (float)tb1[1];
    float W2x = fo * (float)ta2[0] + fr * (float)tb2[0];
    float W2y = fo * (float)ta2[1] + fr * (float)tb2[1];
    float m1x = (float)xv1[0] * W1x, m1y = (float)xv1[1] * W1y;
    float m2x = (float)xv2[0] * W2x, m2y = (float)xv2[1] * W2y;
    aqx = fmaf((float)xv0[0], W0x, aqx);
    aqy = fmaf((float)xv0[1], W0y, aqy);
    a0x += m1x * dx + m2x * (float)mv0[0];
    a0y += m1y * dx + m2y * (float)mv0[1];
    a1x += m1x * dy + m2x * (float)mv1[0];
    a1y += m1y * dy + m2y * (float)mv1[1];
    a2x += m1x * dz + m2x * (float)mv2[0];
    a2y += m1y * dz + m2y * (float)mv2[1];
  };

  int p = s;
  for (; p + 2 <= e; p += 2) {
    // scalars for both edges
    int jA = jperm[p], jB = jperm[p + 1];
    float4 gA = geo[p], gB = geo[p + 1];
    float uA = fminf(gA.x, 5.0f) * scale;
    float uB = fminf(gB.x, 5.0f) * scale;
    int tA = min((int)uA, TAB_T - 2);
    int tB = min((int)uB, TAB_T - 2);
    float frA = uA - (float)tA, frB = uB - (float)tB;
    const f16* taA = tab + (size_t)tA * 384;
    const f16* taB = tab + (size_t)tB * 384;
    const f16* xjA = x + (size_t)jA * 384;
    const f16* xjB = x + (size_t)jB * 384;
    const f16* mjA = mu_in + (size_t)jA * 384;
    const f16* mjB = mu_in + (size_t)jB * 384;
    // issue all loads for both edges
    f16x2 tA0 = *(const f16x2*)(taA + d0);
    f16x2 tA1 = *(const f16x2*)(taA + 128 + d0);
    f16x2 tA2 = *(const f16x2*)(taA + 256 + d0);
    f16x2 tA3 = *(const f16x2*)(taA + 384 + d0);
    f16x2 tA4 = *(const f16x2*)(taA + 512 + d0);
    f16x2 tA5 = *(const f16x2*)(taA + 640 + d0);
    f16x2 xA0 = *(const f16x2*)(xjA + d0);
    f16x2 xA1 = *(const f16x2*)(xjA + 128 + d0);
    f16x2 xA2 = *(const f16x2*)(xjA + 256 + d0);
    f16x2 mA0 = *(const f16x2*)(mjA + d0);
    f16x2 mA1 = *(const f16x2*)(mjA + 128 + d0);
    f16x2 mA2 = *(const f16x2*)(mjA + 256 + d0);
    f16x2 tB0 = *(const f16x2*)(taB + d0);
    f16x2 tB1 = *(const f16x2*)(taB + 128 + d0);
    f16x2 tB2 = *(const f16x2*)(taB + 256 + d0);
    f16x2 tB3 = *(const f16x2*)(taB + 384 + d0);
    f16x2 tB4 = *(const f16x2*)(taB + 512 + d0);
    f16x2 tB5 = *(const f16x2*)(taB + 640 + d0);
    f16x2 xB0 = *(const f16x2*)(xjB + d0);
    f16x2 xB1 = *(const f16x2*)(xjB + 128 + d0);
    f16x2 xB2 = *(const f16x2*)(xjB + 256 + d0);
    f16x2 mB0 = *(const f16x2*)(mjB + d0);
    f16x2 mB1 = *(const f16x2*)(mjB + 128 + d0);
    f16x2 mB2 = *(const f16x2*)(mjB + 256 + d0);
    body(jA, uA, gA.y, gA.z, gA.w, tA0, tA1, tA2, tA3, tA4, tA5,
         xA0, xA1, xA2, mA0, mA1, mA2, frA);
    body(jB, uB, gB.y, gB.z, gB.w, tB0, tB1, tB2, tB3, tB4, tB5,
         xB0, xB1, xB2, mB0, mB1, mB2, frB);
  }
  for (; p < e; ++p) {
    int j = jperm[p];
    float4 g = geo[p];
    float u = fminf(g.x, 5.0f) * scale;
    int t0 = min((int)u, TAB_T - 2);
    float fr = u - (float)t0;
    const f16* ta = tab + (size_t)t0 * 384;
    const f16* xj = x + (size_t)j * 384;
    const f16* mj = mu_in + (size_t)j * 384;
    body(j, u, g.y, g.z, g.w,
         *(const f16x2*)(ta + d0), *(const f16x2*)(ta + 128 + d0), *(const f16x2*)(ta + 256 + d0),
         *(const f16x2*)(ta + 384 + d0), *(const f16x2*)(ta + 512 + d0), *(const f16x2*)(ta + 640 + d0),
         *(const f16x2*)(xj + d0), *(const f16x2*)(xj + 128 + d0), *(const f16x2*)(xj + 256 + d0),
         *(const f16x2*)(mj + d0), *(const f16x2*)(mj + 128 + d0), *(const f16x2*)(mj + 256 + d0),
         fr);
  }

  float* qp = q + (size_t)i * 128 + d0;
  float2 qv = *(float2*)qp;
  qv.x += aqx; qv.y += aqy;
  *(float2*)qp = qv;
  const f16* min_ = mu_in + (size_t)i * 384;
  f16* mout = mu_out + (size_t)i * 384;
  f16x2 o0, o1, o2;
  f16x2 i0 = *(const f16x2*)(min_ + d0);
  f16x2 i1 = *(const f16x2*)(min_ + 128 + d0);
  f16x2 i2 = *(const f16x2*)(min_ + 256 + d0);
  o0[0] = (f16)((float)i0[0] + a0x); o0[1] = (f16)((float)i0[1] + a0y);
  o1[0] = (f16)((float)i1[0] + a1x); o1[1] = (f16)((float)i1[1] + a1y);
  o2[0] = (f16)((float)i2[0] + a2x); o2[1] = (f16)((float)i2[1] + a2y);
  *(f16x2*)(mout + d0)       = o0;
  *(f16x2*)(mout + 128 + d0) = o1;
  *(f16x2*)(mout + 256 + d0) = o2;
}

// ---------------- mix-phase elementwise kernels ----------------
// mumix layout: [N][3][256], per (n,dir): cols 0-127 = V, 128-255 = W
__global__ void k_ctx(const f16* __restrict__ mumix, const float* __restrict__ q,
                      f16* __restrict__ ctx, float* __restrict__ svw) {
  int t = blockIdx.x * 256 + threadIdx.x;
  if (t >= N_NODES * 128) return;
  int n = t >> 7, d = t & 127;
  const f16* mm = mumix + (size_t)n * 768;
  float v0 = (float)mm[d],       w0 = (float)mm[128 + d];
  float v1 = (float)mm[256 + d], w1 = (float)mm[384 + d];
  float v2 = (float)mm[512 + d], w2 = (float)mm[640 + d];
  float vn = sqrtf(v0*v0 + v1*v1 + v2*v2 + 1e-8f);
  float s  = v0*w0 + v1*w1 + v2*w2;
  ctx[(size_t)n * 256 + d]       = (f16)q[t];
  ctx[(size_t)n * 256 + 128 + d] = (f16)vn;
  svw[t] = s;
}

__global__ void k_mixupd(const f16* __restrict__ xm, const f16* __restrict__ mumix,
                         const float* __restrict__ svw, float* __restrict__ q,
                         f16* __restrict__ mu) {
  int t = blockIdx.x * 256 + threadIdx.x;
  if (t >= N_NODES * 128) return;
  int n = t >> 7, d = t & 127;
  const f16* xr = xm + (size_t)n * 384;
  float dq = (float)xr[d], dmu = (float)xr[128 + d], dqmu = (float)xr[256 + d];
  q[t] += dq + dqmu * svw[t];
  const f16* mm = mumix + (size_t)n * 768;
  f16* mr = mu + (size_t)n * 384;
  mr[d]       = (f16)((float)mr[d]       + dmu * (float)mm[128 + d]);
  mr[128 + d] = (f16)((float)mr[128 + d] + dmu * (float)mm[384 + d]);
  mr[256 + d] = (f16)((float)mr[256 + d] + dmu * (float)mm[640 + d]);
}

// ---------------- final outputs ----------------
__global__ __launch_bounds__(256) void k_posattr(
    const int* __restrict__ rs, const int* __restrict__ jperm,
    const f16* __restrict__ mu, const float* __restrict__ w, float* __restrict__ pos_out) {
  const int wid  = threadIdx.x >> 6;
  const int lane = threadIdx.x & 63;
  const int i = blockIdx.x * 4 + wid;
  if (i >= N_NODES) return;
  const int d0 = lane * 2;
  float a0x = 0.f, a0y = 0.f, a1x = 0.f, a1y = 0.f, a2x = 0.f, a2y = 0.f;
  const int s = rs[i], e = rs[i + 1];
  int p = s;
  for (; p + 2 <= e; p += 2) {
    int jA = jperm[p], jB = jperm[p + 1];
    const f16* mA = mu + (size_t)jA * 384;
    const f16* mB = mu + (size_t)jB * 384;
    f16x2 A0 = *(const f16x2*)(mA + d0);
    f16x2 A1 = *(const f16x2*)(mA + 128 + d0);
    f16x2 A2 = *(const f16x2*)(mA + 256 + d0);
    f16x2 B0 = *(const f16x2*)(mB + d0);
    f16x2 B1 = *(const f16x2*)(mB + 128 + d0);
    f16x2 B2 = *(const f16x2*)(mB + 256 + d0);
    a0x += (float)A0[0] + (float)B0[0]; a0y += (float)A0[1] + (float)B0[1];
    a1x += (float)A1[0] + (float)B1[0]; a1y += (float)A1[1] + (float)B1[1];
    a2x += (float)A2[0] + (float)B2[0]; a2y += (float)A2[1] + (float)B2[1];
  }
  for (; p < e; ++p) {
    int j = jperm[p];
    const f16* mj = mu + (size_t)j * 384;
    f16x2 A0 = *(const f16x2*)(mj + d0);
    f16x2 A1 = *(const f16x2*)(mj + 128 + d0);
    f16x2 A2 = *(const f16x2*)(mj + 256 + d0);
    a0x += (float)A0[0]; a0y += (float)A0[1];
    a1x += (float)A1[0]; a1y += (float)A1[1];
    a2x += (float)A2[0]; a2y += (float)A2[1];
  }
  float wx = w[d0], wy = w[d0 + 1];
  float s0 = fminf(fmaxf(a0x, -5.f), 5.f) * wx + fminf(fmaxf(a0y, -5.f), 5.f) * wy;
  float s1 = fminf(fmaxf(a1x, -5.f), 5.f) * wx + fminf(fmaxf(a1y, -5.f), 5.f) * wy;
  float s2 = fminf(fmaxf(a2x, -5.f), 5.f) * wx + fminf(fmaxf(a2y, -5.f), 5.f) * wy;
  #pragma unroll
  for (int off = 32; off > 0; off >>= 1) {
    s0 += __shfl_down(s0, off, 64);
    s1 += __shfl_down(s1, off, 64);
    s2 += __shfl_down(s2, off, 64);
  }
  if (lane == 0) {
    pos_out[(size_t)i * 3 + 0] = fminf(fmaxf(s0, -5.f), 5.f);
    pos_out[(size_t)i * 3 + 1] = fminf(fmaxf(s1, -5.f), 5.f);
    pos_out[(size_t)i * 3 + 2] = fminf(fmaxf(s2, -5.f), 5.f);
  }
}

__global__ __launch_bounds__(128) void k_ln(const float* __restrict__ q, const float* __restrict__ g,
                                            const float* __restrict__ b, float* __restrict__ out) {
  __shared__ float s1[128], s2[128];
  int n = blockIdx.x, d = threadIdx.x;
  float v = q[(size_t)n * 128 + d];
  v = fminf(fmaxf(v, -5.f), 5.f);
  s1[d] = v; s2[d] = v * v;
  __syncthreads();
  for (int off = 64; off > 0; off >>= 1) {
    if (d < off) { s1[d] += s1[d+off]; s2[d] += s2[d+off]; }
    __syncthreads();
  }
  float mean = s1[0] * (1.0f / 128.0f);
  float var  = s2[0] * (1.0f / 128.0f) - mean * mean;
  float y = (v - mean) * rsqrtf(var + 1e-5f) * g[d] + b[d];
  out[(size_t)n * 128 + d] = tanhf(y);
}

extern "C" void kernel_launch(void* const* d_in, const int* in_sizes, int n_in,
                              void* d_out, int out_size, void* d_ws, size_t ws_size,
                              hipStream_t stream) {
  const float* z         = (const float*)d_in[0];
  const float* pos       = (const float*)d_in[1];
  const int*   edge_idx  = (const int*)d_in[2];
  const float* in_w      = (const float*)d_in[3];
  const float* in_b      = (const float*)d_in[4];
  const float* filt_w    = (const float*)d_in[5];
  const float* filt_b    = (const float*)d_in[6];
  const float* inter_w1  = (const float*)d_in[7];
  const float* inter_b1  = (const float*)d_in[8];
  const float* inter_w2  = (const float*)d_in[9];
  const float* inter_b2  = (const float*)d_in[10];
  const float* mix_mu_w  = (const float*)d_in[11];
  const float* mix_w1    = (const float*)d_in[12];
  const float* mix_b1    = (const float*)d_in[13];
  const float* mix_w2    = (const float*)d_in[14];
  const float* mix_b2    = (const float*)d_in[15];
  const float* mu_proj_w = (const float*)d_in[16];
  const float* ln_g      = (const float*)d_in[17];
  const float* ln_b      = (const float*)d_in[18];

  char* base = (char*)d_ws;
  size_t off = 0;
  auto alloc = [&](size_t bytes) -> char* {
    char* p = base + off;
    off += (bytes + 255) & ~(size_t)255;
    return p;
  };
  float*  q     = (float*)alloc((size_t)N_NODES * 128 * 4);
  float*  svw   = (float*)alloc((size_t)N_NODES * 128 * 4);
  f16*    h     = (f16*)alloc((size_t)N_NODES * 128 * 2);
  f16*    x16   = (f16*)alloc((size_t)N_NODES * 384 * 2);   // x / xm
  f16*    mu_a  = (f16*)alloc((size_t)N_NODES * 384 * 2);
  f16*    mu_b  = (f16*)alloc((size_t)N_NODES * 384 * 2);
  f16*    mumix = (f16*)alloc((size_t)N_NODES * 768 * 2);
  f16*    ctx   = (f16*)alloc((size_t)N_NODES * 256 * 2);
  float4* geo   = (float4*)alloc((size_t)N_EDGES * 16);
  int*    cnt   = (int*)alloc((size_t)N_NODES * 4);
  int*    incl  = (int*)alloc((size_t)N_NODES * 4);
  int*    bsum  = (int*)alloc(128 * 4);
  int*    rs    = (int*)alloc((size_t)(N_NODES + 1) * 4);
  int*    cur   = (int*)alloc((size_t)N_NODES * 4);
  int*    eidx  = (int*)alloc((size_t)N_EDGES * 4);
  int*    jperm = (int*)alloc((size_t)N_EDGES * 4);
  f16*    tab   = (f16*)alloc((size_t)TAB_T * 384 * 2);
  // f16 transposed weights
  f16* wt_in = (f16*)alloc((size_t)128 * 64 * 2);
  f16* wt_f  = (f16*)alloc((size_t)384 * 64 * 2);
  f16* wt_i1 = (f16*)alloc((size_t)3 * 128 * 128 * 2);
  f16* wt_i2 = (f16*)alloc((size_t)3 * 384 * 128 * 2);
  f16* wt_mu = (f16*)alloc((size_t)3 * 256 * 128 * 2);
  f16* wt_x1 = (f16*)alloc((size_t)3 * 128 * 256 * 2);
  f16* wt_x2 = (f16*)alloc((size_t)3 * 384 * 128 * 2);
  if (off > ws_size) return;

  float* out_node = (float*)d_out;
  float* out_pos  = (float*)d_out + (size_t)N_NODES * 128;

  // ---- weight prep (f16, [N][K]) ----
  {
    WJobs jb;
    int ji = 0;
    jb.j[ji++] = {in_w,   wt_in, 6, 128, 0, 128 * 64};
    jb.j[ji++] = {filt_w, wt_f,  6, 384, 0, 384 * 64};
    for (int l = 0; l < 3; ++l)
      jb.j[ji++] = {inter_w1 + (size_t)l*128*128, wt_i1 + (size_t)l*128*128, 7, 128, 0, 128*128};
    for (int l = 0; l < 3; ++l)
      jb.j[ji++] = {inter_w2 + (size_t)l*128*384, wt_i2 + (size_t)l*384*128, 7, 384, 0, 384*128};
    for (int l = 0; l < 3; ++l)
      jb.j[ji++] = {mix_mu_w + (size_t)l*128*256, wt_mu + (size_t)l*256*128, 7, 256, 0, 256*128};
    for (int l = 0; l < 3; ++l)
      jb.j[ji++] = {mix_w1 + (size_t)l*256*128, wt_x1 + (size_t)l*128*256, 8, 128, 0, 128*256};
    for (int l = 0; l < 3; ++l)
      jb.j[ji++] = {mix_w2 + (size_t)l*128*384, wt_x2 + (size_t)l*384*128, 7, 384, 0, 384*128};
    dim3 g(192, 17);
    k_wt_all<<<g, 256, 0, stream>>>(jb);
  }

  // ---- filter lookup table ----
  k_tab<<<TAB_T, 128, 0, stream>>>(wt_f, filt_b, tab);

  // ---- CSR build ----
  hipMemsetAsync(cnt, 0, (size_t)N_NODES * 4, stream);
  k_hist<<<N_EDGES / 256, 256, 0, stream>>>(edge_idx, cnt);
  k_scan_blk<<<NB_SCAN, 256, 0, stream>>>(cnt, incl, bsum);
  k_scan_top<<<1, 128, 0, stream>>>(bsum);
  k_scan_add<<<NB_SCAN, 256, 0, stream>>>(cnt, incl, bsum, rs);
  hipMemcpyAsync(cur, rs, (size_t)N_NODES * 4, hipMemcpyDeviceToDevice, stream);
  k_fill<<<N_EDGES / 256, 256, 0, stream>>>(edge_idx, cur, eidx);

  // ---- edge geometry (CSR-permuted) ----
  k_edge_geom<<<N_EDGES / 256, 256, 0, stream>>>(pos, edge_idx, eidx, geo, jperm);

  // ---- input embedding ----
  dim3 ge((N_NODES + 127) / 128, 1);
  dim3 gx((N_NODES + 127) / 128, 3);
  dim3 gv((N_NODES * 3 + 127) / 128, 2);
  k_mgemm<1, float, float><<<ge, 256, 0, stream>>>(z, wt_in, in_b, q, N_NODES, 64, 128);
  hipMemsetAsync(mu_a, 0, (size_t)N_NODES * 384 * 2, stream);

  f16* mu_cur = mu_a;
  f16* mu_nxt = mu_b;
  const int gn4 = (N_NODES + 3) / 4;
  for (int l = 0; l < NLAYER; ++l) {
    k_mgemm<1, float, f16><<<ge, 256, 0, stream>>>(q, wt_i1 + (size_t)l*128*128,
                                                   inter_b1 + (size_t)l*128, h, N_NODES, 128, 128);
    k_mgemm<0, f16, f16><<<gx, 256, 0, stream>>>(h, wt_i2 + (size_t)l*384*128,
                                                 inter_b2 + (size_t)l*384, x16, N_NODES, 128, 384);
    k_edge_msg<<<gn4, 256, 0, stream>>>(rs, jperm, x16, tab, geo, mu_cur, q, mu_nxt);
    { f16* t = mu_cur; mu_cur = mu_nxt; mu_nxt = t; }
    // mumix: [3N][128] @ [256][128]^T -> [3N][256] (V cols 0-127, W cols 128-255)
    k_mgemm<0, f16, f16><<<gv, 256, 0, stream>>>(mu_cur, wt_mu + (size_t)l*256*128, nullptr,
                                                 mumix, N_NODES * 3, 128, 256);
    k_ctx<<<(N_NODES * 128) / 256, 256, 0, stream>>>(mumix, q, ctx, svw);
    k_mgemm<1, f16, f16><<<ge, 256, 0, stream>>>(ctx, wt_x1 + (size_t)l*128*256,
                                                 mix_b1 + (size_t)l*128, h, N_NODES, 256, 128);
    k_mgemm<0, f16, f16><<<gx, 256, 0, stream>>>(h, wt_x2 + (size_t)l*384*128,
                                                 mix_b2 + (size_t)l*384, x16, N_NODES, 128, 384);
    k_mixupd<<<(N_NODES * 128) / 256, 256, 0, stream>>>(x16, mumix, svw, q, mu_cur);
  }

  // ---- outputs ----
  k_posattr<<<gn4, 256, 0, stream>>>(rs, jperm, mu_cur, mu_proj_w, out_pos);
  k_ln<<<N_NODES, 128, 0, stream>>>(q, ln_g, ln_b, out_node);
}

// Round 7
// 760.732 us; speedup vs baseline: 3.2708x; 1.0893x over previous
//
#include <hip/hip_runtime.h>
#include <math.h>

#ifndef M_PI
#define M_PI 3.14159265358979323846
#endif

static constexpr int N_NODES = 20000;
static constexpr int N_EDGES = 320000;
static constexpr int NLAYER  = 3;
static constexpr int NB_SCAN = (N_NODES + 255) / 256;  // 79
static constexpr int TAB_T   = 4096;                   // filter lookup rows

typedef _Float16 f16;
typedef __attribute__((ext_vector_type(2))) _Float16 f16x2;
typedef __attribute__((ext_vector_type(8))) _Float16 f16x8;
typedef __attribute__((ext_vector_type(4))) float f32x4;

__device__ __forceinline__ void storev(float* p, float v) { *p = v; }
__device__ __forceinline__ void storev(f16* p, float v)   { *p = (f16)v; }

// ---------------- CSR build ----------------
__global__ void k_hist(const int* __restrict__ idx_i, int* __restrict__ cnt) {
  int e = blockIdx.x * 256 + threadIdx.x;
  if (e < N_EDGES) atomicAdd(&cnt[idx_i[e]], 1);
}

__global__ void k_scan_blk(const int* __restrict__ cnt, int* __restrict__ incl,
                           int* __restrict__ bsum) {
  __shared__ int buf[256];
  int t = threadIdx.x;
  int i = blockIdx.x * 256 + t;
  int v = (i < N_NODES) ? cnt[i] : 0;
  buf[t] = v;
  __syncthreads();
  #pragma unroll
  for (int off = 1; off < 256; off <<= 1) {
    int x = (t >= off) ? buf[t - off] : 0;
    __syncthreads();
    buf[t] += x;
    __syncthreads();
  }
  if (i < N_NODES) incl[i] = buf[t];
  if (t == 255) bsum[blockIdx.x] = buf[255];
}

__global__ void k_scan_top(int* __restrict__ bsum) {
  __shared__ int buf[128];
  int t = threadIdx.x;
  int v = (t < NB_SCAN) ? bsum[t] : 0;
  buf[t] = v;
  __syncthreads();
  #pragma unroll
  for (int off = 1; off < 128; off <<= 1) {
    int x = (t >= off) ? buf[t - off] : 0;
    __syncthreads();
    buf[t] += x;
    __syncthreads();
  }
  if (t <= NB_SCAN) bsum[t] = buf[t] - v;  // exclusive; t==NB_SCAN -> total
}

__global__ void k_scan_add(const int* __restrict__ cnt, const int* __restrict__ incl,
                           const int* __restrict__ bsum, int* __restrict__ rs) {
  int i = blockIdx.x * 256 + threadIdx.x;
  if (i < N_NODES) rs[i] = bsum[blockIdx.x] + incl[i] - cnt[i];
  if (i == 0) rs[N_NODES] = bsum[NB_SCAN];
}

__global__ void k_fill(const int* __restrict__ idx_i, int* __restrict__ cur, int* __restrict__ eidx) {
  int e = blockIdx.x * 256 + threadIdx.x;
  if (e < N_EDGES) {
    int p = atomicAdd(&cur[idx_i[e]], 1);
    eidx[p] = e;
  }
}

// ---------------- edge geometry, CSR-permuted; geo = {d, dx, dy, dz} ----------------
__global__ void k_edge_geom(const float* __restrict__ pos, const int* __restrict__ idx_all,
                            const int* __restrict__ eidx, float4* __restrict__ geo,
                            int* __restrict__ jperm) {
  int p = blockIdx.x * 256 + threadIdx.x;
  if (p >= N_EDGES) return;
  int e = eidx[p];
  int i = idx_all[e];
  int j = idx_all[N_EDGES + e];
  float rx = pos[j*3+0] - pos[i*3+0];
  float ry = pos[j*3+1] - pos[i*3+1];
  float rz = pos[j*3+2] - pos[i*3+2];
  float d = sqrtf(rx*rx + ry*ry + rz*rz);
  d = fmaxf(d, 1e-8f);
  float inv = 1.0f / d;
  geo[p] = make_float4(d, rx*inv, ry*inv, rz*inv);
  jperm[p] = j;
}

// ---------------- weight transpose+convert: Wt[n][k] = (f16)src[k][col0+n] ----------------
struct WJob { const float* src; f16* dst; int kshift; int ld; int col0; int nk; };
struct WJobs { WJob j[17]; };

__global__ void k_wt_all(WJobs jb) {
  WJob w = jb.j[blockIdx.y];
  int t = blockIdx.x * 256 + threadIdx.x;
  if (t >= w.nk) return;
  int K = 1 << w.kshift;
  int n = t >> w.kshift;
  int k = t & (K - 1);
  w.dst[t] = (f16)w.src[(size_t)k * w.ld + w.col0 + n];
}

// ---------------- filter lookup table: tab[t][n], t over d in [0,5] ----------------
__global__ __launch_bounds__(128) void k_tab(const f16* __restrict__ wt_f /*[384][64]*/,
                                             const float* __restrict__ bias,
                                             f16* __restrict__ tab) {
  __shared__ float ph[64];
  const int t = blockIdx.x;
  const float dist = 5.0f * (float)t / (float)(TAB_T - 1);
  const int tid = threadIdx.x;
  const float delta = 5.0f / 63.0f;
  const float coeff = -0.5f / (delta * delta);
  if (tid < 64) {
    float u = dist - delta * (float)tid;
    ph[tid] = expf(coeff * u * u);
  }
  __syncthreads();
  float xc = dist * 0.2f;
  float fc = (xc < 1.0f) ? 0.5f * (cosf((float)M_PI * xc) + 1.0f) : 0.0f;
  #pragma unroll
  for (int s = 0; s < 3; ++s) {
    int n = tid + s * 128;
    const f16* wr = wt_f + (size_t)n * 64;
    float acc = 0.f;
    #pragma unroll
    for (int k = 0; k < 64; ++k) acc += ph[k] * (float)wr[k];
    float v = (acc + bias[n]) * fc;
    v = fminf(fmaxf(v, -5.0f), 5.0f);
    tab[(size_t)t * 384 + n] = (f16)v;
  }
}

// ---------------- MFMA f16 GEMM (128-tile, LDS-staged A and B) ----------------
template<int EPI, typename AT, typename CT>
__global__ __launch_bounds__(256) void k_mgemm(
    const AT* __restrict__ A, const f16* __restrict__ Wt,
    const float* __restrict__ bias, CT* __restrict__ C,
    int M, int K, int ldc) {
  __shared__ f16 As[128 * 32];
  __shared__ f16 Bs[128 * 32];
  const int bm = blockIdx.x * 128;
  const int bn = blockIdx.y * 128;
  const int tid = threadIdx.x;
  const int wave = tid >> 6, lane = tid & 63;
  const int wm = (wave & 1) * 64, wn = (wave >> 1) * 64;
  const int lr = lane & 15;
  const int lk = lane >> 4;
  const int srow = tid >> 1;
  const int sc0 = (tid & 1) * 2;
  const int sw = (srow >> 1) & 3;
  f32x4 acc[4][4] = {};
  for (int k0 = 0; k0 < K; k0 += 32) {
    {
      int gm = bm + srow;
      f16x8 c0, c1;
      if (gm < M) {
        if constexpr (sizeof(AT) == 2) {
          const f16* ap = (const f16*)A + (size_t)gm * K + k0 + sc0 * 8;
          c0 = *(const f16x8*)ap;
          c1 = *(const f16x8*)(ap + 8);
        } else {
          const float* ap = (const float*)A + (size_t)gm * K + k0 + sc0 * 8;
          float4 v0 = ((const float4*)ap)[0];
          float4 v1 = ((const float4*)ap)[1];
          float4 v2 = ((const float4*)ap)[2];
          float4 v3 = ((const float4*)ap)[3];
          c0[0]=(f16)v0.x; c0[1]=(f16)v0.y; c0[2]=(f16)v0.z; c0[3]=(f16)v0.w;
          c0[4]=(f16)v1.x; c0[5]=(f16)v1.y; c0[6]=(f16)v1.z; c0[7]=(f16)v1.w;
          c1[0]=(f16)v2.x; c1[1]=(f16)v2.y; c1[2]=(f16)v2.z; c1[3]=(f16)v2.w;
          c1[4]=(f16)v3.x; c1[5]=(f16)v3.y; c1[6]=(f16)v3.z; c1[7]=(f16)v3.w;
        }
      } else {
        #pragma unroll
        for (int u = 0; u < 8; ++u) { c0[u] = (f16)0.f; c1[u] = (f16)0.f; }
      }
      *(f16x8*)&As[srow * 32 + ((sc0 ^ sw) << 3)]       = c0;
      *(f16x8*)&As[srow * 32 + (((sc0 + 1) ^ sw) << 3)] = c1;
    }
    {
      const f16* bp = Wt + (size_t)(bn + srow) * K + k0 + sc0 * 8;
      f16x8 b0 = *(const f16x8*)bp;
      f16x8 b1 = *(const f16x8*)(bp + 8);
      *(f16x8*)&Bs[srow * 32 + ((sc0 ^ sw) << 3)]       = b0;
      *(f16x8*)&Bs[srow * 32 + (((sc0 + 1) ^ sw) << 3)] = b1;
    }
    __syncthreads();
    f16x8 af[4], bf[4];
    #pragma unroll
    for (int mt = 0; mt < 4; ++mt) {
      int r = wm + mt * 16 + lr;
      af[mt] = *(const f16x8*)&As[r * 32 + ((lk ^ ((r >> 1) & 3)) << 3)];
    }
    #pragma unroll
    for (int nt = 0; nt < 4; ++nt) {
      int r = wn + nt * 16 + lr;
      bf[nt] = *(const f16x8*)&Bs[r * 32 + ((lk ^ ((r >> 1) & 3)) << 3)];
    }
    #pragma unroll
    for (int mt = 0; mt < 4; ++mt)
      #pragma unroll
      for (int nt = 0; nt < 4; ++nt)
        acc[mt][nt] = __builtin_amdgcn_mfma_f32_16x16x32_f16(af[mt], bf[nt], acc[mt][nt], 0, 0, 0);
    __syncthreads();
  }
  #pragma unroll
  for (int mt = 0; mt < 4; ++mt) {
    int gm0 = bm + wm + mt * 16 + lk * 4;
    #pragma unroll
    for (int nt = 0; nt < 4; ++nt) {
      int gn = bn + wn + nt * 16 + lr;
      float bv = bias ? bias[gn] : 0.0f;
      #pragma unroll
      for (int rr = 0; rr < 4; ++rr) {
        int gm = gm0 + rr;
        if (gm >= M) continue;
        float v = acc[mt][nt][rr] + bv;
        if (EPI == 1) v = v / (1.0f + expf(-v));
        storev(&C[(size_t)gm * ldc + gn], v);
      }
    }
  }
}

// ======== fused inter MLP: x = silu(q@W1^T+b1)@W2^T+b2, 64-row tiles ========
// q fp32 [M][128]; W1 [128][128]; W2 [384][128]; xout f16 [M][384]
__global__ __launch_bounds__(256) void k_fused_i(
    const float* __restrict__ q, const f16* __restrict__ W1, const float* __restrict__ b1,
    const f16* __restrict__ W2, const float* __restrict__ b2,
    f16* __restrict__ xout, int M) {
  __shared__ f16 As[64 * 32];
  __shared__ f16 Hs[64 * 132];
  const int tid = threadIdx.x;
  const int wave = tid >> 6, lane = tid & 63;
  const int wm = (wave & 1) * 32, wn = (wave >> 1) * 64;
  const int lr = lane & 15, lk = lane >> 4;
  const int srow = tid >> 2, c8 = tid & 3;
  const int sw = (srow >> 1) & 3;
  const int bm = blockIdx.x * 64;
  f32x4 acc[2][4] = {};
  for (int k0 = 0; k0 < 128; k0 += 32) {
    {
      int gm = bm + srow;
      f16x8 c0;
      if (gm < M) {
        const float* ap = q + (size_t)gm * 128 + k0 + c8 * 8;
        float4 v0 = ((const float4*)ap)[0];
        float4 v1 = ((const float4*)ap)[1];
        c0[0]=(f16)v0.x; c0[1]=(f16)v0.y; c0[2]=(f16)v0.z; c0[3]=(f16)v0.w;
        c0[4]=(f16)v1.x; c0[5]=(f16)v1.y; c0[6]=(f16)v1.z; c0[7]=(f16)v1.w;
      } else {
        #pragma unroll
        for (int u = 0; u < 8; ++u) c0[u] = (f16)0.f;
      }
      *(f16x8*)&As[srow * 32 + ((c8 ^ sw) << 3)] = c0;
    }
    __syncthreads();
    f16x8 af[2], bf[4];
    #pragma unroll
    for (int mt = 0; mt < 2; ++mt) {
      int r = wm + mt * 16 + lr;
      af[mt] = *(const f16x8*)&As[r * 32 + ((lk ^ ((r >> 1) & 3)) << 3)];
    }
    #pragma unroll
    for (int nt = 0; nt < 4; ++nt)
      bf[nt] = *(const f16x8*)&W1[(size_t)(wn + nt * 16 + lr) * 128 + k0 + lk * 8];
    #pragma unroll
    for (int mt = 0; mt < 2; ++mt)
      #pragma unroll
      for (int nt = 0; nt < 4; ++nt)
        acc[mt][nt] = __builtin_amdgcn_mfma_f32_16x16x32_f16(af[mt], bf[nt], acc[mt][nt], 0, 0, 0);
    __syncthreads();
  }
  // h = silu -> LDS
  #pragma unroll
  for (int mt = 0; mt < 2; ++mt)
    #pragma unroll
    for (int nt = 0; nt < 4; ++nt) {
      int col = wn + nt * 16 + lr;
      float bv = b1[col];
      #pragma unroll
      for (int rr = 0; rr < 4; ++rr) {
        int row = wm + mt * 16 + lk * 4 + rr;
        float v = acc[mt][nt][rr] + bv;
        v = v / (1.0f + expf(-v));
        Hs[row * 132 + col] = (f16)v;
      }
    }
  __syncthreads();
  // phase 2: x = h @ W2^T + b2, 3 col chunks of 128
  #pragma unroll
  for (int cc = 0; cc < 3; ++cc) {
    f32x4 a2[2][4] = {};
    for (int k0 = 0; k0 < 128; k0 += 32) {
      f16x8 af2[2], bf2[4];
      #pragma unroll
      for (int mt = 0; mt < 2; ++mt)
        af2[mt] = *(const f16x8*)&Hs[(wm + mt * 16 + lr) * 132 + k0 + lk * 8];
      #pragma unroll
      for (int nt = 0; nt < 4; ++nt)
        bf2[nt] = *(const f16x8*)&W2[(size_t)(cc * 128 + wn + nt * 16 + lr) * 128 + k0 + lk * 8];
      #pragma unroll
      for (int mt = 0; mt < 2; ++mt)
        #pragma unroll
        for (int nt = 0; nt < 4; ++nt)
          a2[mt][nt] = __builtin_amdgcn_mfma_f32_16x16x32_f16(af2[mt], bf2[nt], a2[mt][nt], 0, 0, 0);
    }
    #pragma unroll
    for (int mt = 0; mt < 2; ++mt)
      #pragma unroll
      for (int nt = 0; nt < 4; ++nt) {
        int gn = cc * 128 + wn + nt * 16 + lr;
        float bv = b2[gn];
        #pragma unroll
        for (int rr = 0; rr < 4; ++rr) {
          int gm = bm + wm + mt * 16 + lk * 4 + rr;
          if (gm >= M) continue;
          xout[(size_t)gm * 384 + gn] = (f16)(a2[mt][nt][rr] + bv);
        }
      }
  }
}

// ======== fused mix MLP + update: xm = silu([q,vn]@W1^T+b1)@W2^T+b2; then
//          q += dq + dqmu*svw; mu += dmu*muW  (mixupd fused in epilogue) ========
// q fp32 [M][128] (read+update); vn fp32 [M][128]; W1 [128][256]; W2 [384][128]
__global__ __launch_bounds__(256) void k_fused_x(
    float* __restrict__ q, const float* __restrict__ vn, const float* __restrict__ svw,
    const f16* __restrict__ W1, const float* __restrict__ b1,
    const f16* __restrict__ W2, const float* __restrict__ b2,
    const f16* __restrict__ mumix, f16* __restrict__ mu, int M) {
  __shared__ f16 As[64 * 32];
  __shared__ f16 Hs[64 * 132];
  const int tid = threadIdx.x;
  const int wave = tid >> 6, lane = tid & 63;
  const int wm = (wave & 1) * 32, wn = (wave >> 1) * 64;
  const int lr = lane & 15, lk = lane >> 4;
  const int srow = tid >> 2, c8 = tid & 3;
  const int sw = (srow >> 1) & 3;
  const int bm = blockIdx.x * 64;
  f32x4 acc[2][4] = {};
  for (int k0 = 0; k0 < 256; k0 += 32) {
    {
      int gm = bm + srow;
      int col = k0 + c8 * 8;
      f16x8 c0;
      if (gm < M) {
        const float* src = (col < 128) ? (q + (size_t)gm * 128 + col)
                                       : (vn + (size_t)gm * 128 + col - 128);
        float4 v0 = ((const float4*)src)[0];
        float4 v1 = ((const float4*)src)[1];
        c0[0]=(f16)v0.x; c0[1]=(f16)v0.y; c0[2]=(f16)v0.z; c0[3]=(f16)v0.w;
        c0[4]=(f16)v1.x; c0[5]=(f16)v1.y; c0[6]=(f16)v1.z; c0[7]=(f16)v1.w;
      } else {
        #pragma unroll
        for (int u = 0; u < 8; ++u) c0[u] = (f16)0.f;
      }
      *(f16x8*)&As[srow * 32 + ((c8 ^ sw) << 3)] = c0;
    }
    __syncthreads();
    f16x8 af[2], bf[4];
    #pragma unroll
    for (int mt = 0; mt < 2; ++mt) {
      int r = wm + mt * 16 + lr;
      af[mt] = *(const f16x8*)&As[r * 32 + ((lk ^ ((r >> 1) & 3)) << 3)];
    }
    #pragma unroll
    for (int nt = 0; nt < 4; ++nt)
      bf[nt] = *(const f16x8*)&W1[(size_t)(wn + nt * 16 + lr) * 256 + k0 + lk * 8];
    #pragma unroll
    for (int mt = 0; mt < 2; ++mt)
      #pragma unroll
      for (int nt = 0; nt < 4; ++nt)
        acc[mt][nt] = __builtin_amdgcn_mfma_f32_16x16x32_f16(af[mt], bf[nt], acc[mt][nt], 0, 0, 0);
    __syncthreads();
  }
  #pragma unroll
  for (int mt = 0; mt < 2; ++mt)
    #pragma unroll
    for (int nt = 0; nt < 4; ++nt) {
      int col = wn + nt * 16 + lr;
      float bv = b1[col];
      #pragma unroll
      for (int rr = 0; rr < 4; ++rr) {
        int row = wm + mt * 16 + lk * 4 + rr;
        float v = acc[mt][nt][rr] + bv;
        v = v / (1.0f + expf(-v));
        Hs[row * 132 + col] = (f16)v;
      }
    }
  __syncthreads();
  // phase 2: all 3 chunks kept in registers
  f32x4 a2[3][2][4] = {};
  #pragma unroll
  for (int cc = 0; cc < 3; ++cc)
    for (int k0 = 0; k0 < 128; k0 += 32) {
      f16x8 af2[2], bf2[4];
      #pragma unroll
      for (int mt = 0; mt < 2; ++mt)
        af2[mt] = *(const f16x8*)&Hs[(wm + mt * 16 + lr) * 132 + k0 + lk * 8];
      #pragma unroll
      for (int nt = 0; nt < 4; ++nt)
        bf2[nt] = *(const f16x8*)&W2[(size_t)(cc * 128 + wn + nt * 16 + lr) * 128 + k0 + lk * 8];
      #pragma unroll
      for (int mt = 0; mt < 2; ++mt)
        #pragma unroll
        for (int nt = 0; nt < 4; ++nt)
          a2[cc][mt][nt] = __builtin_amdgcn_mfma_f32_16x16x32_f16(af2[mt], bf2[nt], a2[cc][mt][nt], 0, 0, 0);
    }
  // epilogue: mixupd on live registers
  #pragma unroll
  for (int mt = 0; mt < 2; ++mt)
    #pragma unroll
    for (int nt = 0; nt < 4; ++nt) {
      int col = wn + nt * 16 + lr;
      float b_dq = b2[col], b_dmu = b2[128 + col], b_dqmu = b2[256 + col];
      #pragma unroll
      for (int rr = 0; rr < 4; ++rr) {
        int gm = bm + wm + mt * 16 + lk * 4 + rr;
        if (gm >= M) continue;
        float dq   = a2[0][mt][nt][rr] + b_dq;
        float dmu  = a2[1][mt][nt][rr] + b_dmu;
        float dqmu = a2[2][mt][nt][rr] + b_dqmu;
        size_t qi = (size_t)gm * 128 + col;
        q[qi] += dq + dqmu * svw[qi];
        const f16* mm = mumix + (size_t)gm * 768;
        f16* mr = mu + (size_t)gm * 384;
        mr[col]       = (f16)((float)mr[col]       + dmu * (float)mm[128 + col]);
        mr[128 + col] = (f16)((float)mr[128 + col] + dmu * (float)mm[384 + col]);
        mr[256 + col] = (f16)((float)mr[256 + col] + dmu * (float)mm[640 + col]);
      }
    }
}

// ---------------- per-node edge reduction: wave per node, f16x2, 2x unroll ----------------
__global__ __launch_bounds__(256) void k_edge_msg(
    const int* __restrict__ rs, const int* __restrict__ jperm,
    const f16* __restrict__ x, const f16* __restrict__ tab,
    const float4* __restrict__ geo, const f16* __restrict__ mu_in,
    float* __restrict__ q, f16* __restrict__ mu_out) {
  const int wid  = threadIdx.x >> 6;
  const int lane = threadIdx.x & 63;
  const int i = blockIdx.x * 4 + wid;
  if (i >= N_NODES) return;
  const int d0 = lane * 2;
  const float scale = (float)(TAB_T - 1) / 5.0f;
  float aqx = 0.f, aqy = 0.f;
  float a0x = 0.f, a0y = 0.f, a1x = 0.f, a1y = 0.f, a2x = 0.f, a2y = 0.f;
  const int s = rs[i], e = rs[i + 1];

  auto body = [&](float dx, float dy, float dz,
                  f16x2 ta0, f16x2 ta1, f16x2 ta2, f16x2 tb0, f16x2 tb1, f16x2 tb2,
                  f16x2 xv0, f16x2 xv1, f16x2 xv2, f16x2 mv0, f16x2 mv1, f16x2 mv2,
                  float fr) {
    float fo = 1.0f - fr;
    float W0x = fo * (float)ta0[0] + fr * (float)tb0[0];
    float W0y = fo * (float)ta0[1] + fr * (float)tb0[1];
    float W1x = fo * (float)ta1[0] + fr * (float)tb1[0];
    float W1y = fo * (float)ta1[1] + fr * (float)tb1[1];
    float W2x = fo * (float)ta2[0] + fr * (float)tb2[0];
    float W2y = fo * (float)ta2[1] + fr * (float)tb2[1];
    float m1x = (float)xv1[0] * W1x, m1y = (float)xv1[1] * W1y;
    float m2x = (float)xv2[0] * W2x, m2y = (float)xv2[1] * W2y;
    aqx = fmaf((float)xv0[0], W0x, aqx);
    aqy = fmaf((float)xv0[1], W0y, aqy);
    a0x += m1x * dx + m2x * (float)mv0[0];
    a0y += m1y * dx + m2y * (float)mv0[1];
    a1x += m1x * dy + m2x * (float)mv1[0];
    a1y += m1y * dy + m2y * (float)mv1[1];
    a2x += m1x * dz + m2x * (float)mv2[0];
    a2y += m1y * dz + m2y * (float)mv2[1];
  };

  int p = s;
  for (; p + 2 <= e; p += 2) {
    int jA = jperm[p], jB = jperm[p + 1];
    float4 gA = geo[p], gB = geo[p + 1];
    float uA = fminf(gA.x, 5.0f) * scale;
    float uB = fminf(gB.x, 5.0f) * scale;
    int tA = min((int)uA, TAB_T - 2);
    int tB = min((int)uB, TAB_T - 2);
    float frA = uA - (float)tA, frB = uB - (float)tB;
    const f16* taA = tab + (size_t)tA * 384;
    const f16* taB = tab + (size_t)tB * 384;
    const f16* xjA = x + (size_t)jA * 384;
    const f16* xjB = x + (size_t)jB * 384;
    const f16* mjA = mu_in + (size_t)jA * 384;
    const f16* mjB = mu_in + (size_t)jB * 384;
    f16x2 tA0 = *(const f16x2*)(taA + d0);
    f16x2 tA1 = *(const f16x2*)(taA + 128 + d0);
    f16x2 tA2 = *(const f16x2*)(taA + 256 + d0);
    f16x2 tA3 = *(const f16x2*)(taA + 384 + d0);
    f16x2 tA4 = *(const f16x2*)(taA + 512 + d0);
    f16x2 tA5 = *(const f16x2*)(taA + 640 + d0);
    f16x2 xA0 = *(const f16x2*)(xjA + d0);
    f16x2 xA1 = *(const f16x2*)(xjA + 128 + d0);
    f16x2 xA2 = *(const f16x2*)(xjA + 256 + d0);
    f16x2 mA0 = *(const f16x2*)(mjA + d0);
    f16x2 mA1 = *(const f16x2*)(mjA + 128 + d0);
    f16x2 mA2 = *(const f16x2*)(mjA + 256 + d0);
    f16x2 tB0 = *(const f16x2*)(taB + d0);
    f16x2 tB1 = *(const f16x2*)(taB + 128 + d0);
    f16x2 tB2 = *(const f16x2*)(taB + 256 + d0);
    f16x2 tB3 = *(const f16x2*)(taB + 384 + d0);
    f16x2 tB4 = *(const f16x2*)(taB + 512 + d0);
    f16x2 tB5 = *(const f16x2*)(taB + 640 + d0);
    f16x2 xB0 = *(const f16x2*)(xjB + d0);
    f16x2 xB1 = *(const f16x2*)(xjB + 128 + d0);
    f16x2 xB2 = *(const f16x2*)(xjB + 256 + d0);
    f16x2 mB0 = *(const f16x2*)(mjB + d0);
    f16x2 mB1 = *(const f16x2*)(mjB + 128 + d0);
    f16x2 mB2 = *(const f16x2*)(mjB + 256 + d0);
    body(gA.y, gA.z, gA.w, tA0, tA1, tA2, tA3, tA4, tA5,
         xA0, xA1, xA2, mA0, mA1, mA2, frA);
    body(gB.y, gB.z, gB.w, tB0, tB1, tB2, tB3, tB4, tB5,
         xB0, xB1, xB2, mB0, mB1, mB2, frB);
  }
  for (; p < e; ++p) {
    int j = jperm[p];
    float4 g = geo[p];
    float u = fminf(g.x, 5.0f) * scale;
    int t0 = min((int)u, TAB_T - 2);
    float fr = u - (float)t0;
    const f16* ta = tab + (size_t)t0 * 384;
    const f16* xj = x + (size_t)j * 384;
    const f16* mj = mu_in + (size_t)j * 384;
    body(g.y, g.z, g.w,
         *(const f16x2*)(ta + d0), *(const f16x2*)(ta + 128 + d0), *(const f16x2*)(ta + 256 + d0),
         *(const f16x2*)(ta + 384 + d0), *(const f16x2*)(ta + 512 + d0), *(const f16x2*)(ta + 640 + d0),
         *(const f16x2*)(xj + d0), *(const f16x2*)(xj + 128 + d0), *(const f16x2*)(xj + 256 + d0),
         *(const f16x2*)(mj + d0), *(const f16x2*)(mj + 128 + d0), *(const f16x2*)(mj + 256 + d0),
         fr);
  }

  float* qp = q + (size_t)i * 128 + d0;
  float2 qv = *(float2*)qp;
  qv.x += aqx; qv.y += aqy;
  *(float2*)qp = qv;
  const f16* min_ = mu_in + (size_t)i * 384;
  f16* mout = mu_out + (size_t)i * 384;
  f16x2 o0, o1, o2;
  f16x2 i0 = *(const f16x2*)(min_ + d0);
  f16x2 i1 = *(const f16x2*)(min_ + 128 + d0);
  f16x2 i2 = *(const f16x2*)(min_ + 256 + d0);
  o0[0] = (f16)((float)i0[0] + a0x); o0[1] = (f16)((float)i0[1] + a0y);
  o1[0] = (f16)((float)i1[0] + a1x); o1[1] = (f16)((float)i1[1] + a1y);
  o2[0] = (f16)((float)i2[0] + a2x); o2[1] = (f16)((float)i2[1] + a2y);
  *(f16x2*)(mout + d0)       = o0;
  *(f16x2*)(mout + 128 + d0) = o1;
  *(f16x2*)(mout + 256 + d0) = o2;
}

// ---------------- ctx reduction: vn (fp32), svw (fp32) from mumix ----------------
// mumix layout: [N][3][256], per (n,dir): cols 0-127 = V, 128-255 = W
__global__ void k_ctx(const f16* __restrict__ mumix, float* __restrict__ vn,
                      float* __restrict__ svw) {
  int t = blockIdx.x * 256 + threadIdx.x;
  if (t >= N_NODES * 128) return;
  int n = t >> 7, d = t & 127;
  const f16* mm = mumix + (size_t)n * 768;
  float v0 = (float)mm[d],       w0 = (float)mm[128 + d];
  float v1 = (float)mm[256 + d], w1 = (float)mm[384 + d];
  float v2 = (float)mm[512 + d], w2 = (float)mm[640 + d];
  vn[t]  = sqrtf(v0*v0 + v1*v1 + v2*v2 + 1e-8f);
  svw[t] = v0*w0 + v1*w1 + v2*w2;
}

// ---------------- final outputs ----------------
__global__ __launch_bounds__(256) void k_posattr(
    const int* __restrict__ rs, const int* __restrict__ jperm,
    const f16* __restrict__ mu, const float* __restrict__ w, float* __restrict__ pos_out) {
  const int wid  = threadIdx.x >> 6;
  const int lane = threadIdx.x & 63;
  const int i = blockIdx.x * 4 + wid;
  if (i >= N_NODES) return;
  const int d0 = lane * 2;
  float a0x = 0.f, a0y = 0.f, a1x = 0.f, a1y = 0.f, a2x = 0.f, a2y = 0.f;
  const int s = rs[i], e = rs[i + 1];
  int p = s;
  for (; p + 2 <= e; p += 2) {
    int jA = jperm[p], jB = jperm[p + 1];
    const f16* mA = mu + (size_t)jA * 384;
    const f16* mB = mu + (size_t)jB * 384;
    f16x2 A0 = *(const f16x2*)(mA + d0);
    f16x2 A1 = *(const f16x2*)(mA + 128 + d0);
    f16x2 A2 = *(const f16x2*)(mA + 256 + d0);
    f16x2 B0 = *(const f16x2*)(mB + d0);
    f16x2 B1 = *(const f16x2*)(mB + 128 + d0);
    f16x2 B2 = *(const f16x2*)(mB + 256 + d0);
    a0x += (float)A0[0] + (float)B0[0]; a0y += (float)A0[1] + (float)B0[1];
    a1x += (float)A1[0] + (float)B1[0]; a1y += (float)A1[1] + (float)B1[1];
    a2x += (float)A2[0] + (float)B2[0]; a2y += (float)A2[1] + (float)B2[1];
  }
  for (; p < e; ++p) {
    int j = jperm[p];
    const f16* mj = mu + (size_t)j * 384;
    f16x2 A0 = *(const f16x2*)(mj + d0);
    f16x2 A1 = *(const f16x2*)(mj + 128 + d0);
    f16x2 A2 = *(const f16x2*)(mj + 256 + d0);
    a0x += (float)A0[0]; a0y += (float)A0[1];
    a1x += (float)A1[0]; a1y += (float)A1[1];
    a2x += (float)A2[0]; a2y += (float)A2[1];
  }
  float wx = w[d0], wy = w[d0 + 1];
  float s0 = fminf(fmaxf(a0x, -5.f), 5.f) * wx + fminf(fmaxf(a0y, -5.f), 5.f) * wy;
  float s1 = fminf(fmaxf(a1x, -5.f), 5.f) * wx + fminf(fmaxf(a1y, -5.f), 5.f) * wy;
  float s2 = fminf(fmaxf(a2x, -5.f), 5.f) * wx + fminf(fmaxf(a2y, -5.f), 5.f) * wy;
  #pragma unroll
  for (int off = 32; off > 0; off >>= 1) {
    s0 += __shfl_down(s0, off, 64);
    s1 += __shfl_down(s1, off, 64);
    s2 += __shfl_down(s2, off, 64);
  }
  if (lane == 0) {
    pos_out[(size_t)i * 3 + 0] = fminf(fmaxf(s0, -5.f), 5.f);
    pos_out[(size_t)i * 3 + 1] = fminf(fmaxf(s1, -5.f), 5.f);
    pos_out[(size_t)i * 3 + 2] = fminf(fmaxf(s2, -5.f), 5.f);
  }
}

__global__ __launch_bounds__(128) void k_ln(const float* __restrict__ q, const float* __restrict__ g,
                                            const float* __restrict__ b, float* __restrict__ out) {
  __shared__ float s1[128], s2[128];
  int n = blockIdx.x, d = threadIdx.x;
  float v = q[(size_t)n * 128 + d];
  v = fminf(fmaxf(v, -5.f), 5.f);
  s1[d] = v; s2[d] = v * v;
  __syncthreads();
  for (int off = 64; off > 0; off >>= 1) {
    if (d < off) { s1[d] += s1[d+off]; s2[d] += s2[d+off]; }
    __syncthreads();
  }
  float mean = s1[0] * (1.0f / 128.0f);
  float var  = s2[0] * (1.0f / 128.0f) - mean * mean;
  float y = (v - mean) * rsqrtf(var + 1e-5f) * g[d] + b[d];
  out[(size_t)n * 128 + d] = tanhf(y);
}

extern "C" void kernel_launch(void* const* d_in, const int* in_sizes, int n_in,
                              void* d_out, int out_size, void* d_ws, size_t ws_size,
                              hipStream_t stream) {
  const float* z         = (const float*)d_in[0];
  const float* pos       = (const float*)d_in[1];
  const int*   edge_idx  = (const int*)d_in[2];
  const float* in_w      = (const float*)d_in[3];
  const float* in_b      = (const float*)d_in[4];
  const float* filt_w    = (const float*)d_in[5];
  const float* filt_b    = (const float*)d_in[6];
  const float* inter_w1  = (const float*)d_in[7];
  const float* inter_b1  = (const float*)d_in[8];
  const float* inter_w2  = (const float*)d_in[9];
  const float* inter_b2  = (const float*)d_in[10];
  const float* mix_mu_w  = (const float*)d_in[11];
  const float* mix_w1    = (const float*)d_in[12];
  const float* mix_b1    = (const float*)d_in[13];
  const float* mix_w2    = (const float*)d_in[14];
  const float* mix_b2    = (const float*)d_in[15];
  const float* mu_proj_w = (const float*)d_in[16];
  const float* ln_g      = (const float*)d_in[17];
  const float* ln_b      = (const float*)d_in[18];

  char* base = (char*)d_ws;
  size_t off = 0;
  auto alloc = [&](size_t bytes) -> char* {
    char* p = base + off;
    off += (bytes + 255) & ~(size_t)255;
    return p;
  };
  float*  q     = (float*)alloc((size_t)N_NODES * 128 * 4);
  float*  svw   = (float*)alloc((size_t)N_NODES * 128 * 4);
  float*  vn    = (float*)alloc((size_t)N_NODES * 128 * 4);
  f16*    x16   = (f16*)alloc((size_t)N_NODES * 384 * 2);
  f16*    mu_a  = (f16*)alloc((size_t)N_NODES * 384 * 2);
  f16*    mu_b  = (f16*)alloc((size_t)N_NODES * 384 * 2);
  f16*    mumix = (f16*)alloc((size_t)N_NODES * 768 * 2);
  float4* geo   = (float4*)alloc((size_t)N_EDGES * 16);
  int*    cnt   = (int*)alloc((size_t)N_NODES * 4);
  int*    incl  = (int*)alloc((size_t)N_NODES * 4);
  int*    bsum  = (int*)alloc(128 * 4);
  int*    rs    = (int*)alloc((size_t)(N_NODES + 1) * 4);
  int*    cur   = (int*)alloc((size_t)N_NODES * 4);
  int*    eidx  = (int*)alloc((size_t)N_EDGES * 4);
  int*    jperm = (int*)alloc((size_t)N_EDGES * 4);
  f16*    tab   = (f16*)alloc((size_t)TAB_T * 384 * 2);
  // f16 transposed weights
  f16* wt_in = (f16*)alloc((size_t)128 * 64 * 2);
  f16* wt_f  = (f16*)alloc((size_t)384 * 64 * 2);
  f16* wt_i1 = (f16*)alloc((size_t)3 * 128 * 128 * 2);
  f16* wt_i2 = (f16*)alloc((size_t)3 * 384 * 128 * 2);
  f16* wt_mu = (f16*)alloc((size_t)3 * 256 * 128 * 2);
  f16* wt_x1 = (f16*)alloc((size_t)3 * 128 * 256 * 2);
  f16* wt_x2 = (f16*)alloc((size_t)3 * 384 * 128 * 2);
  if (off > ws_size) return;

  float* out_node = (float*)d_out;
  float* out_pos  = (float*)d_out + (size_t)N_NODES * 128;

  // ---- weight prep (f16, [N][K]) ----
  {
    WJobs jb;
    int ji = 0;
    jb.j[ji++] = {in_w,   wt_in, 6, 128, 0, 128 * 64};
    jb.j[ji++] = {filt_w, wt_f,  6, 384, 0, 384 * 64};
    for (int l = 0; l < 3; ++l)
      jb.j[ji++] = {inter_w1 + (size_t)l*128*128, wt_i1 + (size_t)l*128*128, 7, 128, 0, 128*128};
    for (int l = 0; l < 3; ++l)
      jb.j[ji++] = {inter_w2 + (size_t)l*128*384, wt_i2 + (size_t)l*384*128, 7, 384, 0, 384*128};
    for (int l = 0; l < 3; ++l)
      jb.j[ji++] = {mix_mu_w + (size_t)l*128*256, wt_mu + (size_t)l*256*128, 7, 256, 0, 256*128};
    for (int l = 0; l < 3; ++l)
      jb.j[ji++] = {mix_w1 + (size_t)l*256*128, wt_x1 + (size_t)l*128*256, 8, 128, 0, 128*256};
    for (int l = 0; l < 3; ++l)
      jb.j[ji++] = {mix_w2 + (size_t)l*128*384, wt_x2 + (size_t)l*384*128, 7, 384, 0, 384*128};
    dim3 g(192, 17);
    k_wt_all<<<g, 256, 0, stream>>>(jb);
  }

  // ---- filter lookup table ----
  k_tab<<<TAB_T, 128, 0, stream>>>(wt_f, filt_b, tab);

  // ---- CSR build ----
  hipMemsetAsync(cnt, 0, (size_t)N_NODES * 4, stream);
  k_hist<<<N_EDGES / 256, 256, 0, stream>>>(edge_idx, cnt);
  k_scan_blk<<<NB_SCAN, 256, 0, stream>>>(cnt, incl, bsum);
  k_scan_top<<<1, 128, 0, stream>>>(bsum);
  k_scan_add<<<NB_SCAN, 256, 0, stream>>>(cnt, incl, bsum, rs);
  hipMemcpyAsync(cur, rs, (size_t)N_NODES * 4, hipMemcpyDeviceToDevice, stream);
  k_fill<<<N_EDGES / 256, 256, 0, stream>>>(edge_idx, cur, eidx);

  // ---- edge geometry (CSR-permuted) ----
  k_edge_geom<<<N_EDGES / 256, 256, 0, stream>>>(pos, edge_idx, eidx, geo, jperm);

  // ---- input embedding ----
  dim3 ge((N_NODES + 127) / 128, 1);
  dim3 gv((N_NODES * 3 + 127) / 128, 2);
  k_mgemm<1, float, float><<<ge, 256, 0, stream>>>(z, wt_in, in_b, q, N_NODES, 64, 128);
  hipMemsetAsync(mu_a, 0, (size_t)N_NODES * 384 * 2, stream);

  f16* mu_cur = mu_a;
  f16* mu_nxt = mu_b;
  const int gn4 = (N_NODES + 3) / 4;
  const int gf  = (N_NODES + 63) / 64;  // 313 blocks
  for (int l = 0; l < NLAYER; ++l) {
    k_fused_i<<<gf, 256, 0, stream>>>(q, wt_i1 + (size_t)l*128*128, inter_b1 + (size_t)l*128,
                                      wt_i2 + (size_t)l*384*128, inter_b2 + (size_t)l*384,
                                      x16, N_NODES);
    k_edge_msg<<<gn4, 256, 0, stream>>>(rs, jperm, x16, tab, geo, mu_cur, q, mu_nxt);
    { f16* t = mu_cur; mu_cur = mu_nxt; mu_nxt = t; }
    // mumix: [3N][128] @ [256][128]^T -> [3N][256] (V cols 0-127, W cols 128-255)
    k_mgemm<0, f16, f16><<<gv, 256, 0, stream>>>(mu_cur, wt_mu + (size_t)l*256*128, nullptr,
                                                 mumix, N_NODES * 3, 128, 256);
    k_ctx<<<(N_NODES * 128) / 256, 256, 0, stream>>>(mumix, vn, svw);
    k_fused_x<<<gf, 256, 0, stream>>>(q, vn, svw,
                                      wt_x1 + (size_t)l*128*256, mix_b1 + (size_t)l*128,
                                      wt_x2 + (size_t)l*384*128, mix_b2 + (size_t)l*384,
                                      mumix, mu_cur, N_NODES);
  }

  // ---- outputs ----
  k_posattr<<<gn4, 256, 0, stream>>>(rs, jperm, mu_cur, mu_proj_w, out_pos);
  k_ln<<<N_NODES, 128, 0, stream>>>(q, ln_g, ln_b, out_node);
}

// Round 8
// 663.422 us; speedup vs baseline: 3.7505x; 1.1467x over previous
//
#include <hip/hip_runtime.h>
#include <math.h>

#ifndef M_PI
#define M_PI 3.14159265358979323846
#endif

static constexpr int N_NODES = 20000;
static constexpr int N_EDGES = 320000;
static constexpr int NLAYER  = 3;
static constexpr int NB_SCAN = (N_NODES + 255) / 256;  // 79
static constexpr int TAB_T   = 1024;                   // filter lookup rows (L2-resident)

typedef _Float16 f16;
typedef __attribute__((ext_vector_type(2))) _Float16 f16x2;
typedef __attribute__((ext_vector_type(8))) _Float16 f16x8;
typedef __attribute__((ext_vector_type(4))) float f32x4;

__device__ __forceinline__ void storev(float* p, float v) { *p = v; }
__device__ __forceinline__ void storev(f16* p, float v)   { *p = (f16)v; }

// ---------------- CSR build ----------------
__global__ void k_hist(const int* __restrict__ idx_i, int* __restrict__ cnt) {
  int e = blockIdx.x * 256 + threadIdx.x;
  if (e < N_EDGES) atomicAdd(&cnt[idx_i[e]], 1);
}

__global__ void k_scan_blk(const int* __restrict__ cnt, int* __restrict__ incl,
                           int* __restrict__ bsum) {
  __shared__ int buf[256];
  int t = threadIdx.x;
  int i = blockIdx.x * 256 + t;
  int v = (i < N_NODES) ? cnt[i] : 0;
  buf[t] = v;
  __syncthreads();
  #pragma unroll
  for (int off = 1; off < 256; off <<= 1) {
    int x = (t >= off) ? buf[t - off] : 0;
    __syncthreads();
    buf[t] += x;
    __syncthreads();
  }
  if (i < N_NODES) incl[i] = buf[t];
  if (t == 255) bsum[blockIdx.x] = buf[255];
}

__global__ void k_scan_top(int* __restrict__ bsum) {
  __shared__ int buf[128];
  int t = threadIdx.x;
  int v = (t < NB_SCAN) ? bsum[t] : 0;
  buf[t] = v;
  __syncthreads();
  #pragma unroll
  for (int off = 1; off < 128; off <<= 1) {
    int x = (t >= off) ? buf[t - off] : 0;
    __syncthreads();
    buf[t] += x;
    __syncthreads();
  }
  if (t <= NB_SCAN) bsum[t] = buf[t] - v;  // exclusive; t==NB_SCAN -> total
}

__global__ void k_scan_add(const int* __restrict__ cnt, const int* __restrict__ incl,
                           const int* __restrict__ bsum, int* __restrict__ rs) {
  int i = blockIdx.x * 256 + threadIdx.x;
  if (i < N_NODES) rs[i] = bsum[blockIdx.x] + incl[i] - cnt[i];
  if (i == 0) rs[N_NODES] = bsum[NB_SCAN];
}

__global__ void k_fill(const int* __restrict__ idx_i, int* __restrict__ cur, int* __restrict__ eidx) {
  int e = blockIdx.x * 256 + threadIdx.x;
  if (e < N_EDGES) {
    int p = atomicAdd(&cur[idx_i[e]], 1);
    eidx[p] = e;
  }
}

// ---------------- edge geometry, CSR-permuted; geo = {d, dx, dy, dz} ----------------
__global__ void k_edge_geom(const float* __restrict__ pos, const int* __restrict__ idx_all,
                            const int* __restrict__ eidx, float4* __restrict__ geo,
                            int* __restrict__ jperm) {
  int p = blockIdx.x * 256 + threadIdx.x;
  if (p >= N_EDGES) return;
  int e = eidx[p];
  int i = idx_all[e];
  int j = idx_all[N_EDGES + e];
  float rx = pos[j*3+0] - pos[i*3+0];
  float ry = pos[j*3+1] - pos[i*3+1];
  float rz = pos[j*3+2] - pos[i*3+2];
  float d = sqrtf(rx*rx + ry*ry + rz*rz);
  d = fmaxf(d, 1e-8f);
  float inv = 1.0f / d;
  geo[p] = make_float4(d, rx*inv, ry*inv, rz*inv);
  jperm[p] = j;
}

// ---------------- weight transpose+convert: Wt[n][k] = (f16)src[k][col0+n] ----------------
struct WJob { const float* src; f16* dst; int kshift; int ld; int col0; int nk; };
struct WJobs { WJob j[17]; };

__global__ void k_wt_all(WJobs jb) {
  WJob w = jb.j[blockIdx.y];
  int t = blockIdx.x * 256 + threadIdx.x;
  if (t >= w.nk) return;
  int K = 1 << w.kshift;
  int n = t >> w.kshift;
  int k = t & (K - 1);
  w.dst[t] = (f16)w.src[(size_t)k * w.ld + w.col0 + n];
}

// ---------------- filter lookup table: tab[t][n], t over d in [0,5] ----------------
__global__ __launch_bounds__(128) void k_tab(const f16* __restrict__ wt_f /*[384][64]*/,
                                             const float* __restrict__ bias,
                                             f16* __restrict__ tab) {
  __shared__ float ph[64];
  const int t = blockIdx.x;
  const float dist = 5.0f * (float)t / (float)(TAB_T - 1);
  const int tid = threadIdx.x;
  const float delta = 5.0f / 63.0f;
  const float coeff = -0.5f / (delta * delta);
  if (tid < 64) {
    float u = dist - delta * (float)tid;
    ph[tid] = expf(coeff * u * u);
  }
  __syncthreads();
  float xc = dist * 0.2f;
  float fc = (xc < 1.0f) ? 0.5f * (cosf((float)M_PI * xc) + 1.0f) : 0.0f;
  #pragma unroll
  for (int s = 0; s < 3; ++s) {
    int n = tid + s * 128;
    const f16* wr = wt_f + (size_t)n * 64;
    float acc = 0.f;
    #pragma unroll
    for (int k = 0; k < 64; ++k) acc += ph[k] * (float)wr[k];
    float v = (acc + bias[n]) * fc;
    v = fminf(fmaxf(v, -5.0f), 5.0f);
    tab[(size_t)t * 384 + n] = (f16)v;
  }
}

// ---------------- MFMA f16 GEMM (128-tile, LDS-staged A and B) ----------------
template<int EPI, typename AT, typename CT>
__global__ __launch_bounds__(256) void k_mgemm(
    const AT* __restrict__ A, const f16* __restrict__ Wt,
    const float* __restrict__ bias, CT* __restrict__ C,
    int M, int K, int ldc) {
  __shared__ f16 As[128 * 32];
  __shared__ f16 Bs[128 * 32];
  const int bm = blockIdx.x * 128;
  const int bn = blockIdx.y * 128;
  const int tid = threadIdx.x;
  const int wave = tid >> 6, lane = tid & 63;
  const int wm = (wave & 1) * 64, wn = (wave >> 1) * 64;
  const int lr = lane & 15;
  const int lk = lane >> 4;
  const int srow = tid >> 1;
  const int sc0 = (tid & 1) * 2;
  const int sw = (srow >> 1) & 3;
  f32x4 acc[4][4] = {};
  for (int k0 = 0; k0 < K; k0 += 32) {
    {
      int gm = bm + srow;
      f16x8 c0, c1;
      if (gm < M) {
        if constexpr (sizeof(AT) == 2) {
          const f16* ap = (const f16*)A + (size_t)gm * K + k0 + sc0 * 8;
          c0 = *(const f16x8*)ap;
          c1 = *(const f16x8*)(ap + 8);
        } else {
          const float* ap = (const float*)A + (size_t)gm * K + k0 + sc0 * 8;
          float4 v0 = ((const float4*)ap)[0];
          float4 v1 = ((const float4*)ap)[1];
          float4 v2 = ((const float4*)ap)[2];
          float4 v3 = ((const float4*)ap)[3];
          c0[0]=(f16)v0.x; c0[1]=(f16)v0.y; c0[2]=(f16)v0.z; c0[3]=(f16)v0.w;
          c0[4]=(f16)v1.x; c0[5]=(f16)v1.y; c0[6]=(f16)v1.z; c0[7]=(f16)v1.w;
          c1[0]=(f16)v2.x; c1[1]=(f16)v2.y; c1[2]=(f16)v2.z; c1[3]=(f16)v2.w;
          c1[4]=(f16)v3.x; c1[5]=(f16)v3.y; c1[6]=(f16)v3.z; c1[7]=(f16)v3.w;
        }
      } else {
        #pragma unroll
        for (int u = 0; u < 8; ++u) { c0[u] = (f16)0.f; c1[u] = (f16)0.f; }
      }
      *(f16x8*)&As[srow * 32 + ((sc0 ^ sw) << 3)]       = c0;
      *(f16x8*)&As[srow * 32 + (((sc0 + 1) ^ sw) << 3)] = c1;
    }
    {
      const f16* bp = Wt + (size_t)(bn + srow) * K + k0 + sc0 * 8;
      f16x8 b0 = *(const f16x8*)bp;
      f16x8 b1 = *(const f16x8*)(bp + 8);
      *(f16x8*)&Bs[srow * 32 + ((sc0 ^ sw) << 3)]       = b0;
      *(f16x8*)&Bs[srow * 32 + (((sc0 + 1) ^ sw) << 3)] = b1;
    }
    __syncthreads();
    f16x8 af[4], bf[4];
    #pragma unroll
    for (int mt = 0; mt < 4; ++mt) {
      int r = wm + mt * 16 + lr;
      af[mt] = *(const f16x8*)&As[r * 32 + ((lk ^ ((r >> 1) & 3)) << 3)];
    }
    #pragma unroll
    for (int nt = 0; nt < 4; ++nt) {
      int r = wn + nt * 16 + lr;
      bf[nt] = *(const f16x8*)&Bs[r * 32 + ((lk ^ ((r >> 1) & 3)) << 3)];
    }
    #pragma unroll
    for (int mt = 0; mt < 4; ++mt)
      #pragma unroll
      for (int nt = 0; nt < 4; ++nt)
        acc[mt][nt] = __builtin_amdgcn_mfma_f32_16x16x32_f16(af[mt], bf[nt], acc[mt][nt], 0, 0, 0);
    __syncthreads();
  }
  #pragma unroll
  for (int mt = 0; mt < 4; ++mt) {
    int gm0 = bm + wm + mt * 16 + lk * 4;
    #pragma unroll
    for (int nt = 0; nt < 4; ++nt) {
      int gn = bn + wn + nt * 16 + lr;
      float bv = bias ? bias[gn] : 0.0f;
      #pragma unroll
      for (int rr = 0; rr < 4; ++rr) {
        int gm = gm0 + rr;
        if (gm >= M) continue;
        float v = acc[mt][nt][rr] + bv;
        if (EPI == 1) v = v / (1.0f + expf(-v));
        storev(&C[(size_t)gm * ldc + gn], v);
      }
    }
  }
}

// ======== fused inter MLP: x = silu(q@W1^T+b1)@W2^T+b2, 64-row tiles ========
__global__ __launch_bounds__(256) void k_fused_i(
    const float* __restrict__ q, const f16* __restrict__ W1, const float* __restrict__ b1,
    const f16* __restrict__ W2, const float* __restrict__ b2,
    f16* __restrict__ xout, int M) {
  __shared__ f16 As[64 * 32];
  __shared__ f16 Hs[64 * 132];
  const int tid = threadIdx.x;
  const int wave = tid >> 6, lane = tid & 63;
  const int wm = (wave & 1) * 32, wn = (wave >> 1) * 64;
  const int lr = lane & 15, lk = lane >> 4;
  const int srow = tid >> 2, c8 = tid & 3;
  const int sw = (srow >> 1) & 3;
  const int bm = blockIdx.x * 64;
  f32x4 acc[2][4] = {};
  for (int k0 = 0; k0 < 128; k0 += 32) {
    {
      int gm = bm + srow;
      f16x8 c0;
      if (gm < M) {
        const float* ap = q + (size_t)gm * 128 + k0 + c8 * 8;
        float4 v0 = ((const float4*)ap)[0];
        float4 v1 = ((const float4*)ap)[1];
        c0[0]=(f16)v0.x; c0[1]=(f16)v0.y; c0[2]=(f16)v0.z; c0[3]=(f16)v0.w;
        c0[4]=(f16)v1.x; c0[5]=(f16)v1.y; c0[6]=(f16)v1.z; c0[7]=(f16)v1.w;
      } else {
        #pragma unroll
        for (int u = 0; u < 8; ++u) c0[u] = (f16)0.f;
      }
      *(f16x8*)&As[srow * 32 + ((c8 ^ sw) << 3)] = c0;
    }
    __syncthreads();
    f16x8 af[2], bf[4];
    #pragma unroll
    for (int mt = 0; mt < 2; ++mt) {
      int r = wm + mt * 16 + lr;
      af[mt] = *(const f16x8*)&As[r * 32 + ((lk ^ ((r >> 1) & 3)) << 3)];
    }
    #pragma unroll
    for (int nt = 0; nt < 4; ++nt)
      bf[nt] = *(const f16x8*)&W1[(size_t)(wn + nt * 16 + lr) * 128 + k0 + lk * 8];
    #pragma unroll
    for (int mt = 0; mt < 2; ++mt)
      #pragma unroll
      for (int nt = 0; nt < 4; ++nt)
        acc[mt][nt] = __builtin_amdgcn_mfma_f32_16x16x32_f16(af[mt], bf[nt], acc[mt][nt], 0, 0, 0);
    __syncthreads();
  }
  #pragma unroll
  for (int mt = 0; mt < 2; ++mt)
    #pragma unroll
    for (int nt = 0; nt < 4; ++nt) {
      int col = wn + nt * 16 + lr;
      float bv = b1[col];
      #pragma unroll
      for (int rr = 0; rr < 4; ++rr) {
        int row = wm + mt * 16 + lk * 4 + rr;
        float v = acc[mt][nt][rr] + bv;
        v = v / (1.0f + expf(-v));
        Hs[row * 132 + col] = (f16)v;
      }
    }
  __syncthreads();
  #pragma unroll
  for (int cc = 0; cc < 3; ++cc) {
    f32x4 a2[2][4] = {};
    for (int k0 = 0; k0 < 128; k0 += 32) {
      f16x8 af2[2], bf2[4];
      #pragma unroll
      for (int mt = 0; mt < 2; ++mt)
        af2[mt] = *(const f16x8*)&Hs[(wm + mt * 16 + lr) * 132 + k0 + lk * 8];
      #pragma unroll
      for (int nt = 0; nt < 4; ++nt)
        bf2[nt] = *(const f16x8*)&W2[(size_t)(cc * 128 + wn + nt * 16 + lr) * 128 + k0 + lk * 8];
      #pragma unroll
      for (int mt = 0; mt < 2; ++mt)
        #pragma unroll
        for (int nt = 0; nt < 4; ++nt)
          a2[mt][nt] = __builtin_amdgcn_mfma_f32_16x16x32_f16(af2[mt], bf2[nt], a2[mt][nt], 0, 0, 0);
    }
    #pragma unroll
    for (int mt = 0; mt < 2; ++mt)
      #pragma unroll
      for (int nt = 0; nt < 4; ++nt) {
        int gn = cc * 128 + wn + nt * 16 + lr;
        float bv = b2[gn];
        #pragma unroll
        for (int rr = 0; rr < 4; ++rr) {
          int gm = bm + wm + mt * 16 + lk * 4 + rr;
          if (gm >= M) continue;
          xout[(size_t)gm * 384 + gn] = (f16)(a2[mt][nt][rr] + bv);
        }
      }
  }
}

// ======== fused mix MLP + update (vn computed in A-stage, svw in epilogue) ========
// q fp32 [M][128] (read+update); mumix f16 [M][768]; W1 [128][256]; W2 [384][128]
__global__ __launch_bounds__(256) void k_fused_x(
    float* __restrict__ q,
    const f16* __restrict__ W1, const float* __restrict__ b1,
    const f16* __restrict__ W2, const float* __restrict__ b2,
    const f16* __restrict__ mumix, f16* __restrict__ mu, int M) {
  __shared__ f16 As[64 * 32];
  __shared__ f16 Hs[64 * 132];
  const int tid = threadIdx.x;
  const int wave = tid >> 6, lane = tid & 63;
  const int wm = (wave & 1) * 32, wn = (wave >> 1) * 64;
  const int lr = lane & 15, lk = lane >> 4;
  const int srow = tid >> 2, c8 = tid & 3;
  const int sw = (srow >> 1) & 3;
  const int bm = blockIdx.x * 64;
  f32x4 acc[2][4] = {};
  for (int k0 = 0; k0 < 256; k0 += 32) {
    {
      int gm = bm + srow;
      int col = k0 + c8 * 8;
      f16x8 c0;
      if (gm >= M) {
        #pragma unroll
        for (int u = 0; u < 8; ++u) c0[u] = (f16)0.f;
      } else if (col < 128) {
        const float* src = q + (size_t)gm * 128 + col;
        float4 v0 = ((const float4*)src)[0];
        float4 v1 = ((const float4*)src)[1];
        c0[0]=(f16)v0.x; c0[1]=(f16)v0.y; c0[2]=(f16)v0.z; c0[3]=(f16)v0.w;
        c0[4]=(f16)v1.x; c0[5]=(f16)v1.y; c0[6]=(f16)v1.z; c0[7]=(f16)v1.w;
      } else {
        // vn channels col-128 .. col-121 from mumix V blocks
        const f16* mm = mumix + (size_t)gm * 768 + (col - 128);
        f16x8 V0 = *(const f16x8*)(mm);
        f16x8 V1 = *(const f16x8*)(mm + 256);
        f16x8 V2 = *(const f16x8*)(mm + 512);
        #pragma unroll
        for (int u = 0; u < 8; ++u) {
          float a = (float)V0[u], b_ = (float)V1[u], c = (float)V2[u];
          c0[u] = (f16)sqrtf(a*a + b_*b_ + c*c + 1e-8f);
        }
      }
      *(f16x8*)&As[srow * 32 + ((c8 ^ sw) << 3)] = c0;
    }
    __syncthreads();
    f16x8 af[2], bf[4];
    #pragma unroll
    for (int mt = 0; mt < 2; ++mt) {
      int r = wm + mt * 16 + lr;
      af[mt] = *(const f16x8*)&As[r * 32 + ((lk ^ ((r >> 1) & 3)) << 3)];
    }
    #pragma unroll
    for (int nt = 0; nt < 4; ++nt)
      bf[nt] = *(const f16x8*)&W1[(size_t)(wn + nt * 16 + lr) * 256 + k0 + lk * 8];
    #pragma unroll
    for (int mt = 0; mt < 2; ++mt)
      #pragma unroll
      for (int nt = 0; nt < 4; ++nt)
        acc[mt][nt] = __builtin_amdgcn_mfma_f32_16x16x32_f16(af[mt], bf[nt], acc[mt][nt], 0, 0, 0);
    __syncthreads();
  }
  #pragma unroll
  for (int mt = 0; mt < 2; ++mt)
    #pragma unroll
    for (int nt = 0; nt < 4; ++nt) {
      int col = wn + nt * 16 + lr;
      float bv = b1[col];
      #pragma unroll
      for (int rr = 0; rr < 4; ++rr) {
        int row = wm + mt * 16 + lk * 4 + rr;
        float v = acc[mt][nt][rr] + bv;
        v = v / (1.0f + expf(-v));
        Hs[row * 132 + col] = (f16)v;
      }
    }
  __syncthreads();
  f32x4 a2[3][2][4] = {};
  #pragma unroll
  for (int cc = 0; cc < 3; ++cc)
    for (int k0 = 0; k0 < 128; k0 += 32) {
      f16x8 af2[2], bf2[4];
      #pragma unroll
      for (int mt = 0; mt < 2; ++mt)
        af2[mt] = *(const f16x8*)&Hs[(wm + mt * 16 + lr) * 132 + k0 + lk * 8];
      #pragma unroll
      for (int nt = 0; nt < 4; ++nt)
        bf2[nt] = *(const f16x8*)&W2[(size_t)(cc * 128 + wn + nt * 16 + lr) * 128 + k0 + lk * 8];
      #pragma unroll
      for (int mt = 0; mt < 2; ++mt)
        #pragma unroll
        for (int nt = 0; nt < 4; ++nt)
          a2[cc][mt][nt] = __builtin_amdgcn_mfma_f32_16x16x32_f16(af2[mt], bf2[nt], a2[cc][mt][nt], 0, 0, 0);
    }
  // epilogue: mixupd on live registers; svw recomputed from mumix
  #pragma unroll
  for (int mt = 0; mt < 2; ++mt)
    #pragma unroll
    for (int nt = 0; nt < 4; ++nt) {
      int col = wn + nt * 16 + lr;
      float b_dq = b2[col], b_dmu = b2[128 + col], b_dqmu = b2[256 + col];
      #pragma unroll
      for (int rr = 0; rr < 4; ++rr) {
        int gm = bm + wm + mt * 16 + lk * 4 + rr;
        if (gm >= M) continue;
        float dq   = a2[0][mt][nt][rr] + b_dq;
        float dmu  = a2[1][mt][nt][rr] + b_dmu;
        float dqmu = a2[2][mt][nt][rr] + b_dqmu;
        const f16* mm = mumix + (size_t)gm * 768;
        float V0 = (float)mm[col],       W0 = (float)mm[128 + col];
        float V1 = (float)mm[256 + col], W1v = (float)mm[384 + col];
        float V2 = (float)mm[512 + col], W2v = (float)mm[640 + col];
        float svw = V0 * W0 + V1 * W1v + V2 * W2v;
        size_t qi = (size_t)gm * 128 + col;
        q[qi] += dq + dqmu * svw;
        f16* mr = mu + (size_t)gm * 384;
        mr[col]       = (f16)((float)mr[col]       + dmu * W0);
        mr[128 + col] = (f16)((float)mr[128 + col] + dmu * W1v);
        mr[256 + col] = (f16)((float)mr[256 + col] + dmu * W2v);
      }
    }
}

// ---------------- per-node edge reduction: wave per node, f16x2, 2x unroll ----------------
__global__ __launch_bounds__(256) void k_edge_msg(
    const int* __restrict__ rs, const int* __restrict__ jperm,
    const f16* __restrict__ x, const f16* __restrict__ tab,
    const float4* __restrict__ geo, const f16* __restrict__ mu_in,
    float* __restrict__ q, f16* __restrict__ mu_out) {
  const int wid  = threadIdx.x >> 6;
  const int lane = threadIdx.x & 63;
  const int i = blockIdx.x * 4 + wid;
  if (i >= N_NODES) return;
  const int d0 = lane * 2;
  const float scale = (float)(TAB_T - 1) / 5.0f;
  float aqx = 0.f, aqy = 0.f;
  float a0x = 0.f, a0y = 0.f, a1x = 0.f, a1y = 0.f, a2x = 0.f, a2y = 0.f;
  const int s = rs[i], e = rs[i + 1];

  auto body = [&](float dx, float dy, float dz,
                  f16x2 ta0, f16x2 ta1, f16x2 ta2, f16x2 tb0, f16x2 tb1, f16x2 tb2,
                  f16x2 xv0, f16x2 xv1, f16x2 xv2, f16x2 mv0, f16x2 mv1, f16x2 mv2,
                  float fr) {
    float fo = 1.0f - fr;
    float W0x = fo * (float)ta0[0] + fr * (float)tb0[0];
    float W0y = fo * (float)ta0[1] + fr * (float)tb0[1];
    float W1x = fo * (float)ta1[0] + fr * (float)tb1[0];
    float W1y = fo * (float)ta1[1] + fr * (float)tb1[1];
    float W2x = fo * (float)ta2[0] + fr * (float)tb2[0];
    float W2y = fo * (float)ta2[1] + fr * (float)tb2[1];
    float m1x = (float)xv1[0] * W1x, m1y = (float)xv1[1] * W1y;
    float m2x = (float)xv2[0] * W2x, m2y = (float)xv2[1] * W2y;
    aqx = fmaf((float)xv0[0], W0x, aqx);
    aqy = fmaf((float)xv0[1], W0y, aqy);
    a0x += m1x * dx + m2x * (float)mv0[0];
    a0y += m1y * dx + m2y * (float)mv0[1];
    a1x += m1x * dy + m2x * (float)mv1[0];
    a1y += m1y * dy + m2y * (float)mv1[1];
    a2x += m1x * dz + m2x * (float)mv2[0];
    a2y += m1y * dz + m2y * (float)mv2[1];
  };

  int p = s;
  for (; p + 2 <= e; p += 2) {
    int jA = jperm[p], jB = jperm[p + 1];
    float4 gA = geo[p], gB = geo[p + 1];
    float uA = fminf(gA.x, 5.0f) * scale;
    float uB = fminf(gB.x, 5.0f) * scale;
    int tA = min((int)uA, TAB_T - 2);
    int tB = min((int)uB, TAB_T - 2);
    float frA = uA - (float)tA, frB = uB - (float)tB;
    const f16* taA = tab + (size_t)tA * 384;
    const f16* taB = tab + (size_t)tB * 384;
    const f16* xjA = x + (size_t)jA * 384;
    const f16* xjB = x + (size_t)jB * 384;
    const f16* mjA = mu_in + (size_t)jA * 384;
    const f16* mjB = mu_in + (size_t)jB * 384;
    f16x2 tA0 = *(const f16x2*)(taA + d0);
    f16x2 tA1 = *(const f16x2*)(taA + 128 + d0);
    f16x2 tA2 = *(const f16x2*)(taA + 256 + d0);
    f16x2 tA3 = *(const f16x2*)(taA + 384 + d0);
    f16x2 tA4 = *(const f16x2*)(taA + 512 + d0);
    f16x2 tA5 = *(const f16x2*)(taA + 640 + d0);
    f16x2 xA0 = *(const f16x2*)(xjA + d0);
    f16x2 xA1 = *(const f16x2*)(xjA + 128 + d0);
    f16x2 xA2 = *(const f16x2*)(xjA + 256 + d0);
    f16x2 mA0 = *(const f16x2*)(mjA + d0);
    f16x2 mA1 = *(const f16x2*)(mjA + 128 + d0);
    f16x2 mA2 = *(const f16x2*)(mjA + 256 + d0);
    f16x2 tB0 = *(const f16x2*)(taB + d0);
    f16x2 tB1 = *(const f16x2*)(taB + 128 + d0);
    f16x2 tB2 = *(const f16x2*)(taB + 256 + d0);
    f16x2 tB3 = *(const f16x2*)(taB + 384 + d0);
    f16x2 tB4 = *(const f16x2*)(taB + 512 + d0);
    f16x2 tB5 = *(const f16x2*)(taB + 640 + d0);
    f16x2 xB0 = *(const f16x2*)(xjB + d0);
    f16x2 xB1 = *(const f16x2*)(xjB + 128 + d0);
    f16x2 xB2 = *(const f16x2*)(xjB + 256 + d0);
    f16x2 mB0 = *(const f16x2*)(mjB + d0);
    f16x2 mB1 = *(const f16x2*)(mjB + 128 + d0);
    f16x2 mB2 = *(const f16x2*)(mjB + 256 + d0);
    body(gA.y, gA.z, gA.w, tA0, tA1, tA2, tA3, tA4, tA5,
         xA0, xA1, xA2, mA0, mA1, mA2, frA);
    body(gB.y, gB.z, gB.w, tB0, tB1, tB2, tB3, tB4, tB5,
         xB0, xB1, xB2, mB0, mB1, mB2, frB);
  }
  for (; p < e; ++p) {
    int j = jperm[p];
    float4 g = geo[p];
    float u = fminf(g.x, 5.0f) * scale;
    int t0 = min((int)u, TAB_T - 2);
    float fr = u - (float)t0;
    const f16* ta = tab + (size_t)t0 * 384;
    const f16* xj = x + (size_t)j * 384;
    const f16* mj = mu_in + (size_t)j * 384;
    body(g.y, g.z, g.w,
         *(const f16x2*)(ta + d0), *(const f16x2*)(ta + 128 + d0), *(const f16x2*)(ta + 256 + d0),
         *(const f16x2*)(ta + 384 + d0), *(const f16x2*)(ta + 512 + d0), *(const f16x2*)(ta + 640 + d0),
         *(const f16x2*)(xj + d0), *(const f16x2*)(xj + 128 + d0), *(const f16x2*)(xj + 256 + d0),
         *(const f16x2*)(mj + d0), *(const f16x2*)(mj + 128 + d0), *(const f16x2*)(mj + 256 + d0),
         fr);
  }

  float* qp = q + (size_t)i * 128 + d0;
  float2 qv = *(float2*)qp;
  qv.x += aqx; qv.y += aqy;
  *(float2*)qp = qv;
  const f16* min_ = mu_in + (size_t)i * 384;
  f16* mout = mu_out + (size_t)i * 384;
  f16x2 o0, o1, o2;
  f16x2 i0 = *(const f16x2*)(min_ + d0);
  f16x2 i1 = *(const f16x2*)(min_ + 128 + d0);
  f16x2 i2 = *(const f16x2*)(min_ + 256 + d0);
  o0[0] = (f16)((float)i0[0] + a0x); o0[1] = (f16)((float)i0[1] + a0y);
  o1[0] = (f16)((float)i1[0] + a1x); o1[1] = (f16)((float)i1[1] + a1y);
  o2[0] = (f16)((float)i2[0] + a2x); o2[1] = (f16)((float)i2[1] + a2y);
  *(f16x2*)(mout + d0)       = o0;
  *(f16x2*)(mout + 128 + d0) = o1;
  *(f16x2*)(mout + 256 + d0) = o2;
}

// ---------------- final outputs ----------------
__global__ __launch_bounds__(256) void k_posattr(
    const int* __restrict__ rs, const int* __restrict__ jperm,
    const f16* __restrict__ mu, const float* __restrict__ w, float* __restrict__ pos_out) {
  const int wid  = threadIdx.x >> 6;
  const int lane = threadIdx.x & 63;
  const int i = blockIdx.x * 4 + wid;
  if (i >= N_NODES) return;
  const int d0 = lane * 2;
  float a0x = 0.f, a0y = 0.f, a1x = 0.f, a1y = 0.f, a2x = 0.f, a2y = 0.f;
  const int s = rs[i], e = rs[i + 1];
  int p = s;
  for (; p + 2 <= e; p += 2) {
    int jA = jperm[p], jB = jperm[p + 1];
    const f16* mA = mu + (size_t)jA * 384;
    const f16* mB = mu + (size_t)jB * 384;
    f16x2 A0 = *(const f16x2*)(mA + d0);
    f16x2 A1 = *(const f16x2*)(mA + 128 + d0);
    f16x2 A2 = *(const f16x2*)(mA + 256 + d0);
    f16x2 B0 = *(const f16x2*)(mB + d0);
    f16x2 B1 = *(const f16x2*)(mB + 128 + d0);
    f16x2 B2 = *(const f16x2*)(mB + 256 + d0);
    a0x += (float)A0[0] + (float)B0[0]; a0y += (float)A0[1] + (float)B0[1];
    a1x += (float)A1[0] + (float)B1[0]; a1y += (float)A1[1] + (float)B1[1];
    a2x += (float)A2[0] + (float)B2[0]; a2y += (float)A2[1] + (float)B2[1];
  }
  for (; p < e; ++p) {
    int j = jperm[p];
    const f16* mj = mu + (size_t)j * 384;
    f16x2 A0 = *(const f16x2*)(mj + d0);
    f16x2 A1 = *(const f16x2*)(mj + 128 + d0);
    f16x2 A2 = *(const f16x2*)(mj + 256 + d0);
    a0x += (float)A0[0]; a0y += (float)A0[1];
    a1x += (float)A1[0]; a1y += (float)A1[1];
    a2x += (float)A2[0]; a2y += (float)A2[1];
  }
  float wx = w[d0], wy = w[d0 + 1];
  float s0 = fminf(fmaxf(a0x, -5.f), 5.f) * wx + fminf(fmaxf(a0y, -5.f), 5.f) * wy;
  float s1 = fminf(fmaxf(a1x, -5.f), 5.f) * wx + fminf(fmaxf(a1y, -5.f), 5.f) * wy;
  float s2 = fminf(fmaxf(a2x, -5.f), 5.f) * wx + fminf(fmaxf(a2y, -5.f), 5.f) * wy;
  #pragma unroll
  for (int off = 32; off > 0; off >>= 1) {
    s0 += __shfl_down(s0, off, 64);
    s1 += __shfl_down(s1, off, 64);
    s2 += __shfl_down(s2, off, 64);
  }
  if (lane == 0) {
    pos_out[(size_t)i * 3 + 0] = fminf(fmaxf(s0, -5.f), 5.f);
    pos_out[(size_t)i * 3 + 1] = fminf(fmaxf(s1, -5.f), 5.f);
    pos_out[(size_t)i * 3 + 2] = fminf(fmaxf(s2, -5.f), 5.f);
  }
}

// ---------------- LayerNorm+tanh: wave per node ----------------
__global__ __launch_bounds__(256) void k_ln(const float* __restrict__ q, const float* __restrict__ g,
                                            const float* __restrict__ b, float* __restrict__ out) {
  const int wid = threadIdx.x >> 6, lane = threadIdx.x & 63;
  const int n = blockIdx.x * 4 + wid;
  if (n >= N_NODES) return;
  const int d0 = lane * 2;
  float2 v = *(const float2*)(q + (size_t)n * 128 + d0);
  float v0 = fminf(fmaxf(v.x, -5.f), 5.f);
  float v1 = fminf(fmaxf(v.y, -5.f), 5.f);
  float s = v0 + v1, s2 = v0 * v0 + v1 * v1;
  #pragma unroll
  for (int off = 32; off > 0; off >>= 1) {
    s  += __shfl_down(s,  off, 64);
    s2 += __shfl_down(s2, off, 64);
  }
  s  = __shfl(s,  0, 64);
  s2 = __shfl(s2, 0, 64);
  float mean = s * (1.0f / 128.0f);
  float var  = s2 * (1.0f / 128.0f) - mean * mean;
  float r = rsqrtf(var + 1e-5f);
  out[(size_t)n * 128 + d0]     = tanhf((v0 - mean) * r * g[d0]     + b[d0]);
  out[(size_t)n * 128 + d0 + 1] = tanhf((v1 - mean) * r * g[d0 + 1] + b[d0 + 1]);
}

extern "C" void kernel_launch(void* const* d_in, const int* in_sizes, int n_in,
                              void* d_out, int out_size, void* d_ws, size_t ws_size,
                              hipStream_t stream) {
  const float* z         = (const float*)d_in[0];
  const float* pos       = (const float*)d_in[1];
  const int*   edge_idx  = (const int*)d_in[2];
  const float* in_w      = (const float*)d_in[3];
  const float* in_b      = (const float*)d_in[4];
  const float* filt_w    = (const float*)d_in[5];
  const float* filt_b    = (const float*)d_in[6];
  const float* inter_w1  = (const float*)d_in[7];
  const float* inter_b1  = (const float*)d_in[8];
  const float* inter_w2  = (const float*)d_in[9];
  const float* inter_b2  = (const float*)d_in[10];
  const float* mix_mu_w  = (const float*)d_in[11];
  const float* mix_w1    = (const float*)d_in[12];
  const float* mix_b1    = (const float*)d_in[13];
  const float* mix_w2    = (const float*)d_in[14];
  const float* mix_b2    = (const float*)d_in[15];
  const float* mu_proj_w = (const float*)d_in[16];
  const float* ln_g      = (const float*)d_in[17];
  const float* ln_b      = (const float*)d_in[18];

  char* base = (char*)d_ws;
  size_t off = 0;
  auto alloc = [&](size_t bytes) -> char* {
    char* p = base + off;
    off += (bytes + 255) & ~(size_t)255;
    return p;
  };
  float*  q     = (float*)alloc((size_t)N_NODES * 128 * 4);
  f16*    x16   = (f16*)alloc((size_t)N_NODES * 384 * 2);
  f16*    mu_a  = (f16*)alloc((size_t)N_NODES * 384 * 2);
  f16*    mu_b  = (f16*)alloc((size_t)N_NODES * 384 * 2);
  f16*    mumix = (f16*)alloc((size_t)N_NODES * 768 * 2);
  float4* geo   = (float4*)alloc((size_t)N_EDGES * 16);
  int*    cnt   = (int*)alloc((size_t)N_NODES * 4);
  int*    incl  = (int*)alloc((size_t)N_NODES * 4);
  int*    bsum  = (int*)alloc(128 * 4);
  int*    rs    = (int*)alloc((size_t)(N_NODES + 1) * 4);
  int*    cur   = (int*)alloc((size_t)N_NODES * 4);
  int*    eidx  = (int*)alloc((size_t)N_EDGES * 4);
  int*    jperm = (int*)alloc((size_t)N_EDGES * 4);
  f16*    tab   = (f16*)alloc((size_t)TAB_T * 384 * 2);
  // f16 transposed weights
  f16* wt_in = (f16*)alloc((size_t)128 * 64 * 2);
  f16* wt_f  = (f16*)alloc((size_t)384 * 64 * 2);
  f16* wt_i1 = (f16*)alloc((size_t)3 * 128 * 128 * 2);
  f16* wt_i2 = (f16*)alloc((size_t)3 * 384 * 128 * 2);
  f16* wt_mu = (f16*)alloc((size_t)3 * 256 * 128 * 2);
  f16* wt_x1 = (f16*)alloc((size_t)3 * 128 * 256 * 2);
  f16* wt_x2 = (f16*)alloc((size_t)3 * 384 * 128 * 2);
  if (off > ws_size) return;

  float* out_node = (float*)d_out;
  float* out_pos  = (float*)d_out + (size_t)N_NODES * 128;

  // ---- weight prep (f16, [N][K]) ----
  {
    WJobs jb;
    int ji = 0;
    jb.j[ji++] = {in_w,   wt_in, 6, 128, 0, 128 * 64};
    jb.j[ji++] = {filt_w, wt_f,  6, 384, 0, 384 * 64};
    for (int l = 0; l < 3; ++l)
      jb.j[ji++] = {inter_w1 + (size_t)l*128*128, wt_i1 + (size_t)l*128*128, 7, 128, 0, 128*128};
    for (int l = 0; l < 3; ++l)
      jb.j[ji++] = {inter_w2 + (size_t)l*128*384, wt_i2 + (size_t)l*384*128, 7, 384, 0, 384*128};
    for (int l = 0; l < 3; ++l)
      jb.j[ji++] = {mix_mu_w + (size_t)l*128*256, wt_mu + (size_t)l*256*128, 7, 256, 0, 256*128};
    for (int l = 0; l < 3; ++l)
      jb.j[ji++] = {mix_w1 + (size_t)l*256*128, wt_x1 + (size_t)l*128*256, 8, 128, 0, 128*256};
    for (int l = 0; l < 3; ++l)
      jb.j[ji++] = {mix_w2 + (size_t)l*128*384, wt_x2 + (size_t)l*384*128, 7, 384, 0, 384*128};
    dim3 g(192, 17);
    k_wt_all<<<g, 256, 0, stream>>>(jb);
  }

  // ---- filter lookup table ----
  k_tab<<<TAB_T, 128, 0, stream>>>(wt_f, filt_b, tab);

  // ---- CSR build ----
  hipMemsetAsync(cnt, 0, (size_t)N_NODES * 4, stream);
  k_hist<<<N_EDGES / 256, 256, 0, stream>>>(edge_idx, cnt);
  k_scan_blk<<<NB_SCAN, 256, 0, stream>>>(cnt, incl, bsum);
  k_scan_top<<<1, 128, 0, stream>>>(bsum);
  k_scan_add<<<NB_SCAN, 256, 0, stream>>>(cnt, incl, bsum, rs);
  hipMemcpyAsync(cur, rs, (size_t)N_NODES * 4, hipMemcpyDeviceToDevice, stream);
  k_fill<<<N_EDGES / 256, 256, 0, stream>>>(edge_idx, cur, eidx);

  // ---- edge geometry (CSR-permuted) ----
  k_edge_geom<<<N_EDGES / 256, 256, 0, stream>>>(pos, edge_idx, eidx, geo, jperm);

  // ---- input embedding ----
  dim3 ge((N_NODES + 127) / 128, 1);
  dim3 gv((N_NODES * 3 + 127) / 128, 2);
  k_mgemm<1, float, float><<<ge, 256, 0, stream>>>(z, wt_in, in_b, q, N_NODES, 64, 128);
  hipMemsetAsync(mu_a, 0, (size_t)N_NODES * 384 * 2, stream);

  f16* mu_cur = mu_a;
  f16* mu_nxt = mu_b;
  const int gn4 = (N_NODES + 3) / 4;
  const int gf  = (N_NODES + 63) / 64;  // 313 blocks
  for (int l = 0; l < NLAYER; ++l) {
    k_fused_i<<<gf, 256, 0, stream>>>(q, wt_i1 + (size_t)l*128*128, inter_b1 + (size_t)l*128,
                                      wt_i2 + (size_t)l*384*128, inter_b2 + (size_t)l*384,
                                      x16, N_NODES);
    k_edge_msg<<<gn4, 256, 0, stream>>>(rs, jperm, x16, tab, geo, mu_cur, q, mu_nxt);
    { f16* t = mu_cur; mu_cur = mu_nxt; mu_nxt = t; }
    // mumix: [3N][128] @ [256][128]^T -> [3N][256] (V cols 0-127, W cols 128-255)
    k_mgemm<0, f16, f16><<<gv, 256, 0, stream>>>(mu_cur, wt_mu + (size_t)l*256*128, nullptr,
                                                 mumix, N_NODES * 3, 128, 256);
    k_fused_x<<<gf, 256, 0, stream>>>(q,
                                      wt_x1 + (size_t)l*128*256, mix_b1 + (size_t)l*128,
                                      wt_x2 + (size_t)l*384*128, mix_b2 + (size_t)l*384,
                                      mumix, mu_cur, N_NODES);
  }

  // ---- outputs ----
  k_posattr<<<gn4, 256, 0, stream>>>(rs, jperm, mu_cur, mu_proj_w, out_pos);
  k_ln<<<gn4, 256, 0, stream>>>(q, ln_g, ln_b, out_node);
}

// Round 9
// 613.517 us; speedup vs baseline: 4.0556x; 1.0813x over previous
//
#include <hip/hip_runtime.h>
#include <math.h>

#ifndef M_PI
#define M_PI 3.14159265358979323846
#endif

static constexpr int N_NODES = 20000;
static constexpr int N_EDGES = 320000;
static constexpr int NLAYER  = 3;
static constexpr int NB_SCAN = (N_NODES + 255) / 256;  // 79
static constexpr int TAB_T   = 1024;                   // filter lookup rows (L2-resident)

typedef _Float16 f16;
typedef __attribute__((ext_vector_type(2))) _Float16 f16x2;
typedef __attribute__((ext_vector_type(8))) _Float16 f16x8;
typedef __attribute__((ext_vector_type(4))) float f32x4;

__device__ __forceinline__ void storev(float* p, float v) { *p = v; }
__device__ __forceinline__ void storev(f16* p, float v)   { *p = (f16)v; }

// ---------------- CSR build ----------------
__global__ void k_hist(const int* __restrict__ idx_i, int* __restrict__ cnt) {
  int e = blockIdx.x * 256 + threadIdx.x;
  if (e < N_EDGES) atomicAdd(&cnt[idx_i[e]], 1);
}

__global__ void k_scan_blk(const int* __restrict__ cnt, int* __restrict__ incl,
                           int* __restrict__ bsum) {
  __shared__ int buf[256];
  int t = threadIdx.x;
  int i = blockIdx.x * 256 + t;
  int v = (i < N_NODES) ? cnt[i] : 0;
  buf[t] = v;
  __syncthreads();
  #pragma unroll
  for (int off = 1; off < 256; off <<= 1) {
    int x = (t >= off) ? buf[t - off] : 0;
    __syncthreads();
    buf[t] += x;
    __syncthreads();
  }
  if (i < N_NODES) incl[i] = buf[t];
  if (t == 255) bsum[blockIdx.x] = buf[255];
}

__global__ void k_scan_top(int* __restrict__ bsum) {
  __shared__ int buf[128];
  int t = threadIdx.x;
  int v = (t < NB_SCAN) ? bsum[t] : 0;
  buf[t] = v;
  __syncthreads();
  #pragma unroll
  for (int off = 1; off < 128; off <<= 1) {
    int x = (t >= off) ? buf[t - off] : 0;
    __syncthreads();
    buf[t] += x;
    __syncthreads();
  }
  if (t <= NB_SCAN) bsum[t] = buf[t] - v;  // exclusive; t==NB_SCAN -> total
}

__global__ void k_scan_add(const int* __restrict__ cnt, const int* __restrict__ incl,
                           const int* __restrict__ bsum, int* __restrict__ rs,
                           int* __restrict__ cur) {
  int i = blockIdx.x * 256 + threadIdx.x;
  if (i < N_NODES) {
    int v = bsum[blockIdx.x] + incl[i] - cnt[i];
    rs[i] = v;
    cur[i] = v;
  }
  if (i == 0) rs[N_NODES] = bsum[NB_SCAN];
}

__global__ void k_fill(const int* __restrict__ idx_i, int* __restrict__ cur, int* __restrict__ eidx) {
  int e = blockIdx.x * 256 + threadIdx.x;
  if (e < N_EDGES) {
    int p = atomicAdd(&cur[idx_i[e]], 1);
    eidx[p] = e;
  }
}

// ---------------- edge geometry, CSR-permuted; geo = {d, dx, dy, dz} ----------------
__global__ void k_edge_geom(const float* __restrict__ pos, const int* __restrict__ idx_all,
                            const int* __restrict__ eidx, float4* __restrict__ geo,
                            int* __restrict__ jperm) {
  int p = blockIdx.x * 256 + threadIdx.x;
  if (p >= N_EDGES) return;
  int e = eidx[p];
  int i = idx_all[e];
  int j = idx_all[N_EDGES + e];
  float rx = pos[j*3+0] - pos[i*3+0];
  float ry = pos[j*3+1] - pos[i*3+1];
  float rz = pos[j*3+2] - pos[i*3+2];
  float d = sqrtf(rx*rx + ry*ry + rz*rz);
  d = fmaxf(d, 1e-8f);
  float inv = 1.0f / d;
  geo[p] = make_float4(d, rx*inv, ry*inv, rz*inv);
  jperm[p] = j;
}

// ---------------- weight transpose+convert: Wt[n][k] = (f16)src[k][col0+n] ----------------
struct WJob { const float* src; f16* dst; int kshift; int ld; int col0; int nk; };
struct WJobs { WJob j[17]; };

__global__ void k_wt_all(WJobs jb) {
  WJob w = jb.j[blockIdx.y];
  int t = blockIdx.x * 256 + threadIdx.x;
  if (t >= w.nk) return;
  int K = 1 << w.kshift;
  int n = t >> w.kshift;
  int k = t & (K - 1);
  w.dst[t] = (f16)w.src[(size_t)k * w.ld + w.col0 + n];
}

// ---------------- filter lookup table: tab[t][n], t over d in [0,5] ----------------
__global__ __launch_bounds__(128) void k_tab(const f16* __restrict__ wt_f /*[384][64]*/,
                                             const float* __restrict__ bias,
                                             f16* __restrict__ tab) {
  __shared__ float ph[64];
  const int t = blockIdx.x;
  const float dist = 5.0f * (float)t / (float)(TAB_T - 1);
  const int tid = threadIdx.x;
  const float delta = 5.0f / 63.0f;
  const float coeff = -0.5f / (delta * delta);
  if (tid < 64) {
    float u = dist - delta * (float)tid;
    ph[tid] = expf(coeff * u * u);
  }
  __syncthreads();
  float xc = dist * 0.2f;
  float fc = (xc < 1.0f) ? 0.5f * (cosf((float)M_PI * xc) + 1.0f) : 0.0f;
  #pragma unroll
  for (int s = 0; s < 3; ++s) {
    int n = tid + s * 128;
    const f16* wr = wt_f + (size_t)n * 64;
    float acc = 0.f;
    #pragma unroll
    for (int k = 0; k < 64; ++k) acc += ph[k] * (float)wr[k];
    float v = (acc + bias[n]) * fc;
    v = fminf(fmaxf(v, -5.0f), 5.0f);
    tab[(size_t)t * 384 + n] = (f16)v;
  }
}

// ---------------- MFMA f16 GEMM (embed only) ----------------
template<int EPI, typename AT, typename CT>
__global__ __launch_bounds__(256) void k_mgemm(
    const AT* __restrict__ A, const f16* __restrict__ Wt,
    const float* __restrict__ bias, CT* __restrict__ C,
    int M, int K, int ldc) {
  __shared__ f16 As[128 * 32];
  __shared__ f16 Bs[128 * 32];
  const int bm = blockIdx.x * 128;
  const int bn = blockIdx.y * 128;
  const int tid = threadIdx.x;
  const int wave = tid >> 6, lane = tid & 63;
  const int wm = (wave & 1) * 64, wn = (wave >> 1) * 64;
  const int lr = lane & 15;
  const int lk = lane >> 4;
  const int srow = tid >> 1;
  const int sc0 = (tid & 1) * 2;
  const int sw = (srow >> 1) & 3;
  f32x4 acc[4][4] = {};
  for (int k0 = 0; k0 < K; k0 += 32) {
    {
      int gm = bm + srow;
      f16x8 c0, c1;
      if (gm < M) {
        if constexpr (sizeof(AT) == 2) {
          const f16* ap = (const f16*)A + (size_t)gm * K + k0 + sc0 * 8;
          c0 = *(const f16x8*)ap;
          c1 = *(const f16x8*)(ap + 8);
        } else {
          const float* ap = (const float*)A + (size_t)gm * K + k0 + sc0 * 8;
          float4 v0 = ((const float4*)ap)[0];
          float4 v1 = ((const float4*)ap)[1];
          float4 v2 = ((const float4*)ap)[2];
          float4 v3 = ((const float4*)ap)[3];
          c0[0]=(f16)v0.x; c0[1]=(f16)v0.y; c0[2]=(f16)v0.z; c0[3]=(f16)v0.w;
          c0[4]=(f16)v1.x; c0[5]=(f16)v1.y; c0[6]=(f16)v1.z; c0[7]=(f16)v1.w;
          c1[0]=(f16)v2.x; c1[1]=(f16)v2.y; c1[2]=(f16)v2.z; c1[3]=(f16)v2.w;
          c1[4]=(f16)v3.x; c1[5]=(f16)v3.y; c1[6]=(f16)v3.z; c1[7]=(f16)v3.w;
        }
      } else {
        #pragma unroll
        for (int u = 0; u < 8; ++u) { c0[u] = (f16)0.f; c1[u] = (f16)0.f; }
      }
      *(f16x8*)&As[srow * 32 + ((sc0 ^ sw) << 3)]       = c0;
      *(f16x8*)&As[srow * 32 + (((sc0 + 1) ^ sw) << 3)] = c1;
    }
    {
      const f16* bp = Wt + (size_t)(bn + srow) * K + k0 + sc0 * 8;
      f16x8 b0 = *(const f16x8*)bp;
      f16x8 b1 = *(const f16x8*)(bp + 8);
      *(f16x8*)&Bs[srow * 32 + ((sc0 ^ sw) << 3)]       = b0;
      *(f16x8*)&Bs[srow * 32 + (((sc0 + 1) ^ sw) << 3)] = b1;
    }
    __syncthreads();
    f16x8 af[4], bf[4];
    #pragma unroll
    for (int mt = 0; mt < 4; ++mt) {
      int r = wm + mt * 16 + lr;
      af[mt] = *(const f16x8*)&As[r * 32 + ((lk ^ ((r >> 1) & 3)) << 3)];
    }
    #pragma unroll
    for (int nt = 0; nt < 4; ++nt) {
      int r = wn + nt * 16 + lr;
      bf[nt] = *(const f16x8*)&Bs[r * 32 + ((lk ^ ((r >> 1) & 3)) << 3)];
    }
    #pragma unroll
    for (int mt = 0; mt < 4; ++mt)
      #pragma unroll
      for (int nt = 0; nt < 4; ++nt)
        acc[mt][nt] = __builtin_amdgcn_mfma_f32_16x16x32_f16(af[mt], bf[nt], acc[mt][nt], 0, 0, 0);
    __syncthreads();
  }
  #pragma unroll
  for (int mt = 0; mt < 4; ++mt) {
    int gm0 = bm + wm + mt * 16 + lk * 4;
    #pragma unroll
    for (int nt = 0; nt < 4; ++nt) {
      int gn = bn + wn + nt * 16 + lr;
      float bv = bias ? bias[gn] : 0.0f;
      #pragma unroll
      for (int rr = 0; rr < 4; ++rr) {
        int gm = gm0 + rr;
        if (gm >= M) continue;
        float v = acc[mt][nt][rr] + bv;
        if (EPI == 1) v = v / (1.0f + expf(-v));
        storev(&C[(size_t)gm * ldc + gn], v);
      }
    }
  }
}

// ======== fused inter MLP: x = silu(q@W1^T+b1)@W2^T+b2, 64-row tiles ========
__global__ __launch_bounds__(256) void k_fused_i(
    const float* __restrict__ q, const f16* __restrict__ W1, const float* __restrict__ b1,
    const f16* __restrict__ W2, const float* __restrict__ b2,
    f16* __restrict__ xout, int M) {
  __shared__ f16 As[64 * 32];
  __shared__ f16 Hs[64 * 132];
  const int tid = threadIdx.x;
  const int wave = tid >> 6, lane = tid & 63;
  const int wm = (wave & 1) * 32, wn = (wave >> 1) * 64;
  const int lr = lane & 15, lk = lane >> 4;
  const int srow = tid >> 2, c8 = tid & 3;
  const int sw = (srow >> 1) & 3;
  const int bm = blockIdx.x * 64;
  f32x4 acc[2][4] = {};
  for (int k0 = 0; k0 < 128; k0 += 32) {
    {
      int gm = bm + srow;
      f16x8 c0;
      if (gm < M) {
        const float* ap = q + (size_t)gm * 128 + k0 + c8 * 8;
        float4 v0 = ((const float4*)ap)[0];
        float4 v1 = ((const float4*)ap)[1];
        c0[0]=(f16)v0.x; c0[1]=(f16)v0.y; c0[2]=(f16)v0.z; c0[3]=(f16)v0.w;
        c0[4]=(f16)v1.x; c0[5]=(f16)v1.y; c0[6]=(f16)v1.z; c0[7]=(f16)v1.w;
      } else {
        #pragma unroll
        for (int u = 0; u < 8; ++u) c0[u] = (f16)0.f;
      }
      *(f16x8*)&As[srow * 32 + ((c8 ^ sw) << 3)] = c0;
    }
    __syncthreads();
    f16x8 af[2], bf[4];
    #pragma unroll
    for (int mt = 0; mt < 2; ++mt) {
      int r = wm + mt * 16 + lr;
      af[mt] = *(const f16x8*)&As[r * 32 + ((lk ^ ((r >> 1) & 3)) << 3)];
    }
    #pragma unroll
    for (int nt = 0; nt < 4; ++nt)
      bf[nt] = *(const f16x8*)&W1[(size_t)(wn + nt * 16 + lr) * 128 + k0 + lk * 8];
    #pragma unroll
    for (int mt = 0; mt < 2; ++mt)
      #pragma unroll
      for (int nt = 0; nt < 4; ++nt)
        acc[mt][nt] = __builtin_amdgcn_mfma_f32_16x16x32_f16(af[mt], bf[nt], acc[mt][nt], 0, 0, 0);
    __syncthreads();
  }
  #pragma unroll
  for (int mt = 0; mt < 2; ++mt)
    #pragma unroll
    for (int nt = 0; nt < 4; ++nt) {
      int col = wn + nt * 16 + lr;
      float bv = b1[col];
      #pragma unroll
      for (int rr = 0; rr < 4; ++rr) {
        int row = wm + mt * 16 + lk * 4 + rr;
        float v = acc[mt][nt][rr] + bv;
        v = v / (1.0f + expf(-v));
        Hs[row * 132 + col] = (f16)v;
      }
    }
  __syncthreads();
  #pragma unroll
  for (int cc = 0; cc < 3; ++cc) {
    f32x4 a2[2][4] = {};
    for (int k0 = 0; k0 < 128; k0 += 32) {
      f16x8 af2[2], bf2[4];
      #pragma unroll
      for (int mt = 0; mt < 2; ++mt)
        af2[mt] = *(const f16x8*)&Hs[(wm + mt * 16 + lr) * 132 + k0 + lk * 8];
      #pragma unroll
      for (int nt = 0; nt < 4; ++nt)
        bf2[nt] = *(const f16x8*)&W2[(size_t)(cc * 128 + wn + nt * 16 + lr) * 128 + k0 + lk * 8];
      #pragma unroll
      for (int mt = 0; mt < 2; ++mt)
        #pragma unroll
        for (int nt = 0; nt < 4; ++nt)
          a2[mt][nt] = __builtin_amdgcn_mfma_f32_16x16x32_f16(af2[mt], bf2[nt], a2[mt][nt], 0, 0, 0);
    }
    #pragma unroll
    for (int mt = 0; mt < 2; ++mt)
      #pragma unroll
      for (int nt = 0; nt < 4; ++nt) {
        int gn = cc * 128 + wn + nt * 16 + lr;
        float bv = b2[gn];
        #pragma unroll
        for (int rr = 0; rr < 4; ++rr) {
          int gm = bm + wm + mt * 16 + lk * 4 + rr;
          if (gm >= M) continue;
          xout[(size_t)gm * 384 + gn] = (f16)(a2[mt][nt][rr] + bv);
        }
      }
  }
}

// ======== fully fused mix phase: mumix GEMM + vn + MLP + q/mu update ========
// 32 nodes/block (96 mu rows). mu f16 [N][3][128] RMW; q fp32 [N][128] RMW.
// Wmu [256][128]; W1 [128][256]; W2 [384][128].
__global__ __launch_bounds__(256) void k_fused_mx(
    float* __restrict__ q, f16* __restrict__ mu,
    const f16* __restrict__ Wmu,
    const f16* __restrict__ W1, const float* __restrict__ b1,
    const f16* __restrict__ W2, const float* __restrict__ b2) {
  // LDS pool: MM[96][264] f16 (50688 B) + scratch 24576 B (As4 then VN/HS)
  __shared__ __align__(16) char pool[50688 + 24576];
  f16* MM  = (f16*)pool;                       // mumix tile, rows = nn*3+dir
  f16* As4 = (f16*)(pool + 50688);             // phase A staging [4][96][32]
  f16* VN  = (f16*)(pool + 50688);             // reused: vn [4][32][32]
  f16* HS  = (f16*)(pool + 50688 + 8192);      // h tile [32][132]

  const int tid = threadIdx.x;
  const int wave = tid >> 6, lane = tid & 63;
  const int lr = lane & 15, lk = lane >> 4;
  const int n0 = blockIdx.x * 32;
  const int r0 = n0 * 3;

  // ---- stage mu rows [r0, r0+96) into As4 (k-block-major, XOR swizzle) ----
  #pragma unroll
  for (int rep = 0; rep < 6; ++rep) {
    int idx = rep * 256 + tid;          // 0..1535
    int row = idx >> 4;                 // 0..95
    int g   = idx & 15;                 // granule of 8 f16 within 128 cols
    int kb = g >> 2, c8 = g & 3;
    f16x8 v = *(const f16x8*)(mu + (size_t)(r0 + row) * 128 + g * 8);
    *(f16x8*)&As4[((kb * 96 + row) << 5) + (((c8 ^ ((row >> 1) & 3))) << 3)] = v;
  }
  __syncthreads();

  // ---- phase A: MM = mu @ Wmu^T  (96 x 256, two 128-col halves) ----
  const int wmA = (wave & 1) * 48;
  const int wnA0 = (wave >> 1) * 64;    // within half: 2 col-waves x 64
  #pragma unroll
  for (int half = 0; half < 2; ++half) {
    f32x4 accA[3][4] = {};
    #pragma unroll
    for (int kk = 0; kk < 4; ++kk) {
      f16x8 af[3], bf[4];
      #pragma unroll
      for (int mt = 0; mt < 3; ++mt) {
        int r = wmA + mt * 16 + lr;
        af[mt] = *(const f16x8*)&As4[((kk * 96 + r) << 5) + ((lk ^ ((r >> 1) & 3)) << 3)];
      }
      #pragma unroll
      for (int nt = 0; nt < 4; ++nt)
        bf[nt] = *(const f16x8*)&Wmu[(size_t)(half * 128 + wnA0 + nt * 16 + lr) * 128 + kk * 32 + lk * 8];
      #pragma unroll
      for (int mt = 0; mt < 3; ++mt)
        #pragma unroll
        for (int nt = 0; nt < 4; ++nt)
          accA[mt][nt] = __builtin_amdgcn_mfma_f32_16x16x32_f16(af[mt], bf[nt], accA[mt][nt], 0, 0, 0);
    }
    #pragma unroll
    for (int mt = 0; mt < 3; ++mt)
      #pragma unroll
      for (int nt = 0; nt < 4; ++nt) {
        int col = half * 128 + wnA0 + nt * 16 + lr;
        #pragma unroll
        for (int rr = 0; rr < 4; ++rr) {
          int row = wmA + mt * 16 + lk * 4 + rr;
          MM[row * 264 + col] = (f16)accA[mt][nt][rr];
        }
      }
  }
  __syncthreads();   // MM complete; As4 reads done -> VN region reusable

  // ---- vn pass: VN[n][c] = sqrt(sum_d V_d^2 + 1e-8), XOR-swizzled layout ----
  #pragma unroll
  for (int rep = 0; rep < 16; ++rep) {
    int idx = rep * 256 + tid;          // 0..4095
    int nn = idx >> 7, c = idx & 127;
    float V0 = (float)MM[(nn * 3 + 0) * 264 + c];
    float V1 = (float)MM[(nn * 3 + 1) * 264 + c];
    float V2 = (float)MM[(nn * 3 + 2) * 264 + c];
    float vnv = sqrtf(V0 * V0 + V1 * V1 + V2 * V2 + 1e-8f);
    int kb = c >> 5, c8 = (c >> 3) & 3, ce = c & 7;
    VN[((kb * 32 + nn) << 5) + ((c8 ^ ((nn >> 1) & 3)) << 3) + ce] = (f16)vnv;
  }
  __syncthreads();

  // ---- phase B: h = silu([q|vn] @ W1^T + b1), 32 x 128, K=256 ----
  const int wmB = (wave & 1) * 16, wnB = (wave >> 1) * 64;
  f32x4 accB[4] = {};
  #pragma unroll
  for (int kk = 0; kk < 8; ++kk) {
    f16x8 af;
    int row = wmB + lr;
    if (kk < 4) {
      const float* qp_ = q + (size_t)(n0 + row) * 128 + kk * 32 + lk * 8;
      float4 v0 = ((const float4*)qp_)[0];
      float4 v1 = ((const float4*)qp_)[1];
      af[0]=(f16)v0.x; af[1]=(f16)v0.y; af[2]=(f16)v0.z; af[3]=(f16)v0.w;
      af[4]=(f16)v1.x; af[5]=(f16)v1.y; af[6]=(f16)v1.z; af[7]=(f16)v1.w;
    } else {
      af = *(const f16x8*)&VN[(((kk - 4) * 32 + row) << 5) + ((lk ^ ((row >> 1) & 3)) << 3)];
    }
    f16x8 bf[4];
    #pragma unroll
    for (int nt = 0; nt < 4; ++nt)
      bf[nt] = *(const f16x8*)&W1[(size_t)(wnB + nt * 16 + lr) * 256 + kk * 32 + lk * 8];
    #pragma unroll
    for (int nt = 0; nt < 4; ++nt)
      accB[nt] = __builtin_amdgcn_mfma_f32_16x16x32_f16(af, bf[nt], accB[nt], 0, 0, 0);
  }
  #pragma unroll
  for (int nt = 0; nt < 4; ++nt) {
    int col = wnB + nt * 16 + lr;
    float bv = b1[col];
    #pragma unroll
    for (int rr = 0; rr < 4; ++rr) {
      int row = wmB + lk * 4 + rr;
      float v = accB[nt][rr] + bv;
      v = v / (1.0f + expf(-v));
      HS[row * 132 + col] = (f16)v;
    }
  }
  __syncthreads();

  // ---- phase C: xm = h @ W2^T + b2 (3 chunks), epilogue updates q & mu ----
  f32x4 accC[3][4] = {};
  #pragma unroll
  for (int cc = 0; cc < 3; ++cc)
    #pragma unroll
    for (int kk = 0; kk < 4; ++kk) {
      f16x8 af = *(const f16x8*)&HS[(wmB + lr) * 132 + kk * 32 + lk * 8];
      f16x8 bf[4];
      #pragma unroll
      for (int nt = 0; nt < 4; ++nt)
        bf[nt] = *(const f16x8*)&W2[(size_t)(cc * 128 + wnB + nt * 16 + lr) * 128 + kk * 32 + lk * 8];
      #pragma unroll
      for (int nt = 0; nt < 4; ++nt)
        accC[cc][nt] = __builtin_amdgcn_mfma_f32_16x16x32_f16(af, bf[nt], accC[cc][nt], 0, 0, 0);
    }
  #pragma unroll
  for (int nt = 0; nt < 4; ++nt) {
    int col = wnB + nt * 16 + lr;
    float b_dq = b2[col], b_dmu = b2[128 + col], b_dqmu = b2[256 + col];
    #pragma unroll
    for (int rr = 0; rr < 4; ++rr) {
      int nn = wmB + lk * 4 + rr;
      int gm = n0 + nn;
      float dq   = accC[0][nt][rr] + b_dq;
      float dmu  = accC[1][nt][rr] + b_dmu;
      float dqmu = accC[2][nt][rr] + b_dqmu;
      float V0 = (float)MM[(nn * 3 + 0) * 264 + col], W0 = (float)MM[(nn * 3 + 0) * 264 + 128 + col];
      float V1 = (float)MM[(nn * 3 + 1) * 264 + col], W1v = (float)MM[(nn * 3 + 1) * 264 + 128 + col];
      float V2 = (float)MM[(nn * 3 + 2) * 264 + col], W2v = (float)MM[(nn * 3 + 2) * 264 + 128 + col];
      float svw = V0 * W0 + V1 * W1v + V2 * W2v;
      size_t qi = (size_t)gm * 128 + col;
      q[qi] += dq + dqmu * svw;
      f16* mr = mu + (size_t)gm * 384;
      mr[col]       = (f16)((float)mr[col]       + dmu * W0);
      mr[128 + col] = (f16)((float)mr[128 + col] + dmu * W1v);
      mr[256 + col] = (f16)((float)mr[256 + col] + dmu * W2v);
    }
  }
}

// ---------------- per-node edge reduction: wave per node, f16x2, 2x unroll ----------------
__global__ __launch_bounds__(256) void k_edge_msg(
    const int* __restrict__ rs, const int* __restrict__ jperm,
    const f16* __restrict__ x, const f16* __restrict__ tab,
    const float4* __restrict__ geo, const f16* __restrict__ mu_in,
    float* __restrict__ q, f16* __restrict__ mu_out) {
  const int wid  = threadIdx.x >> 6;
  const int lane = threadIdx.x & 63;
  const int i = blockIdx.x * 4 + wid;
  if (i >= N_NODES) return;
  const int d0 = lane * 2;
  const float scale = (float)(TAB_T - 1) / 5.0f;
  float aqx = 0.f, aqy = 0.f;
  float a0x = 0.f, a0y = 0.f, a1x = 0.f, a1y = 0.f, a2x = 0.f, a2y = 0.f;
  const int s = rs[i], e = rs[i + 1];

  auto body = [&](float dx, float dy, float dz,
                  f16x2 ta0, f16x2 ta1, f16x2 ta2, f16x2 tb0, f16x2 tb1, f16x2 tb2,
                  f16x2 xv0, f16x2 xv1, f16x2 xv2, f16x2 mv0, f16x2 mv1, f16x2 mv2,
                  float fr) {
    float fo = 1.0f - fr;
    float W0x = fo * (float)ta0[0] + fr * (float)tb0[0];
    float W0y = fo * (float)ta0[1] + fr * (float)tb0[1];
    float W1x = fo * (float)ta1[0] + fr * (float)tb1[0];
    float W1y = fo * (float)ta1[1] + fr * (float)tb1[1];
    float W2x = fo * (float)ta2[0] + fr * (float)tb2[0];
    float W2y = fo * (float)ta2[1] + fr * (float)tb2[1];
    float m1x = (float)xv1[0] * W1x, m1y = (float)xv1[1] * W1y;
    float m2x = (float)xv2[0] * W2x, m2y = (float)xv2[1] * W2y;
    aqx = fmaf((float)xv0[0], W0x, aqx);
    aqy = fmaf((float)xv0[1], W0y, aqy);
    a0x += m1x * dx + m2x * (float)mv0[0];
    a0y += m1y * dx + m2y * (float)mv0[1];
    a1x += m1x * dy + m2x * (float)mv1[0];
    a1y += m1y * dy + m2y * (float)mv1[1];
    a2x += m1x * dz + m2x * (float)mv2[0];
    a2y += m1y * dz + m2y * (float)mv2[1];
  };

  int p = s;
  for (; p + 2 <= e; p += 2) {
    int jA = jperm[p], jB = jperm[p + 1];
    float4 gA = geo[p], gB = geo[p + 1];
    float uA = fminf(gA.x, 5.0f) * scale;
    float uB = fminf(gB.x, 5.0f) * scale;
    int tA = min((int)uA, TAB_T - 2);
    int tB = min((int)uB, TAB_T - 2);
    float frA = uA - (float)tA, frB = uB - (float)tB;
    const f16* taA = tab + (size_t)tA * 384;
    const f16* taB = tab + (size_t)tB * 384;
    const f16* xjA = x + (size_t)jA * 384;
    const f16* xjB = x + (size_t)jB * 384;
    const f16* mjA = mu_in + (size_t)jA * 384;
    const f16* mjB = mu_in + (size_t)jB * 384;
    f16x2 tA0 = *(const f16x2*)(taA + d0);
    f16x2 tA1 = *(const f16x2*)(taA + 128 + d0);
    f16x2 tA2 = *(const f16x2*)(taA + 256 + d0);
    f16x2 tA3 = *(const f16x2*)(taA + 384 + d0);
    f16x2 tA4 = *(const f16x2*)(taA + 512 + d0);
    f16x2 tA5 = *(const f16x2*)(taA + 640 + d0);
    f16x2 xA0 = *(const f16x2*)(xjA + d0);
    f16x2 xA1 = *(const f16x2*)(xjA + 128 + d0);
    f16x2 xA2 = *(const f16x2*)(xjA + 256 + d0);
    f16x2 mA0 = *(const f16x2*)(mjA + d0);
    f16x2 mA1 = *(const f16x2*)(mjA + 128 + d0);
    f16x2 mA2 = *(const f16x2*)(mjA + 256 + d0);
    f16x2 tB0 = *(const f16x2*)(taB + d0);
    f16x2 tB1 = *(const f16x2*)(taB + 128 + d0);
    f16x2 tB2 = *(const f16x2*)(taB + 256 + d0);
    f16x2 tB3 = *(const f16x2*)(taB + 384 + d0);
    f16x2 tB4 = *(const f16x2*)(taB + 512 + d0);
    f16x2 tB5 = *(const f16x2*)(taB + 640 + d0);
    f16x2 xB0 = *(const f16x2*)(xjB + d0);
    f16x2 xB1 = *(const f16x2*)(xjB + 128 + d0);
    f16x2 xB2 = *(const f16x2*)(xjB + 256 + d0);
    f16x2 mB0 = *(const f16x2*)(mjB + d0);
    f16x2 mB1 = *(const f16x2*)(mjB + 128 + d0);
    f16x2 mB2 = *(const f16x2*)(mjB + 256 + d0);
    body(gA.y, gA.z, gA.w, tA0, tA1, tA2, tA3, tA4, tA5,
         xA0, xA1, xA2, mA0, mA1, mA2, frA);
    body(gB.y, gB.z, gB.w, tB0, tB1, tB2, tB3, tB4, tB5,
         xB0, xB1, xB2, mB0, mB1, mB2, frB);
  }
  for (; p < e; ++p) {
    int j = jperm[p];
    float4 g = geo[p];
    float u = fminf(g.x, 5.0f) * scale;
    int t0 = min((int)u, TAB_T - 2);
    float fr = u - (float)t0;
    const f16* ta = tab + (size_t)t0 * 384;
    const f16* xj = x + (size_t)j * 384;
    const f16* mj = mu_in + (size_t)j * 384;
    body(g.y, g.z, g.w,
         *(const f16x2*)(ta + d0), *(const f16x2*)(ta + 128 + d0), *(const f16x2*)(ta + 256 + d0),
         *(const f16x2*)(ta + 384 + d0), *(const f16x2*)(ta + 512 + d0), *(const f16x2*)(ta + 640 + d0),
         *(const f16x2*)(xj + d0), *(const f16x2*)(xj + 128 + d0), *(const f16x2*)(xj + 256 + d0),
         *(const f16x2*)(mj + d0), *(const f16x2*)(mj + 128 + d0), *(const f16x2*)(mj + 256 + d0),
         fr);
  }

  float* qp = q + (size_t)i * 128 + d0;
  float2 qv = *(float2*)qp;
  qv.x += aqx; qv.y += aqy;
  *(float2*)qp = qv;
  const f16* min_ = mu_in + (size_t)i * 384;
  f16* mout = mu_out + (size_t)i * 384;
  f16x2 o0, o1, o2;
  f16x2 i0 = *(const f16x2*)(min_ + d0);
  f16x2 i1 = *(const f16x2*)(min_ + 128 + d0);
  f16x2 i2 = *(const f16x2*)(min_ + 256 + d0);
  o0[0] = (f16)((float)i0[0] + a0x); o0[1] = (f16)((float)i0[1] + a0y);
  o1[0] = (f16)((float)i1[0] + a1x); o1[1] = (f16)((float)i1[1] + a1y);
  o2[0] = (f16)((float)i2[0] + a2x); o2[1] = (f16)((float)i2[1] + a2y);
  *(f16x2*)(mout + d0)       = o0;
  *(f16x2*)(mout + 128 + d0) = o1;
  *(f16x2*)(mout + 256 + d0) = o2;
}

// ---------------- final outputs ----------------
__global__ __launch_bounds__(256) void k_posattr(
    const int* __restrict__ rs, const int* __restrict__ jperm,
    const f16* __restrict__ mu, const float* __restrict__ w, float* __restrict__ pos_out) {
  const int wid  = threadIdx.x >> 6;
  const int lane = threadIdx.x & 63;
  const int i = blockIdx.x * 4 + wid;
  if (i >= N_NODES) return;
  const int d0 = lane * 2;
  float a0x = 0.f, a0y = 0.f, a1x = 0.f, a1y = 0.f, a2x = 0.f, a2y = 0.f;
  const int s = rs[i], e = rs[i + 1];
  int p = s;
  for (; p + 2 <= e; p += 2) {
    int jA = jperm[p], jB = jperm[p + 1];
    const f16* mA = mu + (size_t)jA * 384;
    const f16* mB = mu + (size_t)jB * 384;
    f16x2 A0 = *(const f16x2*)(mA + d0);
    f16x2 A1 = *(const f16x2*)(mA + 128 + d0);
    f16x2 A2 = *(const f16x2*)(mA + 256 + d0);
    f16x2 B0 = *(const f16x2*)(mB + d0);
    f16x2 B1 = *(const f16x2*)(mB + 128 + d0);
    f16x2 B2 = *(const f16x2*)(mB + 256 + d0);
    a0x += (float)A0[0] + (float)B0[0]; a0y += (float)A0[1] + (float)B0[1];
    a1x += (float)A1[0] + (float)B1[0]; a1y += (float)A1[1] + (float)B1[1];
    a2x += (float)A2[0] + (float)B2[0]; a2y += (float)A2[1] + (float)B2[1];
  }
  for (; p < e; ++p) {
    int j = jperm[p];
    const f16* mj = mu + (size_t)j * 384;
    f16x2 A0 = *(const f16x2*)(mj + d0);
    f16x2 A1 = *(const f16x2*)(mj + 128 + d0);
    f16x2 A2 = *(const f16x2*)(mj + 256 + d0);
    a0x += (float)A0[0]; a0y += (float)A0[1];
    a1x += (float)A1[0]; a1y += (float)A1[1];
    a2x += (float)A2[0]; a2y += (float)A2[1];
  }
  float wx = w[d0], wy = w[d0 + 1];
  float s0 = fminf(fmaxf(a0x, -5.f), 5.f) * wx + fminf(fmaxf(a0y, -5.f), 5.f) * wy;
  float s1 = fminf(fmaxf(a1x, -5.f), 5.f) * wx + fminf(fmaxf(a1y, -5.f), 5.f) * wy;
  float s2 = fminf(fmaxf(a2x, -5.f), 5.f) * wx + fminf(fmaxf(a2y, -5.f), 5.f) * wy;
  #pragma unroll
  for (int off = 32; off > 0; off >>= 1) {
    s0 += __shfl_down(s0, off, 64);
    s1 += __shfl_down(s1, off, 64);
    s2 += __shfl_down(s2, off, 64);
  }
  if (lane == 0) {
    pos_out[(size_t)i * 3 + 0] = fminf(fmaxf(s0, -5.f), 5.f);
    pos_out[(size_t)i * 3 + 1] = fminf(fmaxf(s1, -5.f), 5.f);
    pos_out[(size_t)i * 3 + 2] = fminf(fmaxf(s2, -5.f), 5.f);
  }
}

// ---------------- LayerNorm+tanh: wave per node ----------------
__global__ __launch_bounds__(256) void k_ln(const float* __restrict__ q, const float* __restrict__ g,
                                            const float* __restrict__ b, float* __restrict__ out) {
  const int wid = threadIdx.x >> 6, lane = threadIdx.x & 63;
  const int n = blockIdx.x * 4 + wid;
  if (n >= N_NODES) return;
  const int d0 = lane * 2;
  float2 v = *(const float2*)(q + (size_t)n * 128 + d0);
  float v0 = fminf(fmaxf(v.x, -5.f), 5.f);
  float v1 = fminf(fmaxf(v.y, -5.f), 5.f);
  float s = v0 + v1, s2 = v0 * v0 + v1 * v1;
  #pragma unroll
  for (int off = 32; off > 0; off >>= 1) {
    s  += __shfl_down(s,  off, 64);
    s2 += __shfl_down(s2, off, 64);
  }
  s  = __shfl(s,  0, 64);
  s2 = __shfl(s2, 0, 64);
  float mean = s * (1.0f / 128.0f);
  float var  = s2 * (1.0f / 128.0f) - mean * mean;
  float r = rsqrtf(var + 1e-5f);
  out[(size_t)n * 128 + d0]     = tanhf((v0 - mean) * r * g[d0]     + b[d0]);
  out[(size_t)n * 128 + d0 + 1] = tanhf((v1 - mean) * r * g[d0 + 1] + b[d0 + 1]);
}

extern "C" void kernel_launch(void* const* d_in, const int* in_sizes, int n_in,
                              void* d_out, int out_size, void* d_ws, size_t ws_size,
                              hipStream_t stream) {
  const float* z         = (const float*)d_in[0];
  const float* pos       = (const float*)d_in[1];
  const int*   edge_idx  = (const int*)d_in[2];
  const float* in_w      = (const float*)d_in[3];
  const float* in_b      = (const float*)d_in[4];
  const float* filt_w    = (const float*)d_in[5];
  const float* filt_b    = (const float*)d_in[6];
  const float* inter_w1  = (const float*)d_in[7];
  const float* inter_b1  = (const float*)d_in[8];
  const float* inter_w2  = (const float*)d_in[9];
  const float* inter_b2  = (const float*)d_in[10];
  const float* mix_mu_w  = (const float*)d_in[11];
  const float* mix_w1    = (const float*)d_in[12];
  const float* mix_b1    = (const float*)d_in[13];
  const float* mix_w2    = (const float*)d_in[14];
  const float* mix_b2    = (const float*)d_in[15];
  const float* mu_proj_w = (const float*)d_in[16];
  const float* ln_g      = (const float*)d_in[17];
  const float* ln_b      = (const float*)d_in[18];

  char* base = (char*)d_ws;
  size_t off = 0;
  auto alloc = [&](size_t bytes) -> char* {
    char* p = base + off;
    off += (bytes + 255) & ~(size_t)255;
    return p;
  };
  float*  q     = (float*)alloc((size_t)N_NODES * 128 * 4);
  f16*    x16   = (f16*)alloc((size_t)N_NODES * 384 * 2);
  f16*    mu_a  = (f16*)alloc((size_t)N_NODES * 384 * 2);
  f16*    mu_b  = (f16*)alloc((size_t)N_NODES * 384 * 2);
  float4* geo   = (float4*)alloc((size_t)N_EDGES * 16);
  int*    cnt   = (int*)alloc((size_t)N_NODES * 4);
  int*    incl  = (int*)alloc((size_t)N_NODES * 4);
  int*    bsum  = (int*)alloc(128 * 4);
  int*    rs    = (int*)alloc((size_t)(N_NODES + 1) * 4);
  int*    cur   = (int*)alloc((size_t)N_NODES * 4);
  int*    eidx  = (int*)alloc((size_t)N_EDGES * 4);
  int*    jperm = (int*)alloc((size_t)N_EDGES * 4);
  f16*    tab   = (f16*)alloc((size_t)TAB_T * 384 * 2);
  // f16 transposed weights
  f16* wt_in = (f16*)alloc((size_t)128 * 64 * 2);
  f16* wt_f  = (f16*)alloc((size_t)384 * 64 * 2);
  f16* wt_i1 = (f16*)alloc((size_t)3 * 128 * 128 * 2);
  f16* wt_i2 = (f16*)alloc((size_t)3 * 384 * 128 * 2);
  f16* wt_mu = (f16*)alloc((size_t)3 * 256 * 128 * 2);
  f16* wt_x1 = (f16*)alloc((size_t)3 * 128 * 256 * 2);
  f16* wt_x2 = (f16*)alloc((size_t)3 * 384 * 128 * 2);
  if (off > ws_size) return;

  float* out_node = (float*)d_out;
  float* out_pos  = (float*)d_out + (size_t)N_NODES * 128;

  // ---- weight prep (f16, [N][K]) ----
  {
    WJobs jb;
    int ji = 0;
    jb.j[ji++] = {in_w,   wt_in, 6, 128, 0, 128 * 64};
    jb.j[ji++] = {filt_w, wt_f,  6, 384, 0, 384 * 64};
    for (int l = 0; l < 3; ++l)
      jb.j[ji++] = {inter_w1 + (size_t)l*128*128, wt_i1 + (size_t)l*128*128, 7, 128, 0, 128*128};
    for (int l = 0; l < 3; ++l)
      jb.j[ji++] = {inter_w2 + (size_t)l*128*384, wt_i2 + (size_t)l*384*128, 7, 384, 0, 384*128};
    for (int l = 0; l < 3; ++l)
      jb.j[ji++] = {mix_mu_w + (size_t)l*128*256, wt_mu + (size_t)l*256*128, 7, 256, 0, 256*128};
    for (int l = 0; l < 3; ++l)
      jb.j[ji++] = {mix_w1 + (size_t)l*256*128, wt_x1 + (size_t)l*128*256, 8, 128, 0, 128*256};
    for (int l = 0; l < 3; ++l)
      jb.j[ji++] = {mix_w2 + (size_t)l*128*384, wt_x2 + (size_t)l*384*128, 7, 384, 0, 384*128};
    dim3 g(192, 17);
    k_wt_all<<<g, 256, 0, stream>>>(jb);
  }

  // ---- filter lookup table ----
  k_tab<<<TAB_T, 128, 0, stream>>>(wt_f, filt_b, tab);

  // ---- CSR build ----
  hipMemsetAsync(cnt, 0, (size_t)N_NODES * 4, stream);
  k_hist<<<N_EDGES / 256, 256, 0, stream>>>(edge_idx, cnt);
  k_scan_blk<<<NB_SCAN, 256, 0, stream>>>(cnt, incl, bsum);
  k_scan_top<<<1, 128, 0, stream>>>(bsum);
  k_scan_add<<<NB_SCAN, 256, 0, stream>>>(cnt, incl, bsum, rs, cur);
  k_fill<<<N_EDGES / 256, 256, 0, stream>>>(edge_idx, cur, eidx);

  // ---- edge geometry (CSR-permuted) ----
  k_edge_geom<<<N_EDGES / 256, 256, 0, stream>>>(pos, edge_idx, eidx, geo, jperm);

  // ---- input embedding ----
  dim3 ge((N_NODES + 127) / 128, 1);
  k_mgemm<1, float, float><<<ge, 256, 0, stream>>>(z, wt_in, in_b, q, N_NODES, 64, 128);
  hipMemsetAsync(mu_a, 0, (size_t)N_NODES * 384 * 2, stream);

  f16* mu_cur = mu_a;
  f16* mu_nxt = mu_b;
  const int gn4 = (N_NODES + 3) / 4;
  const int gf  = (N_NODES + 63) / 64;   // 313
  const int gmx = N_NODES / 32;          // 625
  for (int l = 0; l < NLAYER; ++l) {
    k_fused_i<<<gf, 256, 0, stream>>>(q, wt_i1 + (size_t)l*128*128, inter_b1 + (size_t)l*128,
                                      wt_i2 + (size_t)l*384*128, inter_b2 + (size_t)l*384,
                                      x16, N_NODES);
    k_edge_msg<<<gn4, 256, 0, stream>>>(rs, jperm, x16, tab, geo, mu_cur, q, mu_nxt);
    { f16* t = mu_cur; mu_cur = mu_nxt; mu_nxt = t; }
    k_fused_mx<<<gmx, 256, 0, stream>>>(q, mu_cur, wt_mu + (size_t)l*256*128,
                                        wt_x1 + (size_t)l*128*256, mix_b1 + (size_t)l*128,
                                        wt_x2 + (size_t)l*384*128, mix_b2 + (size_t)l*384);
  }

  // ---- outputs ----
  k_posattr<<<gn4, 256, 0, stream>>>(rs, jperm, mu_cur, mu_proj_w, out_pos);
  k_ln<<<gn4, 256, 0, stream>>>(q, ln_g, ln_b, out_node);
}

// Round 10
// 587.261 us; speedup vs baseline: 4.2369x; 1.0447x over previous
//
#include <hip/hip_runtime.h>
#include <math.h>

#ifndef M_PI
#define M_PI 3.14159265358979323846
#endif

static constexpr int N_NODES = 20000;
static constexpr int N_EDGES = 320000;
static constexpr int NLAYER  = 3;
static constexpr int NB_SCAN = (N_NODES + 255) / 256;  // 79
static constexpr int TAB_T   = 1024;                   // filter lookup rows (L2-resident)

typedef _Float16 f16;
typedef __attribute__((ext_vector_type(2))) _Float16 f16x2;
typedef __attribute__((ext_vector_type(8))) _Float16 f16x8;
typedef __attribute__((ext_vector_type(4))) float f32x4;

__device__ __forceinline__ void storev(float* p, float v) { *p = v; }
__device__ __forceinline__ void storev(f16* p, float v)   { *p = (f16)v; }

// ---------------- CSR build ----------------
__global__ void k_hist(const int* __restrict__ idx_i, int* __restrict__ cnt) {
  int e = blockIdx.x * 256 + threadIdx.x;
  if (e < N_EDGES) atomicAdd(&cnt[idx_i[e]], 1);
}

__global__ void k_scan_blk(const int* __restrict__ cnt, int* __restrict__ incl,
                           int* __restrict__ bsum) {
  __shared__ int buf[256];
  int t = threadIdx.x;
  int i = blockIdx.x * 256 + t;
  int v = (i < N_NODES) ? cnt[i] : 0;
  buf[t] = v;
  __syncthreads();
  #pragma unroll
  for (int off = 1; off < 256; off <<= 1) {
    int x = (t >= off) ? buf[t - off] : 0;
    __syncthreads();
    buf[t] += x;
    __syncthreads();
  }
  if (i < N_NODES) incl[i] = buf[t];
  if (t == 255) bsum[blockIdx.x] = buf[255];
}

__global__ void k_scan_top(int* __restrict__ bsum) {
  __shared__ int buf[128];
  int t = threadIdx.x;
  int v = (t < NB_SCAN) ? bsum[t] : 0;
  buf[t] = v;
  __syncthreads();
  #pragma unroll
  for (int off = 1; off < 128; off <<= 1) {
    int x = (t >= off) ? buf[t - off] : 0;
    __syncthreads();
    buf[t] += x;
    __syncthreads();
  }
  if (t <= NB_SCAN) bsum[t] = buf[t] - v;  // exclusive; t==NB_SCAN -> total
}

__global__ void k_scan_add(const int* __restrict__ cnt, const int* __restrict__ incl,
                           const int* __restrict__ bsum, int* __restrict__ rs,
                           int* __restrict__ cur) {
  int i = blockIdx.x * 256 + threadIdx.x;
  if (i < N_NODES) {
    int v = bsum[blockIdx.x] + incl[i] - cnt[i];
    rs[i] = v;
    cur[i] = v;
  }
  if (i == 0) rs[N_NODES] = bsum[NB_SCAN];
}

// ---------------- fill + edge geometry (merged): geo = {d, dx, dy, dz} ----------------
__global__ void k_fill_geom(const int* __restrict__ idx_all, const float* __restrict__ pos,
                            int* __restrict__ cur, float4* __restrict__ geo,
                            int* __restrict__ jperm) {
  int e = blockIdx.x * 256 + threadIdx.x;
  if (e >= N_EDGES) return;
  int i = idx_all[e];
  int j = idx_all[N_EDGES + e];
  int p = atomicAdd(&cur[i], 1);
  float rx = pos[j*3+0] - pos[i*3+0];
  float ry = pos[j*3+1] - pos[i*3+1];
  float rz = pos[j*3+2] - pos[i*3+2];
  float d = sqrtf(rx*rx + ry*ry + rz*rz);
  d = fmaxf(d, 1e-8f);
  float inv = 1.0f / d;
  geo[p] = make_float4(d, rx*inv, ry*inv, rz*inv);
  jperm[p] = j;
}

// ---------------- weight transpose + filter table (merged prep) ----------------
struct WJob { const float* src; f16* dst; int kshift; int ld; int col0; int nk; };
struct WJobs { WJob j[16]; };

// grid (192, 24): y<16 -> wt job y; y>=16 -> tab rows (y-16)*128 + x (x<128)
__global__ __launch_bounds__(256) void k_prep(WJobs jb, const float* __restrict__ filt_w,
                                              const float* __restrict__ filt_b,
                                              f16* __restrict__ tab) {
  if (blockIdx.y < 16) {
    WJob w = jb.j[blockIdx.y];
    int t = blockIdx.x * 256 + threadIdx.x;
    if (t >= w.nk) return;
    int K = 1 << w.kshift;
    int n = t >> w.kshift;
    int k = t & (K - 1);
    w.dst[t] = (f16)w.src[(size_t)k * w.ld + w.col0 + n];
    return;
  }
  // ---- tab branch ----
  if (blockIdx.x >= 128) return;
  const int t = (blockIdx.y - 16) * 128 + blockIdx.x;
  __shared__ float ph[64];
  const int tid = threadIdx.x;
  const float dist = 5.0f * (float)t / (float)(TAB_T - 1);
  const float delta = 5.0f / 63.0f;
  const float coeff = -0.5f / (delta * delta);
  if (tid < 64) {
    float u = dist - delta * (float)tid;
    ph[tid] = expf(coeff * u * u);
  }
  __syncthreads();
  float xc = dist * 0.2f;
  float fc = (xc < 1.0f) ? 0.5f * (cosf((float)M_PI * xc) + 1.0f) : 0.0f;
  for (int n = tid; n < 384; n += 256) {
    float acc = 0.f;
    #pragma unroll
    for (int k = 0; k < 64; ++k) acc += ph[k] * filt_w[k * 384 + n];
    float v = (acc + filt_b[n]) * fc;
    v = fminf(fmaxf(v, -5.0f), 5.0f);
    tab[(size_t)t * 384 + n] = (f16)v;
  }
}

// ---------------- MFMA f16 GEMM (embed only) ----------------
template<int EPI, typename AT, typename CT>
__global__ __launch_bounds__(256) void k_mgemm(
    const AT* __restrict__ A, const f16* __restrict__ Wt,
    const float* __restrict__ bias, CT* __restrict__ C,
    int M, int K, int ldc) {
  __shared__ f16 As[128 * 32];
  __shared__ f16 Bs[128 * 32];
  const int bm = blockIdx.x * 128;
  const int bn = blockIdx.y * 128;
  const int tid = threadIdx.x;
  const int wave = tid >> 6, lane = tid & 63;
  const int wm = (wave & 1) * 64, wn = (wave >> 1) * 64;
  const int lr = lane & 15;
  const int lk = lane >> 4;
  const int srow = tid >> 1;
  const int sc0 = (tid & 1) * 2;
  const int sw = (srow >> 1) & 3;
  f32x4 acc[4][4] = {};
  for (int k0 = 0; k0 < K; k0 += 32) {
    {
      int gm = bm + srow;
      f16x8 c0, c1;
      if (gm < M) {
        if constexpr (sizeof(AT) == 2) {
          const f16* ap = (const f16*)A + (size_t)gm * K + k0 + sc0 * 8;
          c0 = *(const f16x8*)ap;
          c1 = *(const f16x8*)(ap + 8);
        } else {
          const float* ap = (const float*)A + (size_t)gm * K + k0 + sc0 * 8;
          float4 v0 = ((const float4*)ap)[0];
          float4 v1 = ((const float4*)ap)[1];
          float4 v2 = ((const float4*)ap)[2];
          float4 v3 = ((const float4*)ap)[3];
          c0[0]=(f16)v0.x; c0[1]=(f16)v0.y; c0[2]=(f16)v0.z; c0[3]=(f16)v0.w;
          c0[4]=(f16)v1.x; c0[5]=(f16)v1.y; c0[6]=(f16)v1.z; c0[7]=(f16)v1.w;
          c1[0]=(f16)v2.x; c1[1]=(f16)v2.y; c1[2]=(f16)v2.z; c1[3]=(f16)v2.w;
          c1[4]=(f16)v3.x; c1[5]=(f16)v3.y; c1[6]=(f16)v3.z; c1[7]=(f16)v3.w;
        }
      } else {
        #pragma unroll
        for (int u = 0; u < 8; ++u) { c0[u] = (f16)0.f; c1[u] = (f16)0.f; }
      }
      *(f16x8*)&As[srow * 32 + ((sc0 ^ sw) << 3)]       = c0;
      *(f16x8*)&As[srow * 32 + (((sc0 + 1) ^ sw) << 3)] = c1;
    }
    {
      const f16* bp = Wt + (size_t)(bn + srow) * K + k0 + sc0 * 8;
      f16x8 b0 = *(const f16x8*)bp;
      f16x8 b1 = *(const f16x8*)(bp + 8);
      *(f16x8*)&Bs[srow * 32 + ((sc0 ^ sw) << 3)]       = b0;
      *(f16x8*)&Bs[srow * 32 + (((sc0 + 1) ^ sw) << 3)] = b1;
    }
    __syncthreads();
    f16x8 af[4], bf[4];
    #pragma unroll
    for (int mt = 0; mt < 4; ++mt) {
      int r = wm + mt * 16 + lr;
      af[mt] = *(const f16x8*)&As[r * 32 + ((lk ^ ((r >> 1) & 3)) << 3)];
    }
    #pragma unroll
    for (int nt = 0; nt < 4; ++nt) {
      int r = wn + nt * 16 + lr;
      bf[nt] = *(const f16x8*)&Bs[r * 32 + ((lk ^ ((r >> 1) & 3)) << 3)];
    }
    #pragma unroll
    for (int mt = 0; mt < 4; ++mt)
      #pragma unroll
      for (int nt = 0; nt < 4; ++nt)
        acc[mt][nt] = __builtin_amdgcn_mfma_f32_16x16x32_f16(af[mt], bf[nt], acc[mt][nt], 0, 0, 0);
    __syncthreads();
  }
  #pragma unroll
  for (int mt = 0; mt < 4; ++mt) {
    int gm0 = bm + wm + mt * 16 + lk * 4;
    #pragma unroll
    for (int nt = 0; nt < 4; ++nt) {
      int gn = bn + wn + nt * 16 + lr;
      float bv = bias ? bias[gn] : 0.0f;
      #pragma unroll
      for (int rr = 0; rr < 4; ++rr) {
        int gm = gm0 + rr;
        if (gm >= M) continue;
        float v = acc[mt][nt][rr] + bv;
        if (EPI == 1) v = v / (1.0f + expf(-v));
        storev(&C[(size_t)gm * ldc + gn], v);
      }
    }
  }
}

// ======== fused inter MLP: x = silu(q@W1^T+b1)@W2^T+b2, 64-row tiles ========
__global__ __launch_bounds__(256) void k_fused_i(
    const float* __restrict__ q, const f16* __restrict__ W1, const float* __restrict__ b1,
    const f16* __restrict__ W2, const float* __restrict__ b2,
    f16* __restrict__ xout, int M) {
  __shared__ f16 As[64 * 32];
  __shared__ f16 Hs[64 * 132];
  const int tid = threadIdx.x;
  const int wave = tid >> 6, lane = tid & 63;
  const int wm = (wave & 1) * 32, wn = (wave >> 1) * 64;
  const int lr = lane & 15, lk = lane >> 4;
  const int srow = tid >> 2, c8 = tid & 3;
  const int sw = (srow >> 1) & 3;
  const int bm = blockIdx.x * 64;
  f32x4 acc[2][4] = {};
  for (int k0 = 0; k0 < 128; k0 += 32) {
    {
      int gm = bm + srow;
      f16x8 c0;
      if (gm < M) {
        const float* ap = q + (size_t)gm * 128 + k0 + c8 * 8;
        float4 v0 = ((const float4*)ap)[0];
        float4 v1 = ((const float4*)ap)[1];
        c0[0]=(f16)v0.x; c0[1]=(f16)v0.y; c0[2]=(f16)v0.z; c0[3]=(f16)v0.w;
        c0[4]=(f16)v1.x; c0[5]=(f16)v1.y; c0[6]=(f16)v1.z; c0[7]=(f16)v1.w;
      } else {
        #pragma unroll
        for (int u = 0; u < 8; ++u) c0[u] = (f16)0.f;
      }
      *(f16x8*)&As[srow * 32 + ((c8 ^ sw) << 3)] = c0;
    }
    __syncthreads();
    f16x8 af[2], bf[4];
    #pragma unroll
    for (int mt = 0; mt < 2; ++mt) {
      int r = wm + mt * 16 + lr;
      af[mt] = *(const f16x8*)&As[r * 32 + ((lk ^ ((r >> 1) & 3)) << 3)];
    }
    #pragma unroll
    for (int nt = 0; nt < 4; ++nt)
      bf[nt] = *(const f16x8*)&W1[(size_t)(wn + nt * 16 + lr) * 128 + k0 + lk * 8];
    #pragma unroll
    for (int mt = 0; mt < 2; ++mt)
      #pragma unroll
      for (int nt = 0; nt < 4; ++nt)
        acc[mt][nt] = __builtin_amdgcn_mfma_f32_16x16x32_f16(af[mt], bf[nt], acc[mt][nt], 0, 0, 0);
    __syncthreads();
  }
  #pragma unroll
  for (int mt = 0; mt < 2; ++mt)
    #pragma unroll
    for (int nt = 0; nt < 4; ++nt) {
      int col = wn + nt * 16 + lr;
      float bv = b1[col];
      #pragma unroll
      for (int rr = 0; rr < 4; ++rr) {
        int row = wm + mt * 16 + lk * 4 + rr;
        float v = acc[mt][nt][rr] + bv;
        v = v / (1.0f + expf(-v));
        Hs[row * 132 + col] = (f16)v;
      }
    }
  __syncthreads();
  #pragma unroll
  for (int cc = 0; cc < 3; ++cc) {
    f32x4 a2[2][4] = {};
    for (int k0 = 0; k0 < 128; k0 += 32) {
      f16x8 af2[2], bf2[4];
      #pragma unroll
      for (int mt = 0; mt < 2; ++mt)
        af2[mt] = *(const f16x8*)&Hs[(wm + mt * 16 + lr) * 132 + k0 + lk * 8];
      #pragma unroll
      for (int nt = 0; nt < 4; ++nt)
        bf2[nt] = *(const f16x8*)&W2[(size_t)(cc * 128 + wn + nt * 16 + lr) * 128 + k0 + lk * 8];
      #pragma unroll
      for (int mt = 0; mt < 2; ++mt)
        #pragma unroll
        for (int nt = 0; nt < 4; ++nt)
          a2[mt][nt] = __builtin_amdgcn_mfma_f32_16x16x32_f16(af2[mt], bf2[nt], a2[mt][nt], 0, 0, 0);
    }
    #pragma unroll
    for (int mt = 0; mt < 2; ++mt)
      #pragma unroll
      for (int nt = 0; nt < 4; ++nt) {
        int gn = cc * 128 + wn + nt * 16 + lr;
        float bv = b2[gn];
        #pragma unroll
        for (int rr = 0; rr < 4; ++rr) {
          int gm = bm + wm + mt * 16 + lk * 4 + rr;
          if (gm >= M) continue;
          xout[(size_t)gm * 384 + gn] = (f16)(a2[mt][nt][rr] + bv);
        }
      }
  }
}

// ======== fully fused mix phase: mumix GEMM + vn + MLP + q/mu update ========
__global__ __launch_bounds__(256) void k_fused_mx(
    float* __restrict__ q, f16* __restrict__ mu,
    const f16* __restrict__ Wmu,
    const f16* __restrict__ W1, const float* __restrict__ b1,
    const f16* __restrict__ W2, const float* __restrict__ b2) {
  __shared__ __align__(16) char pool[50688 + 24576];
  f16* MM  = (f16*)pool;
  f16* As4 = (f16*)(pool + 50688);
  f16* VN  = (f16*)(pool + 50688);
  f16* HS  = (f16*)(pool + 50688 + 8192);

  const int tid = threadIdx.x;
  const int wave = tid >> 6, lane = tid & 63;
  const int lr = lane & 15, lk = lane >> 4;
  const int n0 = blockIdx.x * 32;
  const int r0 = n0 * 3;

  #pragma unroll
  for (int rep = 0; rep < 6; ++rep) {
    int idx = rep * 256 + tid;
    int row = idx >> 4;
    int g   = idx & 15;
    int kb = g >> 2, c8 = g & 3;
    f16x8 v = *(const f16x8*)(mu + (size_t)(r0 + row) * 128 + g * 8);
    *(f16x8*)&As4[((kb * 96 + row) << 5) + (((c8 ^ ((row >> 1) & 3))) << 3)] = v;
  }
  __syncthreads();

  const int wmA = (wave & 1) * 48;
  const int wnA0 = (wave >> 1) * 64;
  #pragma unroll
  for (int half = 0; half < 2; ++half) {
    f32x4 accA[3][4] = {};
    #pragma unroll
    for (int kk = 0; kk < 4; ++kk) {
      f16x8 af[3], bf[4];
      #pragma unroll
      for (int mt = 0; mt < 3; ++mt) {
        int r = wmA + mt * 16 + lr;
        af[mt] = *(const f16x8*)&As4[((kk * 96 + r) << 5) + ((lk ^ ((r >> 1) & 3)) << 3)];
      }
      #pragma unroll
      for (int nt = 0; nt < 4; ++nt)
        bf[nt] = *(const f16x8*)&Wmu[(size_t)(half * 128 + wnA0 + nt * 16 + lr) * 128 + kk * 32 + lk * 8];
      #pragma unroll
      for (int mt = 0; mt < 3; ++mt)
        #pragma unroll
        for (int nt = 0; nt < 4; ++nt)
          accA[mt][nt] = __builtin_amdgcn_mfma_f32_16x16x32_f16(af[mt], bf[nt], accA[mt][nt], 0, 0, 0);
    }
    #pragma unroll
    for (int mt = 0; mt < 3; ++mt)
      #pragma unroll
      for (int nt = 0; nt < 4; ++nt) {
        int col = half * 128 + wnA0 + nt * 16 + lr;
        #pragma unroll
        for (int rr = 0; rr < 4; ++rr) {
          int row = wmA + mt * 16 + lk * 4 + rr;
          MM[row * 264 + col] = (f16)accA[mt][nt][rr];
        }
      }
  }
  __syncthreads();

  #pragma unroll
  for (int rep = 0; rep < 16; ++rep) {
    int idx = rep * 256 + tid;
    int nn = idx >> 7, c = idx & 127;
    float V0 = (float)MM[(nn * 3 + 0) * 264 + c];
    float V1 = (float)MM[(nn * 3 + 1) * 264 + c];
    float V2 = (float)MM[(nn * 3 + 2) * 264 + c];
    float vnv = sqrtf(V0 * V0 + V1 * V1 + V2 * V2 + 1e-8f);
    int kb = c >> 5, c8 = (c >> 3) & 3, ce = c & 7;
    VN[((kb * 32 + nn) << 5) + ((c8 ^ ((nn >> 1) & 3)) << 3) + ce] = (f16)vnv;
  }
  __syncthreads();

  const int wmB = (wave & 1) * 16, wnB = (wave >> 1) * 64;
  f32x4 accB[4] = {};
  #pragma unroll
  for (int kk = 0; kk < 8; ++kk) {
    f16x8 af;
    int row = wmB + lr;
    if (kk < 4) {
      const float* qp_ = q + (size_t)(n0 + row) * 128 + kk * 32 + lk * 8;
      float4 v0 = ((const float4*)qp_)[0];
      float4 v1 = ((const float4*)qp_)[1];
      af[0]=(f16)v0.x; af[1]=(f16)v0.y; af[2]=(f16)v0.z; af[3]=(f16)v0.w;
      af[4]=(f16)v1.x; af[5]=(f16)v1.y; af[6]=(f16)v1.z; af[7]=(f16)v1.w;
    } else {
      af = *(const f16x8*)&VN[(((kk - 4) * 32 + row) << 5) + ((lk ^ ((row >> 1) & 3)) << 3)];
    }
    f16x8 bf[4];
    #pragma unroll
    for (int nt = 0; nt < 4; ++nt)
      bf[nt] = *(const f16x8*)&W1[(size_t)(wnB + nt * 16 + lr) * 256 + kk * 32 + lk * 8];
    #pragma unroll
    for (int nt = 0; nt < 4; ++nt)
      accB[nt] = __builtin_amdgcn_mfma_f32_16x16x32_f16(af, bf[nt], accB[nt], 0, 0, 0);
  }
  #pragma unroll
  for (int nt = 0; nt < 4; ++nt) {
    int col = wnB + nt * 16 + lr;
    float bv = b1[col];
    #pragma unroll
    for (int rr = 0; rr < 4; ++rr) {
      int row = wmB + lk * 4 + rr;
      float v = accB[nt][rr] + bv;
      v = v / (1.0f + expf(-v));
      HS[row * 132 + col] = (f16)v;
    }
  }
  __syncthreads();

  f32x4 accC[3][4] = {};
  #pragma unroll
  for (int cc = 0; cc < 3; ++cc)
    #pragma unroll
    for (int kk = 0; kk < 4; ++kk) {
      f16x8 af = *(const f16x8*)&HS[(wmB + lr) * 132 + kk * 32 + lk * 8];
      f16x8 bf[4];
      #pragma unroll
      for (int nt = 0; nt < 4; ++nt)
        bf[nt] = *(const f16x8*)&W2[(size_t)(cc * 128 + wnB + nt * 16 + lr) * 128 + kk * 32 + lk * 8];
      #pragma unroll
      for (int nt = 0; nt < 4; ++nt)
        accC[cc][nt] = __builtin_amdgcn_mfma_f32_16x16x32_f16(af, bf[nt], accC[cc][nt], 0, 0, 0);
    }
  #pragma unroll
  for (int nt = 0; nt < 4; ++nt) {
    int col = wnB + nt * 16 + lr;
    float b_dq = b2[col], b_dmu = b2[128 + col], b_dqmu = b2[256 + col];
    #pragma unroll
    for (int rr = 0; rr < 4; ++rr) {
      int nn = wmB + lk * 4 + rr;
      int gm = n0 + nn;
      float dq   = accC[0][nt][rr] + b_dq;
      float dmu  = accC[1][nt][rr] + b_dmu;
      float dqmu = accC[2][nt][rr] + b_dqmu;
      float V0 = (float)MM[(nn * 3 + 0) * 264 + col], W0 = (float)MM[(nn * 3 + 0) * 264 + 128 + col];
      float V1 = (float)MM[(nn * 3 + 1) * 264 + col], W1v = (float)MM[(nn * 3 + 1) * 264 + 128 + col];
      float V2 = (float)MM[(nn * 3 + 2) * 264 + col], W2v = (float)MM[(nn * 3 + 2) * 264 + 128 + col];
      float svw = V0 * W0 + V1 * W1v + V2 * W2v;
      size_t qi = (size_t)gm * 128 + col;
      q[qi] += dq + dqmu * svw;
      f16* mr = mu + (size_t)gm * 384;
      mr[col]       = (f16)((float)mr[col]       + dmu * W0);
      mr[128 + col] = (f16)((float)mr[128 + col] + dmu * W1v);
      mr[256 + col] = (f16)((float)mr[256 + col] + dmu * W2v);
    }
  }
}

// ---------------- per-node edge reduction (HASMU=false at layer 0: mu==0) ----------------
template<bool HASMU>
__global__ __launch_bounds__(256) void k_edge_msg(
    const int* __restrict__ rs, const int* __restrict__ jperm,
    const f16* __restrict__ x, const f16* __restrict__ tab,
    const float4* __restrict__ geo, const f16* __restrict__ mu_in,
    float* __restrict__ q, f16* __restrict__ mu_out) {
  const int wid  = threadIdx.x >> 6;
  const int lane = threadIdx.x & 63;
  const int i = blockIdx.x * 4 + wid;
  if (i >= N_NODES) return;
  const int d0 = lane * 2;
  const float scale = (float)(TAB_T - 1) / 5.0f;
  float aqx = 0.f, aqy = 0.f;
  float a0x = 0.f, a0y = 0.f, a1x = 0.f, a1y = 0.f, a2x = 0.f, a2y = 0.f;
  const int s = rs[i], e = rs[i + 1];

  for (int p = s; p < e; ++p) {
    int j = jperm[p];
    float4 g = geo[p];
    float u = fminf(g.x, 5.0f) * scale;
    int t0 = min((int)u, TAB_T - 2);
    float fr = u - (float)t0, fo = 1.0f - fr;
    const f16* ta = tab + (size_t)t0 * 384;
    const f16* xj = x + (size_t)j * 384;
    f16x2 ta0 = *(const f16x2*)(ta + d0);
    f16x2 ta1 = *(const f16x2*)(ta + 128 + d0);
    f16x2 tb0 = *(const f16x2*)(ta + 384 + d0);
    f16x2 tb1 = *(const f16x2*)(ta + 512 + d0);
    f16x2 xv0 = *(const f16x2*)(xj + d0);
    f16x2 xv1 = *(const f16x2*)(xj + 128 + d0);
    float W0x = fo * (float)ta0[0] + fr * (float)tb0[0];
    float W0y = fo * (float)ta0[1] + fr * (float)tb0[1];
    float W1x = fo * (float)ta1[0] + fr * (float)tb1[0];
    float W1y = fo * (float)ta1[1] + fr * (float)tb1[1];
    float m1x = (float)xv1[0] * W1x, m1y = (float)xv1[1] * W1y;
    aqx = fmaf((float)xv0[0], W0x, aqx);
    aqy = fmaf((float)xv0[1], W0y, aqy);
    if constexpr (HASMU) {
      f16x2 ta2 = *(const f16x2*)(ta + 256 + d0);
      f16x2 tb2 = *(const f16x2*)(ta + 640 + d0);
      f16x2 xv2 = *(const f16x2*)(xj + 256 + d0);
      const f16* mj = mu_in + (size_t)j * 384;
      f16x2 mv0 = *(const f16x2*)(mj + d0);
      f16x2 mv1 = *(const f16x2*)(mj + 128 + d0);
      f16x2 mv2 = *(const f16x2*)(mj + 256 + d0);
      float W2x = fo * (float)ta2[0] + fr * (float)tb2[0];
      float W2y = fo * (float)ta2[1] + fr * (float)tb2[1];
      float m2x = (float)xv2[0] * W2x, m2y = (float)xv2[1] * W2y;
      a0x += m1x * g.y + m2x * (float)mv0[0];
      a0y += m1y * g.y + m2y * (float)mv0[1];
      a1x += m1x * g.z + m2x * (float)mv1[0];
      a1y += m1y * g.z + m2y * (float)mv1[1];
      a2x += m1x * g.w + m2x * (float)mv2[0];
      a2y += m1y * g.w + m2y * (float)mv2[1];
    } else {
      a0x += m1x * g.y; a0y += m1y * g.y;
      a1x += m1x * g.z; a1y += m1y * g.z;
      a2x += m1x * g.w; a2y += m1y * g.w;
    }
  }

  float* qp = q + (size_t)i * 128 + d0;
  float2 qv = *(float2*)qp;
  qv.x += aqx; qv.y += aqy;
  *(float2*)qp = qv;
  f16* mout = mu_out + (size_t)i * 384;
  f16x2 o0, o1, o2;
  if constexpr (HASMU) {
    const f16* min_ = mu_in + (size_t)i * 384;
    f16x2 i0 = *(const f16x2*)(min_ + d0);
    f16x2 i1 = *(const f16x2*)(min_ + 128 + d0);
    f16x2 i2 = *(const f16x2*)(min_ + 256 + d0);
    o0[0] = (f16)((float)i0[0] + a0x); o0[1] = (f16)((float)i0[1] + a0y);
    o1[0] = (f16)((float)i1[0] + a1x); o1[1] = (f16)((float)i1[1] + a1y);
    o2[0] = (f16)((float)i2[0] + a2x); o2[1] = (f16)((float)i2[1] + a2y);
  } else {
    o0[0] = (f16)a0x; o0[1] = (f16)a0y;
    o1[0] = (f16)a1x; o1[1] = (f16)a1y;
    o2[0] = (f16)a2x; o2[1] = (f16)a2y;
  }
  *(f16x2*)(mout + d0)       = o0;
  *(f16x2*)(mout + 128 + d0) = o1;
  *(f16x2*)(mout + 256 + d0) = o2;
}

// ---------------- final outputs (posattr + ln merged) ----------------
__global__ __launch_bounds__(256) void k_outputs(
    const int* __restrict__ rs, const int* __restrict__ jperm,
    const f16* __restrict__ mu, const float* __restrict__ w, float* __restrict__ pos_out,
    const float* __restrict__ q, const float* __restrict__ g_, const float* __restrict__ b_,
    float* __restrict__ out_node) {
  const int wid  = threadIdx.x >> 6;
  const int lane = threadIdx.x & 63;
  const int i = blockIdx.x * 4 + wid;
  if (i >= N_NODES) return;
  const int d0 = lane * 2;
  if (blockIdx.y == 1) {
    // LayerNorm + tanh
    float2 v = *(const float2*)(q + (size_t)i * 128 + d0);
    float v0 = fminf(fmaxf(v.x, -5.f), 5.f);
    float v1 = fminf(fmaxf(v.y, -5.f), 5.f);
    float s = v0 + v1, s2 = v0 * v0 + v1 * v1;
    #pragma unroll
    for (int off = 32; off > 0; off >>= 1) {
      s  += __shfl_down(s,  off, 64);
      s2 += __shfl_down(s2, off, 64);
    }
    s  = __shfl(s,  0, 64);
    s2 = __shfl(s2, 0, 64);
    float mean = s * (1.0f / 128.0f);
    float var  = s2 * (1.0f / 128.0f) - mean * mean;
    float r = rsqrtf(var + 1e-5f);
    out_node[(size_t)i * 128 + d0]     = tanhf((v0 - mean) * r * g_[d0]     + b_[d0]);
    out_node[(size_t)i * 128 + d0 + 1] = tanhf((v1 - mean) * r * g_[d0 + 1] + b_[d0 + 1]);
    return;
  }
  // pos_attr
  float a0x = 0.f, a0y = 0.f, a1x = 0.f, a1y = 0.f, a2x = 0.f, a2y = 0.f;
  const int s = rs[i], e = rs[i + 1];
  int p = s;
  for (; p + 2 <= e; p += 2) {
    int jA = jperm[p], jB = jperm[p + 1];
    const f16* mA = mu + (size_t)jA * 384;
    const f16* mB = mu + (size_t)jB * 384;
    f16x2 A0 = *(const f16x2*)(mA + d0);
    f16x2 A1 = *(const f16x2*)(mA + 128 + d0);
    f16x2 A2 = *(const f16x2*)(mA + 256 + d0);
    f16x2 B0 = *(const f16x2*)(mB + d0);
    f16x2 B1 = *(const f16x2*)(mB + 128 + d0);
    f16x2 B2 = *(const f16x2*)(mB + 256 + d0);
    a0x += (float)A0[0] + (float)B0[0]; a0y += (float)A0[1] + (float)B0[1];
    a1x += (float)A1[0] + (float)B1[0]; a1y += (float)A1[1] + (float)B1[1];
    a2x += (float)A2[0] + (float)B2[0]; a2y += (float)A2[1] + (float)B2[1];
  }
  for (; p < e; ++p) {
    int j = jperm[p];
    const f16* mj = mu + (size_t)j * 384;
    f16x2 A0 = *(const f16x2*)(mj + d0);
    f16x2 A1 = *(const f16x2*)(mj + 128 + d0);
    f16x2 A2 = *(const f16x2*)(mj + 256 + d0);
    a0x += (float)A0[0]; a0y += (float)A0[1];
    a1x += (float)A1[0]; a1y += (float)A1[1];
    a2x += (float)A2[0]; a2y += (float)A2[1];
  }
  float wx = w[d0], wy = w[d0 + 1];
  float s0 = fminf(fmaxf(a0x, -5.f), 5.f) * wx + fminf(fmaxf(a0y, -5.f), 5.f) * wy;
  float s1 = fminf(fmaxf(a1x, -5.f), 5.f) * wx + fminf(fmaxf(a1y, -5.f), 5.f) * wy;
  float s2 = fminf(fmaxf(a2x, -5.f), 5.f) * wx + fminf(fmaxf(a2y, -5.f), 5.f) * wy;
  #pragma unroll
  for (int off = 32; off > 0; off >>= 1) {
    s0 += __shfl_down(s0, off, 64);
    s1 += __shfl_down(s1, off, 64);
    s2 += __shfl_down(s2, off, 64);
  }
  if (lane == 0) {
    pos_out[(size_t)i * 3 + 0] = fminf(fmaxf(s0, -5.f), 5.f);
    pos_out[(size_t)i * 3 + 1] = fminf(fmaxf(s1, -5.f), 5.f);
    pos_out[(size_t)i * 3 + 2] = fminf(fmaxf(s2, -5.f), 5.f);
  }
}

extern "C" void kernel_launch(void* const* d_in, const int* in_sizes, int n_in,
                              void* d_out, int out_size, void* d_ws, size_t ws_size,
                              hipStream_t stream) {
  const float* z         = (const float*)d_in[0];
  const float* pos       = (const float*)d_in[1];
  const int*   edge_idx  = (const int*)d_in[2];
  const float* in_w      = (const float*)d_in[3];
  const float* in_b      = (const float*)d_in[4];
  const float* filt_w    = (const float*)d_in[5];
  const float* filt_b    = (const float*)d_in[6];
  const float* inter_w1  = (const float*)d_in[7];
  const float* inter_b1  = (const float*)d_in[8];
  const float* inter_w2  = (const float*)d_in[9];
  const float* inter_b2  = (const float*)d_in[10];
  const float* mix_mu_w  = (const float*)d_in[11];
  const float* mix_w1    = (const float*)d_in[12];
  const float* mix_b1    = (const float*)d_in[13];
  const float* mix_w2    = (const float*)d_in[14];
  const float* mix_b2    = (const float*)d_in[15];
  const float* mu_proj_w = (const float*)d_in[16];
  const float* ln_g      = (const float*)d_in[17];
  const float* ln_b      = (const float*)d_in[18];

  char* base = (char*)d_ws;
  size_t off = 0;
  auto alloc = [&](size_t bytes) -> char* {
    char* p = base + off;
    off += (bytes + 255) & ~(size_t)255;
    return p;
  };
  float*  q     = (float*)alloc((size_t)N_NODES * 128 * 4);
  f16*    x16   = (f16*)alloc((size_t)N_NODES * 384 * 2);
  f16*    mu_a  = (f16*)alloc((size_t)N_NODES * 384 * 2);
  f16*    mu_b  = (f16*)alloc((size_t)N_NODES * 384 * 2);
  float4* geo   = (float4*)alloc((size_t)N_EDGES * 16);
  int*    cnt   = (int*)alloc((size_t)N_NODES * 4);
  int*    incl  = (int*)alloc((size_t)N_NODES * 4);
  int*    bsum  = (int*)alloc(128 * 4);
  int*    rs    = (int*)alloc((size_t)(N_NODES + 1) * 4);
  int*    cur   = (int*)alloc((size_t)N_NODES * 4);
  int*    jperm = (int*)alloc((size_t)N_EDGES * 4);
  f16*    tab   = (f16*)alloc((size_t)TAB_T * 384 * 2);
  // f16 transposed weights
  f16* wt_in = (f16*)alloc((size_t)128 * 64 * 2);
  f16* wt_i1 = (f16*)alloc((size_t)3 * 128 * 128 * 2);
  f16* wt_i2 = (f16*)alloc((size_t)3 * 384 * 128 * 2);
  f16* wt_mu = (f16*)alloc((size_t)3 * 256 * 128 * 2);
  f16* wt_x1 = (f16*)alloc((size_t)3 * 128 * 256 * 2);
  f16* wt_x2 = (f16*)alloc((size_t)3 * 384 * 128 * 2);
  if (off > ws_size) return;

  float* out_node = (float*)d_out;
  float* out_pos  = (float*)d_out + (size_t)N_NODES * 128;

  // ---- prep: weight transpose (16 jobs) + filter table, one dispatch ----
  {
    WJobs jb;
    int ji = 0;
    jb.j[ji++] = {in_w, wt_in, 6, 128, 0, 128 * 64};
    for (int l = 0; l < 3; ++l)
      jb.j[ji++] = {inter_w1 + (size_t)l*128*128, wt_i1 + (size_t)l*128*128, 7, 128, 0, 128*128};
    for (int l = 0; l < 3; ++l)
      jb.j[ji++] = {inter_w2 + (size_t)l*128*384, wt_i2 + (size_t)l*384*128, 7, 384, 0, 384*128};
    for (int l = 0; l < 3; ++l)
      jb.j[ji++] = {mix_mu_w + (size_t)l*128*256, wt_mu + (size_t)l*256*128, 7, 256, 0, 256*128};
    for (int l = 0; l < 3; ++l)
      jb.j[ji++] = {mix_w1 + (size_t)l*256*128, wt_x1 + (size_t)l*128*256, 8, 128, 0, 128*256};
    for (int l = 0; l < 3; ++l)
      jb.j[ji++] = {mix_w2 + (size_t)l*128*384, wt_x2 + (size_t)l*384*128, 7, 384, 0, 384*128};
    dim3 g(192, 24);  // y<16: wt jobs; y>=16: tab rows (8 x 128)
    k_prep<<<g, 256, 0, stream>>>(jb, filt_w, filt_b, tab);
  }

  // ---- CSR build + geometry ----
  hipMemsetAsync(cnt, 0, (size_t)N_NODES * 4, stream);
  k_hist<<<N_EDGES / 256, 256, 0, stream>>>(edge_idx, cnt);
  k_scan_blk<<<NB_SCAN, 256, 0, stream>>>(cnt, incl, bsum);
  k_scan_top<<<1, 128, 0, stream>>>(bsum);
  k_scan_add<<<NB_SCAN, 256, 0, stream>>>(cnt, incl, bsum, rs, cur);
  k_fill_geom<<<N_EDGES / 256, 256, 0, stream>>>(edge_idx, pos, cur, geo, jperm);

  // ---- input embedding ----
  dim3 ge((N_NODES + 127) / 128, 1);
  k_mgemm<1, float, float><<<ge, 256, 0, stream>>>(z, wt_in, in_b, q, N_NODES, 64, 128);

  f16* mu_cur = mu_a;
  f16* mu_nxt = mu_b;
  const int gn4 = (N_NODES + 3) / 4;
  const int gf  = (N_NODES + 63) / 64;   // 313
  const int gmx = N_NODES / 32;          // 625
  for (int l = 0; l < NLAYER; ++l) {
    k_fused_i<<<gf, 256, 0, stream>>>(q, wt_i1 + (size_t)l*128*128, inter_b1 + (size_t)l*128,
                                      wt_i2 + (size_t)l*384*128, inter_b2 + (size_t)l*384,
                                      x16, N_NODES);
    if (l == 0)
      k_edge_msg<false><<<gn4, 256, 0, stream>>>(rs, jperm, x16, tab, geo, mu_cur, q, mu_nxt);
    else
      k_edge_msg<true><<<gn4, 256, 0, stream>>>(rs, jperm, x16, tab, geo, mu_cur, q, mu_nxt);
    { f16* t = mu_cur; mu_cur = mu_nxt; mu_nxt = t; }
    k_fused_mx<<<gmx, 256, 0, stream>>>(q, mu_cur, wt_mu + (size_t)l*256*128,
                                        wt_x1 + (size_t)l*128*256, mix_b1 + (size_t)l*128,
                                        wt_x2 + (size_t)l*384*128, mix_b2 + (size_t)l*384);
  }

  // ---- outputs (posattr + ln, one dispatch) ----
  dim3 go(gn4, 2);
  k_outputs<<<go, 256, 0, stream>>>(rs, jperm, mu_cur, mu_proj_w, out_pos,
                                    q, ln_g, ln_b, out_node);
}

// Round 11
// 546.150 us; speedup vs baseline: 4.5558x; 1.0753x over previous
//
#include <hip/hip_runtime.h>
#include <math.h>

#ifndef M_PI
#define M_PI 3.14159265358979323846
#endif

static constexpr int N_NODES = 20000;
static constexpr int N_EDGES = 320000;
static constexpr int NLAYER  = 3;
static constexpr int NB_SCAN = (N_NODES + 255) / 256;  // 79
static constexpr int TAB_T   = 1024;                   // filter lookup rows (L2-resident)

typedef _Float16 f16;
typedef __attribute__((ext_vector_type(2))) _Float16 f16x2;
typedef __attribute__((ext_vector_type(8))) _Float16 f16x8;
typedef __attribute__((ext_vector_type(4))) float f32x4;

// ---------------- CSR build ----------------
__global__ void k_hist(const int* __restrict__ idx_i, int* __restrict__ cnt) {
  int e = blockIdx.x * 256 + threadIdx.x;
  if (e < N_EDGES) atomicAdd(&cnt[idx_i[e]], 1);
}

__global__ void k_scan_blk(const int* __restrict__ cnt, int* __restrict__ incl,
                           int* __restrict__ bsum) {
  __shared__ int buf[256];
  int t = threadIdx.x;
  int i = blockIdx.x * 256 + t;
  int v = (i < N_NODES) ? cnt[i] : 0;
  buf[t] = v;
  __syncthreads();
  #pragma unroll
  for (int off = 1; off < 256; off <<= 1) {
    int x = (t >= off) ? buf[t - off] : 0;
    __syncthreads();
    buf[t] += x;
    __syncthreads();
  }
  if (i < N_NODES) incl[i] = buf[t];
  if (t == 255) bsum[blockIdx.x] = buf[255];
}

__global__ void k_scan_top(int* __restrict__ bsum) {
  __shared__ int buf[128];
  int t = threadIdx.x;
  int v = (t < NB_SCAN) ? bsum[t] : 0;
  buf[t] = v;
  __syncthreads();
  #pragma unroll
  for (int off = 1; off < 128; off <<= 1) {
    int x = (t >= off) ? buf[t - off] : 0;
    __syncthreads();
    buf[t] += x;
    __syncthreads();
  }
  if (t <= NB_SCAN) bsum[t] = buf[t] - v;  // exclusive; t==NB_SCAN -> total
}

__global__ void k_scan_add(const int* __restrict__ cnt, const int* __restrict__ incl,
                           const int* __restrict__ bsum, int* __restrict__ rs,
                           int* __restrict__ cur) {
  int i = blockIdx.x * 256 + threadIdx.x;
  if (i < N_NODES) {
    int v = bsum[blockIdx.x] + incl[i] - cnt[i];
    rs[i] = v;
    cur[i] = v;
  }
  if (i == 0) rs[N_NODES] = bsum[NB_SCAN];
}

// ---------------- fill + edge geometry (merged): geo = {d, dx, dy, dz} ----------------
__global__ void k_fill_geom(const int* __restrict__ idx_all, const float* __restrict__ pos,
                            int* __restrict__ cur, float4* __restrict__ geo,
                            int* __restrict__ jperm) {
  int e = blockIdx.x * 256 + threadIdx.x;
  if (e >= N_EDGES) return;
  int i = idx_all[e];
  int j = idx_all[N_EDGES + e];
  int p = atomicAdd(&cur[i], 1);
  float rx = pos[j*3+0] - pos[i*3+0];
  float ry = pos[j*3+1] - pos[i*3+1];
  float rz = pos[j*3+2] - pos[i*3+2];
  float d = sqrtf(rx*rx + ry*ry + rz*rz);
  d = fmaxf(d, 1e-8f);
  float inv = 1.0f / d;
  geo[p] = make_float4(d, rx*inv, ry*inv, rz*inv);
  jperm[p] = j;
}

// ---------------- weight transpose + filter table (merged prep) ----------------
struct WJob { const float* src; f16* dst; int kshift; int ld; int col0; int nk; };
struct WJobs { WJob j[16]; };

__global__ __launch_bounds__(256) void k_prep(WJobs jb, const float* __restrict__ filt_w,
                                              const float* __restrict__ filt_b,
                                              f16* __restrict__ tab) {
  if (blockIdx.y < 16) {
    WJob w = jb.j[blockIdx.y];
    int t = blockIdx.x * 256 + threadIdx.x;
    if (t >= w.nk) return;
    int K = 1 << w.kshift;
    int n = t >> w.kshift;
    int k = t & (K - 1);
    w.dst[t] = (f16)w.src[(size_t)k * w.ld + w.col0 + n];
    return;
  }
  if (blockIdx.x >= 128) return;
  const int t = (blockIdx.y - 16) * 128 + blockIdx.x;
  __shared__ float ph[64];
  const int tid = threadIdx.x;
  const float dist = 5.0f * (float)t / (float)(TAB_T - 1);
  const float delta = 5.0f / 63.0f;
  const float coeff = -0.5f / (delta * delta);
  if (tid < 64) {
    float u = dist - delta * (float)tid;
    ph[tid] = expf(coeff * u * u);
  }
  __syncthreads();
  float xc = dist * 0.2f;
  float fc = (xc < 1.0f) ? 0.5f * (cosf((float)M_PI * xc) + 1.0f) : 0.0f;
  for (int n = tid; n < 384; n += 256) {
    float acc = 0.f;
    #pragma unroll
    for (int k = 0; k < 64; ++k) acc += ph[k] * filt_w[k * 384 + n];
    float v = (acc + filt_b[n]) * fc;
    v = fminf(fmaxf(v, -5.0f), 5.0f);
    tab[(size_t)t * 384 + n] = (f16)v;
  }
}

// ======== embed + inter MLP (layer 0): q = silu(z@Win^T+b); x = silu(q@Wi1^T+b)@Wi2^T+b ========
// 32 nodes/block, 625 blocks. N_NODES % 32 == 0.
__global__ __launch_bounds__(256) void k_embed_i(
    const float* __restrict__ z, const f16* __restrict__ Win, const float* __restrict__ bin,
    const f16* __restrict__ Wi1, const float* __restrict__ bi1,
    const f16* __restrict__ Wi2, const float* __restrict__ bi2,
    float* __restrict__ q, f16* __restrict__ xout) {
  __shared__ __align__(16) char pool[16896];
  f16* QS  = (f16*)pool;            // [32][132]
  f16* H2S = (f16*)(pool + 8448);   // [32][132]
  const int tid = threadIdx.x;
  const int wave = tid >> 6, lane = tid & 63;
  const int lr = lane & 15, lk = lane >> 4;
  const int wmB = (wave & 1) * 16, wnB = (wave >> 1) * 64;
  const int n0 = blockIdx.x * 32;

  // phase P: q = silu(z @ Win^T + bin), 32x128, K=64
  f32x4 accP[4] = {};
  #pragma unroll
  for (int kk = 0; kk < 2; ++kk) {
    const float* zp = z + (size_t)(n0 + wmB + lr) * 64 + kk * 32 + lk * 8;
    float4 v0 = ((const float4*)zp)[0];
    float4 v1 = ((const float4*)zp)[1];
    f16x8 af;
    af[0]=(f16)v0.x; af[1]=(f16)v0.y; af[2]=(f16)v0.z; af[3]=(f16)v0.w;
    af[4]=(f16)v1.x; af[5]=(f16)v1.y; af[6]=(f16)v1.z; af[7]=(f16)v1.w;
    f16x8 bf[4];
    #pragma unroll
    for (int nt = 0; nt < 4; ++nt)
      bf[nt] = *(const f16x8*)&Win[(size_t)(wnB + nt * 16 + lr) * 64 + kk * 32 + lk * 8];
    #pragma unroll
    for (int nt = 0; nt < 4; ++nt)
      accP[nt] = __builtin_amdgcn_mfma_f32_16x16x32_f16(af, bf[nt], accP[nt], 0, 0, 0);
  }
  #pragma unroll
  for (int nt = 0; nt < 4; ++nt) {
    int col = wnB + nt * 16 + lr;
    float bv = bin[col];
    #pragma unroll
    for (int rr = 0; rr < 4; ++rr) {
      int row = wmB + lk * 4 + rr;
      float v = accP[nt][rr] + bv;
      v = v / (1.0f + expf(-v));
      q[(size_t)(n0 + row) * 128 + col] = v;
      QS[row * 132 + col] = (f16)v;
    }
  }
  __syncthreads();

  // phase D: h2 = silu(QS @ Wi1^T + bi1)
  f32x4 accD[4] = {};
  #pragma unroll
  for (int kk = 0; kk < 4; ++kk) {
    f16x8 af = *(const f16x8*)&QS[(wmB + lr) * 132 + kk * 32 + lk * 8];
    f16x8 bf[4];
    #pragma unroll
    for (int nt = 0; nt < 4; ++nt)
      bf[nt] = *(const f16x8*)&Wi1[(size_t)(wnB + nt * 16 + lr) * 128 + kk * 32 + lk * 8];
    #pragma unroll
    for (int nt = 0; nt < 4; ++nt)
      accD[nt] = __builtin_amdgcn_mfma_f32_16x16x32_f16(af, bf[nt], accD[nt], 0, 0, 0);
  }
  #pragma unroll
  for (int nt = 0; nt < 4; ++nt) {
    int col = wnB + nt * 16 + lr;
    float bv = bi1[col];
    #pragma unroll
    for (int rr = 0; rr < 4; ++rr) {
      int row = wmB + lk * 4 + rr;
      float v = accD[nt][rr] + bv;
      v = v / (1.0f + expf(-v));
      H2S[row * 132 + col] = (f16)v;
    }
  }
  __syncthreads();

  // phase E: x = h2 @ Wi2^T + bi2 (3 chunks of 128)
  #pragma unroll
  for (int cc = 0; cc < 3; ++cc) {
    f32x4 accE[4] = {};
    #pragma unroll
    for (int kk = 0; kk < 4; ++kk) {
      f16x8 af = *(const f16x8*)&H2S[(wmB + lr) * 132 + kk * 32 + lk * 8];
      f16x8 bf[4];
      #pragma unroll
      for (int nt = 0; nt < 4; ++nt)
        bf[nt] = *(const f16x8*)&Wi2[(size_t)(cc * 128 + wnB + nt * 16 + lr) * 128 + kk * 32 + lk * 8];
      #pragma unroll
      for (int nt = 0; nt < 4; ++nt)
        accE[nt] = __builtin_amdgcn_mfma_f32_16x16x32_f16(af, bf[nt], accE[nt], 0, 0, 0);
    }
    #pragma unroll
    for (int nt = 0; nt < 4; ++nt) {
      int gn = cc * 128 + wnB + nt * 16 + lr;
      float bv = bi2[gn];
      #pragma unroll
      for (int rr = 0; rr < 4; ++rr) {
        int gm = n0 + wmB + lk * 4 + rr;
        xout[(size_t)gm * 384 + gn] = (f16)(accE[nt][rr] + bv);
      }
    }
  }
}

// ======== fused mix phase (+ next-layer inter MLP or final LayerNorm) ========
// MODE 0: mix + inter MLP (Wi1/Wi2/bi1/bi2, xout). MODE 1: mix + LN+tanh (ln_g/ln_b/out_node).
template<int MODE>
__global__ __launch_bounds__(256) void k_mix(
    float* __restrict__ q, f16* __restrict__ mu,
    const f16* __restrict__ Wmu,
    const f16* __restrict__ W1, const float* __restrict__ b1,
    const f16* __restrict__ W2, const float* __restrict__ b2,
    const f16* __restrict__ Wi1, const float* __restrict__ bi1,
    const f16* __restrict__ Wi2, const float* __restrict__ bi2,
    f16* __restrict__ xout,
    const float* __restrict__ ln_g, const float* __restrict__ ln_b,
    float* __restrict__ out_node) {
  __shared__ __align__(16) char pool[50688 + 25344];
  f16*   MM  = (f16*)pool;              // [96][264]
  char*  scr = pool + 50688;
  f16*   As4 = (f16*)scr;               // [4][96][32] (staging; dead after phase A)
  f16*   VN  = (f16*)scr;               // [4][32][32] (phase B input)
  f16*   HS  = (f16*)(scr + 8448);      // [32][132]  (phase C input)
  f16*   QS  = (f16*)(scr + 16896);     // [32][132] f16 (MODE 0)
  f16*   H2S = (f16*)scr;               // [32][132]  (MODE 0 phase D out)
  float* QSf = (float*)scr;             // [32][132] f32 (MODE 1)

  const int tid = threadIdx.x;
  const int wave = tid >> 6, lane = tid & 63;
  const int lr = lane & 15, lk = lane >> 4;
  const int n0 = blockIdx.x * 32;
  const int r0 = n0 * 3;

  // ---- stage mu rows into As4 (k-block-major, XOR swizzle) ----
  #pragma unroll
  for (int rep = 0; rep < 6; ++rep) {
    int idx = rep * 256 + tid;
    int row = idx >> 4;
    int g   = idx & 15;
    int kb = g >> 2, c8 = g & 3;
    f16x8 v = *(const f16x8*)(mu + (size_t)(r0 + row) * 128 + g * 8);
    *(f16x8*)&As4[((kb * 96 + row) << 5) + ((c8 ^ ((row >> 1) & 3)) << 3)] = v;
  }
  __syncthreads();

  // ---- phase A: MM = mu @ Wmu^T (96 x 256) ----
  const int wmA = (wave & 1) * 48;
  const int wnA0 = (wave >> 1) * 64;
  #pragma unroll
  for (int half = 0; half < 2; ++half) {
    f32x4 accA[3][4] = {};
    #pragma unroll
    for (int kk = 0; kk < 4; ++kk) {
      f16x8 af[3], bf[4];
      #pragma unroll
      for (int mt = 0; mt < 3; ++mt) {
        int r = wmA + mt * 16 + lr;
        af[mt] = *(const f16x8*)&As4[((kk * 96 + r) << 5) + ((lk ^ ((r >> 1) & 3)) << 3)];
      }
      #pragma unroll
      for (int nt = 0; nt < 4; ++nt)
        bf[nt] = *(const f16x8*)&Wmu[(size_t)(half * 128 + wnA0 + nt * 16 + lr) * 128 + kk * 32 + lk * 8];
      #pragma unroll
      for (int mt = 0; mt < 3; ++mt)
        #pragma unroll
        for (int nt = 0; nt < 4; ++nt)
          accA[mt][nt] = __builtin_amdgcn_mfma_f32_16x16x32_f16(af[mt], bf[nt], accA[mt][nt], 0, 0, 0);
    }
    #pragma unroll
    for (int mt = 0; mt < 3; ++mt)
      #pragma unroll
      for (int nt = 0; nt < 4; ++nt) {
        int col = half * 128 + wnA0 + nt * 16 + lr;
        #pragma unroll
        for (int rr = 0; rr < 4; ++rr) {
          int row = wmA + mt * 16 + lk * 4 + rr;
          MM[row * 264 + col] = (f16)accA[mt][nt][rr];
        }
      }
  }
  __syncthreads();

  // ---- vn pass -> VN (XOR-swizzled) ----
  #pragma unroll
  for (int rep = 0; rep < 16; ++rep) {
    int idx = rep * 256 + tid;
    int nn = idx >> 7, c = idx & 127;
    float V0 = (float)MM[(nn * 3 + 0) * 264 + c];
    float V1 = (float)MM[(nn * 3 + 1) * 264 + c];
    float V2 = (float)MM[(nn * 3 + 2) * 264 + c];
    float vnv = sqrtf(V0 * V0 + V1 * V1 + V2 * V2 + 1e-8f);
    int kb = c >> 5, c8 = (c >> 3) & 3, ce = c & 7;
    VN[((kb * 32 + nn) << 5) + ((c8 ^ ((nn >> 1) & 3)) << 3) + ce] = (f16)vnv;
  }
  __syncthreads();

  // ---- phase B: h = silu([q|vn] @ W1^T + b1) -> HS ----
  const int wmB = (wave & 1) * 16, wnB = (wave >> 1) * 64;
  f32x4 accB[4] = {};
  #pragma unroll
  for (int kk = 0; kk < 8; ++kk) {
    f16x8 af;
    int row = wmB + lr;
    if (kk < 4) {
      const float* qp_ = q + (size_t)(n0 + row) * 128 + kk * 32 + lk * 8;
      float4 v0 = ((const float4*)qp_)[0];
      float4 v1 = ((const float4*)qp_)[1];
      af[0]=(f16)v0.x; af[1]=(f16)v0.y; af[2]=(f16)v0.z; af[3]=(f16)v0.w;
      af[4]=(f16)v1.x; af[5]=(f16)v1.y; af[6]=(f16)v1.z; af[7]=(f16)v1.w;
    } else {
      af = *(const f16x8*)&VN[(((kk - 4) * 32 + row) << 5) + ((lk ^ ((row >> 1) & 3)) << 3)];
    }
    f16x8 bf[4];
    #pragma unroll
    for (int nt = 0; nt < 4; ++nt)
      bf[nt] = *(const f16x8*)&W1[(size_t)(wnB + nt * 16 + lr) * 256 + kk * 32 + lk * 8];
    #pragma unroll
    for (int nt = 0; nt < 4; ++nt)
      accB[nt] = __builtin_amdgcn_mfma_f32_16x16x32_f16(af, bf[nt], accB[nt], 0, 0, 0);
  }
  #pragma unroll
  for (int nt = 0; nt < 4; ++nt) {
    int col = wnB + nt * 16 + lr;
    float bv = b1[col];
    #pragma unroll
    for (int rr = 0; rr < 4; ++rr) {
      int row = wmB + lk * 4 + rr;
      float v = accB[nt][rr] + bv;
      v = v / (1.0f + expf(-v));
      HS[row * 132 + col] = (f16)v;
    }
  }
  __syncthreads();

  // ---- phase C: xm = h @ W2^T + b2 ----
  f32x4 accC[3][4] = {};
  #pragma unroll
  for (int cc = 0; cc < 3; ++cc)
    #pragma unroll
    for (int kk = 0; kk < 4; ++kk) {
      f16x8 af = *(const f16x8*)&HS[(wmB + lr) * 132 + kk * 32 + lk * 8];
      f16x8 bf[4];
      #pragma unroll
      for (int nt = 0; nt < 4; ++nt)
        bf[nt] = *(const f16x8*)&W2[(size_t)(cc * 128 + wnB + nt * 16 + lr) * 128 + kk * 32 + lk * 8];
      #pragma unroll
      for (int nt = 0; nt < 4; ++nt)
        accC[cc][nt] = __builtin_amdgcn_mfma_f32_16x16x32_f16(af, bf[nt], accC[cc][nt], 0, 0, 0);
    }
  __syncthreads();  // HS reads done (MODE1's QSf overlaps HS)

  // ---- epilogue: q/mu update; q-tile kept in LDS for the fused tail ----
  #pragma unroll
  for (int nt = 0; nt < 4; ++nt) {
    int col = wnB + nt * 16 + lr;
    float b_dq = b2[col], b_dmu = b2[128 + col], b_dqmu = b2[256 + col];
    #pragma unroll
    for (int rr = 0; rr < 4; ++rr) {
      int nn = wmB + lk * 4 + rr;
      int gm = n0 + nn;
      float dq   = accC[0][nt][rr] + b_dq;
      float dmu  = accC[1][nt][rr] + b_dmu;
      float dqmu = accC[2][nt][rr] + b_dqmu;
      float V0 = (float)MM[(nn * 3 + 0) * 264 + col], W0 = (float)MM[(nn * 3 + 0) * 264 + 128 + col];
      float V1 = (float)MM[(nn * 3 + 1) * 264 + col], W1v = (float)MM[(nn * 3 + 1) * 264 + 128 + col];
      float V2 = (float)MM[(nn * 3 + 2) * 264 + col], W2v = (float)MM[(nn * 3 + 2) * 264 + 128 + col];
      float svw = V0 * W0 + V1 * W1v + V2 * W2v;
      size_t qi = (size_t)gm * 128 + col;
      float qnew = q[qi] + dq + dqmu * svw;
      if constexpr (MODE == 0) {
        q[qi] = qnew;
        QS[nn * 132 + col] = (f16)qnew;
      } else {
        QSf[nn * 132 + col] = qnew;
      }
      f16* mr = mu + (size_t)gm * 384;
      mr[col]       = (f16)((float)mr[col]       + dmu * W0);
      mr[128 + col] = (f16)((float)mr[128 + col] + dmu * W1v);
      mr[256 + col] = (f16)((float)mr[256 + col] + dmu * W2v);
    }
  }
  __syncthreads();

  if constexpr (MODE == 0) {
    // ---- phase D: h2 = silu(QS @ Wi1^T + bi1) -> H2S ----
    f32x4 accD[4] = {};
    #pragma unroll
    for (int kk = 0; kk < 4; ++kk) {
      f16x8 af = *(const f16x8*)&QS[(wmB + lr) * 132 + kk * 32 + lk * 8];
      f16x8 bf[4];
      #pragma unroll
      for (int nt = 0; nt < 4; ++nt)
        bf[nt] = *(const f16x8*)&Wi1[(size_t)(wnB + nt * 16 + lr) * 128 + kk * 32 + lk * 8];
      #pragma unroll
      for (int nt = 0; nt < 4; ++nt)
        accD[nt] = __builtin_amdgcn_mfma_f32_16x16x32_f16(af, bf[nt], accD[nt], 0, 0, 0);
    }
    #pragma unroll
    for (int nt = 0; nt < 4; ++nt) {
      int col = wnB + nt * 16 + lr;
      float bv = bi1[col];
      #pragma unroll
      for (int rr = 0; rr < 4; ++rr) {
        int row = wmB + lk * 4 + rr;
        float v = accD[nt][rr] + bv;
        v = v / (1.0f + expf(-v));
        H2S[row * 132 + col] = (f16)v;
      }
    }
    __syncthreads();
    // ---- phase E: x = h2 @ Wi2^T + bi2 ----
    #pragma unroll
    for (int cc = 0; cc < 3; ++cc) {
      f32x4 accE[4] = {};
      #pragma unroll
      for (int kk = 0; kk < 4; ++kk) {
        f16x8 af = *(const f16x8*)&H2S[(wmB + lr) * 132 + kk * 32 + lk * 8];
        f16x8 bf[4];
        #pragma unroll
        for (int nt = 0; nt < 4; ++nt)
          bf[nt] = *(const f16x8*)&Wi2[(size_t)(cc * 128 + wnB + nt * 16 + lr) * 128 + kk * 32 + lk * 8];
        #pragma unroll
        for (int nt = 0; nt < 4; ++nt)
          accE[nt] = __builtin_amdgcn_mfma_f32_16x16x32_f16(af, bf[nt], accE[nt], 0, 0, 0);
      }
      #pragma unroll
      for (int nt = 0; nt < 4; ++nt) {
        int gn = cc * 128 + wnB + nt * 16 + lr;
        float bv = bi2[gn];
        #pragma unroll
        for (int rr = 0; rr < 4; ++rr) {
          int gm = n0 + wmB + lk * 4 + rr;
          xout[(size_t)gm * 384 + gn] = (f16)(accE[nt][rr] + bv);
        }
      }
    }
  } else {
    // ---- LayerNorm + tanh on the final q tile ----
    const int d0 = lane * 2;
    #pragma unroll
    for (int rr2 = 0; rr2 < 8; ++rr2) {
      int nn = wave * 8 + rr2;
      float v0 = QSf[nn * 132 + d0];
      float v1 = QSf[nn * 132 + d0 + 1];
      v0 = fminf(fmaxf(v0, -5.f), 5.f);
      v1 = fminf(fmaxf(v1, -5.f), 5.f);
      float s = v0 + v1, s2 = v0 * v0 + v1 * v1;
      #pragma unroll
      for (int off = 32; off > 0; off >>= 1) {
        s  += __shfl_down(s,  off, 64);
        s2 += __shfl_down(s2, off, 64);
      }
      s  = __shfl(s,  0, 64);
      s2 = __shfl(s2, 0, 64);
      float mean = s * (1.0f / 128.0f);
      float var  = s2 * (1.0f / 128.0f) - mean * mean;
      float r = rsqrtf(var + 1e-5f);
      size_t o = (size_t)(n0 + nn) * 128 + d0;
      out_node[o]     = tanhf((v0 - mean) * r * ln_g[d0]     + ln_b[d0]);
      out_node[o + 1] = tanhf((v1 - mean) * r * ln_g[d0 + 1] + ln_b[d0 + 1]);
    }
  }
}

// ---------------- per-node edge reduction (HASMU=false at layer 0: mu==0) ----------------
template<bool HASMU>
__global__ __launch_bounds__(256) void k_edge_msg(
    const int* __restrict__ rs, const int* __restrict__ jperm,
    const f16* __restrict__ x, const f16* __restrict__ tab,
    const float4* __restrict__ geo, const f16* __restrict__ mu_in,
    float* __restrict__ q, f16* __restrict__ mu_out) {
  const int wid  = threadIdx.x >> 6;
  const int lane = threadIdx.x & 63;
  const int i = blockIdx.x * 4 + wid;
  if (i >= N_NODES) return;
  const int d0 = lane * 2;
  const float scale = (float)(TAB_T - 1) / 5.0f;
  float aqx = 0.f, aqy = 0.f;
  float a0x = 0.f, a0y = 0.f, a1x = 0.f, a1y = 0.f, a2x = 0.f, a2y = 0.f;
  const int s = rs[i], e = rs[i + 1];

  for (int p = s; p < e; ++p) {
    int j = jperm[p];
    float4 g = geo[p];
    float u = fminf(g.x, 5.0f) * scale;
    int t0 = min((int)u, TAB_T - 2);
    float fr = u - (float)t0, fo = 1.0f - fr;
    const f16* ta = tab + (size_t)t0 * 384;
    const f16* xj = x + (size_t)j * 384;
    f16x2 ta0 = *(const f16x2*)(ta + d0);
    f16x2 ta1 = *(const f16x2*)(ta + 128 + d0);
    f16x2 tb0 = *(const f16x2*)(ta + 384 + d0);
    f16x2 tb1 = *(const f16x2*)(ta + 512 + d0);
    f16x2 xv0 = *(const f16x2*)(xj + d0);
    f16x2 xv1 = *(const f16x2*)(xj + 128 + d0);
    float W0x = fo * (float)ta0[0] + fr * (float)tb0[0];
    float W0y = fo * (float)ta0[1] + fr * (float)tb0[1];
    float W1x = fo * (float)ta1[0] + fr * (float)tb1[0];
    float W1y = fo * (float)ta1[1] + fr * (float)tb1[1];
    float m1x = (float)xv1[0] * W1x, m1y = (float)xv1[1] * W1y;
    aqx = fmaf((float)xv0[0], W0x, aqx);
    aqy = fmaf((float)xv0[1], W0y, aqy);
    if constexpr (HASMU) {
      f16x2 ta2 = *(const f16x2*)(ta + 256 + d0);
      f16x2 tb2 = *(const f16x2*)(ta + 640 + d0);
      f16x2 xv2 = *(const f16x2*)(xj + 256 + d0);
      const f16* mj = mu_in + (size_t)j * 384;
      f16x2 mv0 = *(const f16x2*)(mj + d0);
      f16x2 mv1 = *(const f16x2*)(mj + 128 + d0);
      f16x2 mv2 = *(const f16x2*)(mj + 256 + d0);
      float W2x = fo * (float)ta2[0] + fr * (float)tb2[0];
      float W2y = fo * (float)ta2[1] + fr * (float)tb2[1];
      float m2x = (float)xv2[0] * W2x, m2y = (float)xv2[1] * W2y;
      a0x += m1x * g.y + m2x * (float)mv0[0];
      a0y += m1y * g.y + m2y * (float)mv0[1];
      a1x += m1x * g.z + m2x * (float)mv1[0];
      a1y += m1y * g.z + m2y * (float)mv1[1];
      a2x += m1x * g.w + m2x * (float)mv2[0];
      a2y += m1y * g.w + m2y * (float)mv2[1];
    } else {
      a0x += m1x * g.y; a0y += m1y * g.y;
      a1x += m1x * g.z; a1y += m1y * g.z;
      a2x += m1x * g.w; a2y += m1y * g.w;
    }
  }

  float* qp = q + (size_t)i * 128 + d0;
  float2 qv = *(float2*)qp;
  qv.x += aqx; qv.y += aqy;
  *(float2*)qp = qv;
  f16* mout = mu_out + (size_t)i * 384;
  f16x2 o0, o1, o2;
  if constexpr (HASMU) {
    const f16* min_ = mu_in + (size_t)i * 384;
    f16x2 i0 = *(const f16x2*)(min_ + d0);
    f16x2 i1 = *(const f16x2*)(min_ + 128 + d0);
    f16x2 i2 = *(const f16x2*)(min_ + 256 + d0);
    o0[0] = (f16)((float)i0[0] + a0x); o0[1] = (f16)((float)i0[1] + a0y);
    o1[0] = (f16)((float)i1[0] + a1x); o1[1] = (f16)((float)i1[1] + a1y);
    o2[0] = (f16)((float)i2[0] + a2x); o2[1] = (f16)((float)i2[1] + a2y);
  } else {
    o0[0] = (f16)a0x; o0[1] = (f16)a0y;
    o1[0] = (f16)a1x; o1[1] = (f16)a1y;
    o2[0] = (f16)a2x; o2[1] = (f16)a2y;
  }
  *(f16x2*)(mout + d0)       = o0;
  *(f16x2*)(mout + 128 + d0) = o1;
  *(f16x2*)(mout + 256 + d0) = o2;
}

// ---------------- pos_attr (per-lane zero-weight skip) ----------------
__global__ __launch_bounds__(256) void k_posattr(
    const int* __restrict__ rs, const int* __restrict__ jperm,
    const f16* __restrict__ mu, const float* __restrict__ w, float* __restrict__ pos_out) {
  const int wid  = threadIdx.x >> 6;
  const int lane = threadIdx.x & 63;
  const int i = blockIdx.x * 4 + wid;
  if (i >= N_NODES) return;
  const int d0 = lane * 2;
  float a0x = 0.f, a0y = 0.f, a1x = 0.f, a1y = 0.f, a2x = 0.f, a2y = 0.f;
  float wx = w[d0], wy = w[d0 + 1];
  if (wx != 0.0f || wy != 0.0f) {   // lanes with zero proj weight contribute exactly 0
    const int s = rs[i], e = rs[i + 1];
    for (int p = s; p < e; ++p) {
      int j = jperm[p];
      const f16* mj = mu + (size_t)j * 384;
      f16x2 A0 = *(const f16x2*)(mj + d0);
      f16x2 A1 = *(const f16x2*)(mj + 128 + d0);
      f16x2 A2 = *(const f16x2*)(mj + 256 + d0);
      a0x += (float)A0[0]; a0y += (float)A0[1];
      a1x += (float)A1[0]; a1y += (float)A1[1];
      a2x += (float)A2[0]; a2y += (float)A2[1];
    }
  }
  float s0 = fminf(fmaxf(a0x, -5.f), 5.f) * wx + fminf(fmaxf(a0y, -5.f), 5.f) * wy;
  float s1 = fminf(fmaxf(a1x, -5.f), 5.f) * wx + fminf(fmaxf(a1y, -5.f), 5.f) * wy;
  float s2 = fminf(fmaxf(a2x, -5.f), 5.f) * wx + fminf(fmaxf(a2y, -5.f), 5.f) * wy;
  #pragma unroll
  for (int off = 32; off > 0; off >>= 1) {
    s0 += __shfl_down(s0, off, 64);
    s1 += __shfl_down(s1, off, 64);
    s2 += __shfl_down(s2, off, 64);
  }
  if (lane == 0) {
    pos_out[(size_t)i * 3 + 0] = fminf(fmaxf(s0, -5.f), 5.f);
    pos_out[(size_t)i * 3 + 1] = fminf(fmaxf(s1, -5.f), 5.f);
    pos_out[(size_t)i * 3 + 2] = fminf(fmaxf(s2, -5.f), 5.f);
  }
}

extern "C" void kernel_launch(void* const* d_in, const int* in_sizes, int n_in,
                              void* d_out, int out_size, void* d_ws, size_t ws_size,
                              hipStream_t stream) {
  const float* z         = (const float*)d_in[0];
  const float* pos       = (const float*)d_in[1];
  const int*   edge_idx  = (const int*)d_in[2];
  const float* in_w      = (const float*)d_in[3];
  const float* in_b      = (const float*)d_in[4];
  const float* filt_w    = (const float*)d_in[5];
  const float* filt_b    = (const float*)d_in[6];
  const float* inter_w1  = (const float*)d_in[7];
  const float* inter_b1  = (const float*)d_in[8];
  const float* inter_w2  = (const float*)d_in[9];
  const float* inter_b2  = (const float*)d_in[10];
  const float* mix_mu_w  = (const float*)d_in[11];
  const float* mix_w1    = (const float*)d_in[12];
  const float* mix_b1    = (const float*)d_in[13];
  const float* mix_w2    = (const float*)d_in[14];
  const float* mix_b2    = (const float*)d_in[15];
  const float* mu_proj_w = (const float*)d_in[16];
  const float* ln_g      = (const float*)d_in[17];
  const float* ln_b      = (const float*)d_in[18];

  char* base = (char*)d_ws;
  size_t off = 0;
  auto alloc = [&](size_t bytes) -> char* {
    char* p = base + off;
    off += (bytes + 255) & ~(size_t)255;
    return p;
  };
  float*  q     = (float*)alloc((size_t)N_NODES * 128 * 4);
  f16*    x16   = (f16*)alloc((size_t)N_NODES * 384 * 2);
  f16*    mu_a  = (f16*)alloc((size_t)N_NODES * 384 * 2);
  f16*    mu_b  = (f16*)alloc((size_t)N_NODES * 384 * 2);
  float4* geo   = (float4*)alloc((size_t)N_EDGES * 16);
  int*    cnt   = (int*)alloc((size_t)N_NODES * 4);
  int*    incl  = (int*)alloc((size_t)N_NODES * 4);
  int*    bsum  = (int*)alloc(128 * 4);
  int*    rs    = (int*)alloc((size_t)(N_NODES + 1) * 4);
  int*    cur   = (int*)alloc((size_t)N_NODES * 4);
  int*    jperm = (int*)alloc((size_t)N_EDGES * 4);
  f16*    tab   = (f16*)alloc((size_t)TAB_T * 384 * 2);
  f16* wt_in = (f16*)alloc((size_t)128 * 64 * 2);
  f16* wt_i1 = (f16*)alloc((size_t)3 * 128 * 128 * 2);
  f16* wt_i2 = (f16*)alloc((size_t)3 * 384 * 128 * 2);
  f16* wt_mu = (f16*)alloc((size_t)3 * 256 * 128 * 2);
  f16* wt_x1 = (f16*)alloc((size_t)3 * 128 * 256 * 2);
  f16* wt_x2 = (f16*)alloc((size_t)3 * 384 * 128 * 2);
  if (off > ws_size) return;

  float* out_node = (float*)d_out;
  float* out_pos  = (float*)d_out + (size_t)N_NODES * 128;

  // ---- prep: weight transpose (16 jobs) + filter table ----
  {
    WJobs jb;
    int ji = 0;
    jb.j[ji++] = {in_w, wt_in, 6, 128, 0, 128 * 64};
    for (int l = 0; l < 3; ++l)
      jb.j[ji++] = {inter_w1 + (size_t)l*128*128, wt_i1 + (size_t)l*128*128, 7, 128, 0, 128*128};
    for (int l = 0; l < 3; ++l)
      jb.j[ji++] = {inter_w2 + (size_t)l*128*384, wt_i2 + (size_t)l*384*128, 7, 384, 0, 384*128};
    for (int l = 0; l < 3; ++l)
      jb.j[ji++] = {mix_mu_w + (size_t)l*128*256, wt_mu + (size_t)l*256*128, 7, 256, 0, 256*128};
    for (int l = 0; l < 3; ++l)
      jb.j[ji++] = {mix_w1 + (size_t)l*256*128, wt_x1 + (size_t)l*128*256, 8, 128, 0, 128*256};
    for (int l = 0; l < 3; ++l)
      jb.j[ji++] = {mix_w2 + (size_t)l*128*384, wt_x2 + (size_t)l*384*128, 7, 384, 0, 384*128};
    dim3 g(192, 24);
    k_prep<<<g, 256, 0, stream>>>(jb, filt_w, filt_b, tab);
  }

  // ---- CSR build + geometry ----
  hipMemsetAsync(cnt, 0, (size_t)N_NODES * 4, stream);
  k_hist<<<N_EDGES / 256, 256, 0, stream>>>(edge_idx, cnt);
  k_scan_blk<<<NB_SCAN, 256, 0, stream>>>(cnt, incl, bsum);
  k_scan_top<<<1, 128, 0, stream>>>(bsum);
  k_scan_add<<<NB_SCAN, 256, 0, stream>>>(cnt, incl, bsum, rs, cur);
  k_fill_geom<<<N_EDGES / 256, 256, 0, stream>>>(edge_idx, pos, cur, geo, jperm);

  // ---- embed + inter MLP (layer 0) ----
  const int gmx = N_NODES / 32;          // 625
  const int gn4 = (N_NODES + 3) / 4;     // 5000
  k_embed_i<<<gmx, 256, 0, stream>>>(z, wt_in, in_b,
                                     wt_i1, inter_b1, wt_i2, inter_b2, q, x16);

  f16* mu_cur = mu_a;
  f16* mu_nxt = mu_b;
  for (int l = 0; l < NLAYER; ++l) {
    if (l == 0)
      k_edge_msg<false><<<gn4, 256, 0, stream>>>(rs, jperm, x16, tab, geo, mu_cur, q, mu_nxt);
    else
      k_edge_msg<true><<<gn4, 256, 0, stream>>>(rs, jperm, x16, tab, geo, mu_cur, q, mu_nxt);
    { f16* t = mu_cur; mu_cur = mu_nxt; mu_nxt = t; }
    if (l < NLAYER - 1) {
      k_mix<0><<<gmx, 256, 0, stream>>>(q, mu_cur, wt_mu + (size_t)l*256*128,
                                        wt_x1 + (size_t)l*128*256, mix_b1 + (size_t)l*128,
                                        wt_x2 + (size_t)l*384*128, mix_b2 + (size_t)l*384,
                                        wt_i1 + (size_t)(l+1)*128*128, inter_b1 + (size_t)(l+1)*128,
                                        wt_i2 + (size_t)(l+1)*384*128, inter_b2 + (size_t)(l+1)*384,
                                        x16, nullptr, nullptr, nullptr);
    } else {
      k_mix<1><<<gmx, 256, 0, stream>>>(q, mu_cur, wt_mu + (size_t)l*256*128,
                                        wt_x1 + (size_t)l*128*256, mix_b1 + (size_t)l*128,
                                        wt_x2 + (size_t)l*384*128, mix_b2 + (size_t)l*384,
                                        nullptr, nullptr, nullptr, nullptr, nullptr,
                                        ln_g, ln_b, out_node);
    }
  }

  // ---- pos_attr ----
  k_posattr<<<gn4, 256, 0, stream>>>(rs, jperm, mu_cur, mu_proj_w, out_pos);
}